// Round 12
// baseline (3377.770 us; speedup 1.0000x reference)
//
#include <hip/hip_runtime.h>
#include <math.h>

// ---------------------------------------------------------------------------
// ODERGRU pipeline for MI355X.
//  K1: einsum -> h1 (3200,96,29)
//  K2: conv1d 96->96 k5 + bias -> h2 + BN partials
//  K3: BN1 reduce   K5: BN2 reduce  (f64 tree)
//  K4: conv1d 96->16 k5 (BN1+lrelu on load) -> h3 + BN2 partials
//  K6: OAS + Cholesky -> x_d, x_o
//  K0: pack ODE/GRU weights f32 -> f16 fragments (MFMA lane order)
//  K7: 4 blocks x 4 waves x 16 rows. Swapped MFMA (A=W streamed, B=X^T from
//      LDS once/layer/wave). NEW: t-outer interleaved MFMA with split-K x2
//      accumulators -> 8 independent chains/wave (kills dependent-MFMA
//      latency); depth-3 A prefetch. 18 barriers/step.
// ---------------------------------------------------------------------------

#define BB 64
#define NIMG 3200

typedef _Float16 f16;
typedef _Float16 f16x8 __attribute__((ext_vector_type(8)));
typedef float f32x4 __attribute__((ext_vector_type(4)));

__device__ __forceinline__ float fsigm(float x) {
  return __fdividef(1.f, 1.f + __expf(-x));
}
__device__ __forceinline__ float ftanh(float x) {
  return 1.f - __fdividef(2.f, __expf(2.f * x) + 1.f);
}

// pk region offsets (u32 units)
#define OFF_W0  0
#define OFF_W1  20480
#define OFF_W2  53248
#define OFF_W3  86016
#define OFF_GRZ 104448
#define OFF_GNX 135168
#define OFF_GNH 143360
#define PK2_TOT 151552

// ------------------------------ K1: filterbank ------------------------------
__global__ __launch_bounds__(256) void k1_fb(const float* __restrict__ x,
                                             const float* __restrict__ fw,
                                             const float* __restrict__ st,
                                             float* __restrict__ h1) {
  __shared__ __align__(16) float ws[129 * 32];
  __shared__ __align__(16) float xs[129 * 32];
  const int tid = threadIdx.x;
  const int n = blockIdx.x;
  const float* xp = x + (size_t)n * 11223;

  for (int i = tid; i < 4128; i += 256) ws[i] = fw[i] * st[i];

  float acc[4][4];
#pragma unroll
  for (int i = 0; i < 4; ++i)
#pragma unroll
    for (int j = 0; j < 4; ++j) acc[i][j] = 0.f;

  const int c = tid / 64;
  const int rem = tid % 64;
  const int m0 = (rem / 8) * 4;
  const int t0 = (rem % 8) * 4;

  for (int fc = 0; fc < 3; ++fc) {
    __syncthreads();
    for (int i = tid; i < 3741; i += 256) {
      int cc = i / 1247;
      int r = i - cc * 1247;
      int f = r / 29;
      int t = r - f * 29;
      xs[(cc * 43 + f) * 32 + t] = xp[cc * 3741 + (fc * 43 + f) * 29 + t];
    }
    for (int i = tid; i < 129; i += 256) {
      xs[i * 32 + 29] = 0.f; xs[i * 32 + 30] = 0.f; xs[i * 32 + 31] = 0.f;
    }
    __syncthreads();
    if (tid < 192) {
      const float* xb = xs + (c * 43) * 32 + t0;
      const float* wb = ws + (fc * 43) * 32 + m0;
      for (int f = 0; f < 43; ++f) {
        float4 xv = *(const float4*)(xb + f * 32);
        float4 wv = *(const float4*)(wb + f * 32);
        float xa[4] = {xv.x, xv.y, xv.z, xv.w};
        float wa[4] = {wv.x, wv.y, wv.z, wv.w};
#pragma unroll
        for (int i = 0; i < 4; ++i)
#pragma unroll
          for (int j = 0; j < 4; ++j) acc[i][j] += wa[i] * xa[j];
      }
    }
  }
  if (tid < 192) {
    const int nt = (t0 == 28) ? 1 : 4;
    for (int i = 0; i < 4; ++i)
      for (int j = 0; j < nt; ++j)
        h1[(size_t)n * 2784 + (size_t)(c * 32 + m0 + i) * 29 + (t0 + j)] = acc[i][j];
  }
}

// ------------------------------ K2: conv1 ------------------------------
__global__ __launch_bounds__(256) void k2_conv1(const float* __restrict__ h1,
                                                const float* __restrict__ w,
                                                const float* __restrict__ bias,
                                                float* __restrict__ h2,
                                                float* __restrict__ part1) {
  __shared__ __align__(16) float ins[2 * 96 * 32];
  __shared__ __align__(16) float wls[96 * 81];
  const int tid = threadIdx.x;
  const int wg = blockIdx.x;

  for (int i = tid; i < 2 * 2784; i += 256) {
    int img = i / 2784;
    int e = i - img * 2784;
    int ci = e / 29;
    int t = e - ci * 29;
    ins[img * 3072 + ci * 32 + t] = h1[(size_t)(wg * 2 + img) * 2784 + e];
  }

  const int img = tid / 96;
  const int co = tid - img * 96;
  float acc[25];
#pragma unroll
  for (int t = 0; t < 25; ++t) acc[t] = 0.f;

  for (int cc = 0; cc < 6; ++cc) {
    __syncthreads();
    for (int i = tid; i < 7680; i += 256) {
      int cw = i / 80;
      int r = i - cw * 80;
      wls[cw * 81 + r] = w[cw * 480 + cc * 80 + r];
    }
    __syncthreads();
    if (tid < 192) {
      for (int ci = 0; ci < 16; ++ci) {
        float xv[29];
#pragma unroll
        for (int j = 0; j < 29; ++j) xv[j] = ins[img * 3072 + (cc * 16 + ci) * 32 + j];
        float wv[5];
#pragma unroll
        for (int d = 0; d < 5; ++d) wv[d] = wls[co * 81 + ci * 5 + d];
#pragma unroll
        for (int t = 0; t < 25; ++t) {
          float s = acc[t];
#pragma unroll
          for (int d = 0; d < 5; ++d) s += xv[t + d] * wv[d];
          acc[t] = s;
        }
      }
    }
  }
  if (tid < 192) {
    const int n = wg * 2 + img;
    const float bval = bias[co];
    float s1 = 0.f, s2 = 0.f;
    for (int t = 0; t < 25; ++t) {
      float v = acc[t] + bval;
      h2[(size_t)n * 2400 + co * 25 + t] = v;
      s1 += v;
      s2 += v * v;
    }
    part1[((size_t)n * 96 + co) * 2 + 0] = s1;
    part1[((size_t)n * 96 + co) * 2 + 1] = s2;
  }
}

// ------------------------------ K3/K5: BN reduce -----------------------------
__global__ __launch_bounds__(256) void k3_bn1(const float* __restrict__ part,
                                              const float* __restrict__ gg,
                                              const float* __restrict__ be,
                                              float* __restrict__ ab) {
  __shared__ double sd[256], sq[256];
  const int c = blockIdx.x;
  const int t = threadIdx.x;
  double s = 0.0, q = 0.0;
  for (int n = t; n < NIMG; n += 256) {
    s += (double)part[((size_t)n * 96 + c) * 2 + 0];
    q += (double)part[((size_t)n * 96 + c) * 2 + 1];
  }
  sd[t] = s; sq[t] = q;
  __syncthreads();
  for (int off = 128; off > 0; off >>= 1) {
    if (t < off) { sd[t] += sd[t + off]; sq[t] += sq[t + off]; }
    __syncthreads();
  }
  if (t == 0) {
    double mu = sd[0] / 80000.0;
    double var = sq[0] / 80000.0 - mu * mu;
    float A = (float)((double)gg[c] / sqrt(var + 1e-5));
    ab[c * 2 + 0] = A;
    ab[c * 2 + 1] = (float)((double)be[c] - mu * (double)A);
  }
}

__global__ __launch_bounds__(256) void k5_bn2(const float* __restrict__ part,
                                              const float* __restrict__ gg,
                                              const float* __restrict__ be,
                                              float* __restrict__ ab) {
  __shared__ double sd[256], sq[256];
  const int c = blockIdx.x;
  const int t = threadIdx.x;
  double s = 0.0, q = 0.0;
  for (int n = t; n < 800; n += 256) {
    s += (double)part[((size_t)n * 16 + c) * 2 + 0];
    q += (double)part[((size_t)n * 16 + c) * 2 + 1];
  }
  sd[t] = s; sq[t] = q;
  __syncthreads();
  for (int off = 128; off > 0; off >>= 1) {
    if (t < off) { sd[t] += sd[t + off]; sq[t] += sq[t + off]; }
    __syncthreads();
  }
  if (t == 0) {
    double mu = sd[0] / 67200.0;
    double var = sq[0] / 67200.0 - mu * mu;
    float A = (float)((double)gg[c] / sqrt(var + 1e-5));
    ab[c * 2 + 0] = A;
    ab[c * 2 + 1] = (float)((double)be[c] - mu * (double)A);
  }
}

// ------------------------------ K4: conv2 ------------------------------
__global__ __launch_bounds__(256) void k4_conv2(const float* __restrict__ h2,
                                                const float* __restrict__ w,
                                                const float* __restrict__ bias,
                                                const float* __restrict__ bn1,
                                                float* __restrict__ h3,
                                                float* __restrict__ part2) {
  __shared__ __align__(16) float ins[4 * 96 * 26];
  __shared__ __align__(16) float wls[16 * 241];
  __shared__ float A1s[96], B1s[96];
  __shared__ float red[16 * 16 * 2];
  const int tid = threadIdx.x;
  const int wg = blockIdx.x;

  if (tid < 96) {
    A1s[tid] = bn1[tid * 2 + 0];
    B1s[tid] = bn1[tid * 2 + 1];
  }
  __syncthreads();
  for (int i = tid; i < 9600; i += 256) {
    int img = i / 2400;
    int e = i - img * 2400;
    int ci = e / 25;
    int t = e - ci * 25;
    float v = h2[(size_t)(wg * 4 + img) * 2400 + e];
    v = A1s[ci] * v + B1s[ci];
    v = (v >= 0.f) ? v : 0.01f * v;
    ins[img * 2496 + ci * 26 + t] = v;
  }
  for (int i = tid; i < 4 * 96; i += 256) ins[(i / 96) * 2496 + (i % 96) * 26 + 25] = 0.f;

  const int img = tid >> 6;
  const int co = (tid >> 2) & 15;
  const int tg = tid & 3;
  const int t0s[4] = {0, 6, 11, 16};
  const int t0 = t0s[tg];
  const int tl = (tg == 0) ? 6 : 5;
  float acc[6] = {0.f, 0.f, 0.f, 0.f, 0.f, 0.f};

  for (int cc = 0; cc < 2; ++cc) {
    __syncthreads();
    for (int i = tid; i < 3840; i += 256) {
      int cw = i / 240;
      int r = i - cw * 240;
      wls[cw * 241 + r] = w[cw * 480 + cc * 240 + r];
    }
    __syncthreads();
    for (int ci = 0; ci < 48; ++ci) {
      float xv[10];
#pragma unroll
      for (int j = 0; j < 10; ++j) xv[j] = ins[img * 2496 + (cc * 48 + ci) * 26 + t0 + j];
      float wv[5];
#pragma unroll
      for (int d = 0; d < 5; ++d) wv[d] = wls[co * 241 + ci * 5 + d];
#pragma unroll
      for (int t = 0; t < 6; ++t) {
        float s = acc[t];
#pragma unroll
        for (int d = 0; d < 5; ++d) s += xv[t + d] * wv[d];
        acc[t] = s;
      }
    }
  }
  const float bval = bias[co];
  float s1 = 0.f, s2 = 0.f;
  const int n = wg * 4 + img;
  for (int t = 0; t < 6; ++t) {
    if (t < tl) {
      float v = acc[t] + bval;
      h3[(size_t)n * 336 + co * 21 + t0 + t] = v;
      s1 += v;
      s2 += v * v;
    }
  }
  red[(co * 16 + img * 4 + tg) * 2 + 0] = s1;
  red[(co * 16 + img * 4 + tg) * 2 + 1] = s2;
  __syncthreads();
  if (tid < 16) {
    float s = 0.f, q = 0.f;
    for (int k = 0; k < 16; ++k) {
      s += red[(tid * 16 + k) * 2 + 0];
      q += red[(tid * 16 + k) * 2 + 1];
    }
    part2[((size_t)wg * 16 + tid) * 2 + 0] = s;
    part2[((size_t)wg * 16 + tid) * 2 + 1] = q;
  }
}

// ------------------------------ K6: OAS + Cholesky ---------------------------
__global__ __launch_bounds__(256) void k6_oas(const float* __restrict__ h3,
                                              const float* __restrict__ bn2,
                                              float* __restrict__ xd,
                                              float* __restrict__ xo) {
  __shared__ float X[4][21 * 17 + 3];
  __shared__ float A[4][16 * 17];
  __shared__ float mcol[4][16];
  const int tid = threadIdx.x;
  const int wid = tid >> 6;
  const int lane = tid & 63;
  const int n = blockIdx.x * 4 + wid;
  const float* hp = h3 + (size_t)n * 336;

  for (int e = lane; e < 336; e += 64) {
    int c = e / 21;
    int t = e - c * 21;
    float v = hp[e];
    v = bn2[c * 2 + 0] * v + bn2[c * 2 + 1];
    v = (v >= 0.f) ? v : 0.01f * v;
    X[wid][t * 17 + c] = v;
  }
  __syncthreads();
  if (lane < 16) {
    float s = 0.f;
    for (int t = 0; t < 21; ++t) s += X[wid][t * 17 + lane];
    mcol[wid][lane] = s * (1.f / 21.f);
  }
  __syncthreads();
  for (int e = lane; e < 336; e += 64) {
    int t = e / 16;
    int c = e - t * 16;
    X[wid][t * 17 + c] -= mcol[wid][c];
  }
  __syncthreads();

  float tr_p = 0.f, al_p = 0.f;
  float ent[3];
  int ei[3], ej[3], ne = 0;
  for (int e = lane; e < 136; e += 64) {
    int i = 0, e2 = e;
    while (e2 >= 16 - i) { e2 -= 16 - i; i++; }
    int j = i + e2;
    float s = 0.f;
    for (int t = 0; t < 21; ++t) s += X[wid][t * 17 + i] * X[wid][t * 17 + j];
    s *= (1.f / 20.f);
    ent[ne] = s; ei[ne] = i; ej[ne] = j; ne++;
    if (i == j) tr_p += s;
    al_p += s * s * ((i == j) ? 1.f : 2.f);
  }
  for (int m = 1; m < 64; m <<= 1) {
    tr_p += __shfl_xor(tr_p, m);
    al_p += __shfl_xor(al_p, m);
  }
  const float mu = tr_p * (1.f / 16.f);
  const float alpha = al_p * (1.f / 256.f);
  const float num = alpha + mu * mu;
  const float den = 22.f * (alpha - mu * mu * (1.f / 16.f));
  const float shr = (den == 0.f) ? 1.f : fminf(num / den, 1.f);
  for (int q = 0; q < ne; ++q) {
    float c = (1.f - shr) * ent[q] + ((ei[q] == ej[q]) ? shr * mu : 0.f);
    A[wid][ei[q] * 17 + ej[q]] = c;
    A[wid][ej[q] * 17 + ei[q]] = c;
  }
  __syncthreads();

  for (int k = 0; k < 16; ++k) {
    float akk = A[wid][k * 17 + k];
    __syncthreads();
    float d = sqrtf(akk);
    float rd = 1.f / d;
    if (lane == k) A[wid][k * 17 + k] = d;
    if (lane > k && lane < 16) A[wid][lane * 17 + k] *= rd;
    __syncthreads();
    if (lane > k && lane < 16) {
      float Lik = A[wid][lane * 17 + k];
      for (int j = k + 1; j <= lane; ++j) A[wid][lane * 17 + j] -= Lik * A[wid][j * 17 + k];
    }
    __syncthreads();
  }
  if (lane < 16) xd[(size_t)n * 16 + lane] = A[wid][lane * 17 + lane];
  for (int p = lane; p < 120; p += 64) {
    int i = 1, p2 = p;
    while (p2 >= i) { p2 -= i; i++; }
    xo[(size_t)n * 120 + p] = A[wid][i * 17 + p2];
  }
}

// ------------------------------ K0: pack W fragments ------------------------
// u32 slot within region: tile=(t*NT+nt), rem: lane=rem/4, word=rem%4.
// index = nt*16 + (lane&15), k = t*32 + 8*(lane>>4) + 2*word (+1).
// (Used as the MFMA *A* operand in k7; A and B share the lane->k map.)
__global__ __launch_bounds__(256) void k0_pack(const float* __restrict__ w0,
                                               const float* __restrict__ w1,
                                               const float* __restrict__ w2,
                                               const float* __restrict__ w3,
                                               const float* __restrict__ wxo,
                                               const float* __restrict__ who,
                                               uint32_t* __restrict__ dst) {
  int i = blockIdx.x * 256 + threadIdx.x;
  if (i >= PK2_TOT) return;
  int j = i, kind, NT;
  if (j < OFF_W1)       { kind = 0; NT = 16; }
  else if (j < OFF_W2)  { kind = 1; NT = 16; j -= OFF_W1; }
  else if (j < OFF_W3)  { kind = 2; NT = 16; j -= OFF_W2; }
  else if (j < OFF_GRZ) { kind = 3; NT = 9;  j -= OFF_W3; }
  else if (j < OFF_GNX) { kind = 4; NT = 15; j -= OFF_GRZ; }
  else if (j < OFF_GNH) { kind = 5; NT = 8;  j -= OFF_GNX; }
  else                  { kind = 6; NT = 8;  j -= OFF_GNH; }
  const int tile = j >> 8;
  const int rem = j & 255;
  const int l = rem >> 2;
  const int wd = rem & 3;
  const int t = tile / NT;
  const int nt = tile - t * NT;
  const int col = nt * 16 + (l & 15);
  const int kk = t * 32 + 8 * (l >> 4) + 2 * wd;

  float v[2];
#pragma unroll
  for (int q = 0; q < 2; ++q) {
    const int k = kk + q;
    float s = 0.f;
    if (kind == 0)      { if (k < 136) s = w0[k * 256 + col]; }
    else if (kind == 1) { s = w1[k * 256 + col]; }
    else if (kind == 2) { s = w2[k * 256 + col]; }
    else if (kind == 3) { if (col < 136) s = w3[k * 136 + col]; }
    else if (kind == 4) {
      if (k < 120) s = wxo[k * 360 + col];
      else if (k >= 128 && k < 248) s = who[(k - 128) * 360 + col];
    } else if (kind == 5) { if (k < 120 && col < 120) s = wxo[k * 360 + 240 + col]; }
    else                  { if (k < 120 && col < 120) s = who[k * 360 + 240 + col]; }
    v[q] = s;
  }
  union { f16 h[2]; uint32_t u; } cv;
  cv.h[0] = (f16)v[0];
  cv.h[1] = (f16)v[1];
  dst[i] = cv.u;
}

// ------------------------------ K7 helpers ----------------------------------
union UF { uint4 u; f16x8 h; };
union PK4 { f16 h[4]; uint2 u2; };

// swizzled LDS address: row-strided buffer, XOR byte-bits 4-6 with row&7
__device__ __forceinline__ char* swzp(void* base, int row, int b, int stride) {
  return (char*)base + row * stride + (b ^ ((row & 7) << 4));
}
// B-fragment read: [row n][k] f16 buffer (stride 512B), k-tile t, group g
__device__ __forceinline__ uint4 rdB(void* X, int t, int n, int g) {
  return *(const uint4*)swzp(X, n, 64 * t + 16 * g, 512);
}

// Streamed-A layer, wave w owns tiles {w, w+4, ...} < NT.
// t-outer interleaved MFMA: up to 4 tiles x split-K(2) = 8 independent chains.
// Depth-3 rotating A-prefetch (static indices).
template <int KT, int NT, typename EPI>
__device__ __forceinline__ void layerW(const uint4* __restrict__ W,
                                       const uint4 (&bf)[KT], int w, int l,
                                       EPI epi) {
  const int cnt = (NT - w + 3) >> 2;   // tiles this wave owns (1..4)
  uint4 a[4][3];
  f32x4 accE[4], accO[4];
#pragma unroll
  for (int c = 0; c < 4; ++c) {
    accE[c] = (f32x4){0.f, 0.f, 0.f, 0.f};
    accO[c] = (f32x4){0.f, 0.f, 0.f, 0.f};
  }
#pragma unroll
  for (int d = 0; d < 3; ++d) {
    if (d < KT) {
#pragma unroll
      for (int c = 0; c < 4; ++c)
        if (c < cnt) a[c][d] = W[(d * NT + (w + 4 * c)) * 64 + l];
    }
  }
#pragma unroll
  for (int t = 0; t < KT; ++t) {
    const int slot = t % 3;
#pragma unroll
    for (int c = 0; c < 4; ++c) {
      if (c < cnt) {
        UF aa; aa.u = a[c][slot];
        UF bb; bb.u = bf[t];
        if (t & 1)
          accO[c] = __builtin_amdgcn_mfma_f32_16x16x32_f16(aa.h, bb.h, accO[c], 0, 0, 0);
        else
          accE[c] = __builtin_amdgcn_mfma_f32_16x16x32_f16(aa.h, bb.h, accE[c], 0, 0, 0);
      }
    }
    if (t + 3 < KT) {
#pragma unroll
      for (int c = 0; c < 4; ++c)
        if (c < cnt) a[c][slot] = W[((t + 3) * NT + (w + 4 * c)) * 64 + l];
    }
  }
#pragma unroll
  for (int c = 0; c < 4; ++c) {
    if (c < cnt) {
      f32x4 acc;
#pragma unroll
      for (int q = 0; q < 4; ++q) acc[q] = accE[c][q] + accO[c][q];
      epi(w + 4 * c, acc);
    }
  }
}

// ------------------------------ K7: scan (4 waves, swapped MFMA, ILP) -------
__global__ __launch_bounds__(256, 1) void k7_scan(
    const float* __restrict__ xdv, const float* __restrict__ xov,
    const float* __restrict__ wxd, const float* __restrict__ whd,
    const float* __restrict__ bdv, const float* __restrict__ bov,
    const uint32_t* __restrict__ pk,
    const float* __restrict__ b0, const float* __restrict__ b1,
    const float* __restrict__ b2, const float* __restrict__ b3,
    const float* __restrict__ cw, const float* __restrict__ cbv,
    float* __restrict__ out) {
  // activation buffers: [16 rows][256 k] f16, stride 512B, swizzled
  __shared__ __align__(16) f16 XA[16 * 256];
  __shared__ __align__(16) f16 XB[16 * 256];
  __shared__ __align__(16) f16 XC[16 * 256];
  __shared__ __align__(16) f16 XG[16 * 256];
  __shared__ __align__(16) float hcf[16 * 160];   // stride 640B, swizzled
  __shared__ __align__(16) float GO[16 * 512];    // stride 2048B, swizzled
  __shared__ __align__(16) float G2[16 * 96];
  __shared__ __align__(16) float xdlv[16 * 16];
  __shared__ __align__(16) float ehl[16 * 16];
  __shared__ __align__(16) float wdaT[48 * 16], whaT[48 * 16];
  __shared__ __align__(16) float b0l[256], b1l[256], b2l[256], b3l[144];
  __shared__ __align__(16) float bovl[360], bdvl[48];

  const int tid = threadIdx.x;   // 0..255
  const int w = tid >> 6;        // wave 0..3
  const int l = tid & 63;
  const int n = l & 15;          // batch row within group
  const int g = l >> 4;          // 0..3
  const int blk = blockIdx.x;

  const uint4* BW0 = (const uint4*)(pk + OFF_W0);
  const uint4* BW1 = (const uint4*)(pk + OFF_W1);
  const uint4* BW2 = (const uint4*)(pk + OFF_W2);
  const uint4* BW3 = (const uint4*)(pk + OFF_W3);
  const uint4* BRZ = (const uint4*)(pk + OFF_GRZ);
  const uint4* BNX = (const uint4*)(pk + OFF_GNX);
  const uint4* BNH = (const uint4*)(pk + OFF_GNH);

  // ---- init ----
  for (int i = tid; i < 768; i += 256) {
    int k = i / 48, c = i - k * 48;
    wdaT[c * 16 + k] = fabsf(wxd[i]);
    whaT[c * 16 + k] = fabsf(whd[i]);
  }
  for (int i = tid; i < 256; i += 256) { b0l[i] = b0[i]; b1l[i] = b1[i]; b2l[i] = b2[i]; }
  if (tid < 144) b3l[tid] = (tid < 136) ? b3[tid] : 0.f;
  for (int i = tid; i < 360; i += 256) bovl[i] = bov[i];
  if (tid < 48) bdvl[tid] = fabsf(bdv[tid]);
  for (int i = tid; i < 16 * 160; i += 256) hcf[i] = 0.f;
  for (int i = tid; i < 16 * 256; i += 256) { XA[i] = (f16)0.f; XG[i] = (f16)0.f; }
  __syncthreads();

  // epilogue helpers ---------------------------------------------------------
  auto epi_tanh = [&](f16* Xout, const float* bl, int nt, f32x4 acc) {
    const int m0 = nt * 16 + 4 * g;
    float4 bb = *(const float4*)&bl[m0];
    PK4 p;
#pragma unroll
    for (int i = 0; i < 4; ++i) p.h[i] = (f16)ftanh(acc[i] + (&bb.x)[i]);
    *(uint2*)swzp(Xout, n, 2 * m0, 512) = p.u2;
  };
  auto epi_l3 = [&](bool last, int nt, f32x4 acc) {
    const int m0 = nt * 16 + 4 * g;
    if (m0 >= 136) return;                       // nt==8, g>=2
    float4 bb = *(const float4*)&b3l[m0];
    float* hp = (float*)swzp(hcf, n, 4 * m0, 640);
    float4 hv = *(const float4*)hp;
    float nv[4];
#pragma unroll
    for (int i = 0; i < 4; ++i) nv[i] = (&hv.x)[i] + 0.25f * (acc[i] + (&bb.x)[i]);
    *(float4*)hp = make_float4(nv[0], nv[1], nv[2], nv[3]);
    if (!last) {
      PK4 p;
#pragma unroll
      for (int i = 0; i < 4; ++i) p.h[i] = (f16)nv[i];
      *(uint2*)swzp(XA, n, 2 * m0, 512) = p.u2;
    } else {
      if (m0 >= 16) {                            // h_o -> XG at k = m0+112
        PK4 p;
#pragma unroll
        for (int i = 0; i < 4; ++i) p.h[i] = (f16)nv[i];
        *(uint2*)swzp(XG, n, 2 * (m0 + 112), 512) = p.u2;
      } else {                                   // exp(hc_d) -> ehl (f32)
        *(float4*)&ehl[n * 16 + m0] =
            make_float4(__expf(nv[0]), __expf(nv[1]), __expf(nv[2]), __expf(nv[3]));
      }
    }
  };
  auto epi_go = [&](int dst0, int nt, f32x4 acc) {
    const int m0 = dst0 + nt * 16 + 4 * g;
    *(float4*)swzp(GO, n, 4 * m0, 2048) = make_float4(acc[0], acc[1], acc[2], acc[3]);
  };

#pragma unroll 1
  for (int s = 0; s < 50; ++s) {
    // ---- stage this step's gate inputs (consumed after several barriers) ----
    for (int i = tid; i < 1920; i += 256) {
      int row = i / 120, c = i - row * 120;
      *(f16*)swzp(XG, row, 2 * c, 512) =
          (f16)xov[((size_t)(blk * 16 + row) * 50 + s) * 120 + c];
    }
    {
      int row = tid >> 4, k = tid & 15;
      xdlv[tid] = xdv[((size_t)(blk * 16 + row) * 50 + s) * 16 + k];
    }

    // ---- ODE: 4 Euler steps; 4 phases each ----
#pragma unroll 1
    for (int e = 0; e < 4; ++e) {
      {
        uint4 bf[5];
#pragma unroll
        for (int t = 0; t < 5; ++t) bf[t] = rdB(XA, t, n, g);
        layerW<5, 16>(BW0, bf, w, l, [&](int nt, f32x4 acc) { epi_tanh(XB, b0l, nt, acc); });
      }
      __syncthreads();
      {
        uint4 bf[8];
#pragma unroll
        for (int t = 0; t < 8; ++t) bf[t] = rdB(XB, t, n, g);
        layerW<8, 16>(BW1, bf, w, l, [&](int nt, f32x4 acc) { epi_tanh(XC, b1l, nt, acc); });
      }
      __syncthreads();
      {
        uint4 bf[8];
#pragma unroll
        for (int t = 0; t < 8; ++t) bf[t] = rdB(XC, t, n, g);
        layerW<8, 16>(BW2, bf, w, l, [&](int nt, f32x4 acc) { epi_tanh(XB, b2l, nt, acc); });
      }
      __syncthreads();
      {
        uint4 bf[8];
#pragma unroll
        for (int t = 0; t < 8; ++t) bf[t] = rdB(XB, t, n, g);
        const bool last = (e == 3);
        layerW<8, 9>(BW3, bf, w, l, [&](int nt, f32x4 acc) { epi_l3(last, nt, acc); });
      }
      __syncthreads();
    }

    // ---- gate matmuls + d-gate dots, one phase ----
    {
      uint4 bf[8];
#pragma unroll
      for (int t = 0; t < 8; ++t) bf[t] = rdB(XG, t, n, g);
      layerW<8, 15>(BRZ, bf, w, l, [&](int nt, f32x4 acc) { epi_go(0, nt, acc); });
      uint4 bx[4] = {bf[0], bf[1], bf[2], bf[3]};
      layerW<4, 8>(BNX, bx, w, l, [&](int nt, f32x4 acc) { epi_go(256, nt, acc); });
      uint4 bh[4] = {bf[4], bf[5], bf[6], bf[7]};
      layerW<4, 8>(BNH, bh, w, l, [&](int nt, f32x4 acc) { epi_go(384, nt, acc); });
    }
    for (int i = tid; i < 1536; i += 256) {
      int row = i / 96, c = i - row * 96;
      const float4* sv = (const float4*)((c < 48) ? &xdlv[row * 16] : &ehl[row * 16]);
      const float4* wv = (const float4*)((c < 48) ? &wdaT[c * 16] : &whaT[(c - 48) * 16]);
      float a = 0.f;
#pragma unroll
      for (int q = 0; q < 4; ++q) {
        float4 xq = sv[q], wq = wv[q];
        a += xq.x * wq.x + xq.y * wq.y + xq.z * wq.z + xq.w * wq.w;
      }
      G2[row * 96 + c] = a;
    }
    __syncthreads();

    // ---- state update (writes hcf AND next-step XA) ----
    for (int i = tid; i < 1920; i += 256) {
      int row = i / 120, e2 = i - row * 120;
      float rr = fsigm(*(const float*)swzp(GO, row, 4 * e2, 2048) + bovl[e2]);
      float zz = fsigm(*(const float*)swzp(GO, row, 4 * (120 + e2), 2048) + bovl[120 + e2]);
      float ig = *(const float*)swzp(GO, row, 4 * (256 + e2), 2048);
      float hg = *(const float*)swzp(GO, row, 4 * (384 + e2), 2048);
      float ng = ftanh(ig + rr * hg + bovl[240 + e2]);
      float* hp = (float*)swzp(hcf, row, 4 * (16 + e2), 640);
      float ho = *hp;
      float v = ng + zz * (ho - ng);
      *hp = v;
      *(f16*)swzp(XA, row, 2 * (16 + e2), 512) = (f16)v;
    }
    {
      int row = tid >> 4, t = tid & 15;
      float ixr = G2[row * 96 + t], ixi = G2[row * 96 + 16 + t], ixn = G2[row * 96 + 32 + t];
      float hhr = G2[row * 96 + 48 + t], hhi = G2[row * 96 + 64 + t], hhn = G2[row * 96 + 80 + t];
      float br = bdvl[t], bi = bdvl[16 + t], bn = bdvl[32 + t];
      float rr = fsigm(br * ixr * hhr);
      float zz = fsigm(bi * ixi * hhi);
      float sp = bn * ixn * rr * hhn;
      float ng = (sp > 20.f) ? sp : __logf(1.f + __expf(sp));
      float* hp = (float*)swzp(hcf, row, 4 * t, 640);
      float v = zz * (*hp) + (1.f - zz) * __logf(ng);
      *hp = v;
      *(f16*)swzp(XA, row, 2 * t, 512) = (f16)v;
    }
    __syncthreads();
  }

  // ---- classifier ----
  if (tid < 80) {
    int row = tid / 5, c = tid - row * 5;
    float a = cbv[c];
    for (int k = 0; k < 136; ++k)
      a += *(const float*)swzp(hcf, row, 4 * k, 640) * cw[k * 5 + c];
    out[(size_t)(blk * 16 + row) * 5 + c] = a;
  }
}

// ------------------------------ launch ------------------------------
extern "C" void kernel_launch(void* const* d_in, const int* in_sizes, int n_in,
                              void* d_out, int out_size, void* d_ws, size_t ws_size,
                              hipStream_t stream) {
  const float* x       = (const float*)d_in[0];
  const float* fw      = (const float*)d_in[1];
  const float* s_tri   = (const float*)d_in[2];
  const float* conv1_w = (const float*)d_in[3];
  const float* conv1_b = (const float*)d_in[4];
  const float* bn1_g   = (const float*)d_in[5];
  const float* bn1_b   = (const float*)d_in[6];
  const float* conv2_w = (const float*)d_in[7];
  const float* conv2_b = (const float*)d_in[8];
  const float* bn2_g   = (const float*)d_in[9];
  const float* bn2_b   = (const float*)d_in[10];
  const float* wx_d    = (const float*)d_in[11];
  const float* wh_d    = (const float*)d_in[12];
  const float* bias_d  = (const float*)d_in[13];
  const float* wx_o    = (const float*)d_in[14];
  const float* wh_o    = (const float*)d_in[15];
  const float* bias_o  = (const float*)d_in[16];
  const float* ode_w0  = (const float*)d_in[17];
  const float* ode_b0  = (const float*)d_in[18];
  const float* ode_w1  = (const float*)d_in[19];
  const float* ode_b1  = (const float*)d_in[20];
  const float* ode_w2  = (const float*)d_in[21];
  const float* ode_b2  = (const float*)d_in[22];
  const float* ode_w3  = (const float*)d_in[23];
  const float* ode_b3  = (const float*)d_in[24];
  const float* cls_w   = (const float*)d_in[25];
  const float* cls_b   = (const float*)d_in[26];

  float* ws = (float*)d_ws;
  float* h1  = ws;                    // 8,908,800 floats (K1->K2), then dead
  float* h3  = ws;                    // 1,075,200 floats (K4->K6)
  float* xd  = ws + 1075200;          // 51,200
  float* xo  = ws + 1126400;          // 384,000
  float* h2  = ws + 8908800;          // 7,680,000 (K2->K4), then reused by K0
  float* p1  = ws + 16588800;         // 614,400
  float* bn1 = ws + 17203200;         // 192
  float* p2  = ws + 17203392;         // 25,600
  float* bn2 = ws + 17228992;         // 32
  uint32_t* pk = (uint32_t*)(ws + 8908800);  // packed W-fragments (dead h2)

  hipLaunchKernelGGL(k1_fb,   dim3(NIMG),   dim3(256), 0, stream, x, fw, s_tri, h1);
  hipLaunchKernelGGL(k2_conv1,dim3(NIMG/2), dim3(256), 0, stream, h1, conv1_w, conv1_b, h2, p1);
  hipLaunchKernelGGL(k3_bn1,  dim3(96),     dim3(256), 0, stream, p1, bn1_g, bn1_b, bn1);
  hipLaunchKernelGGL(k4_conv2,dim3(NIMG/4), dim3(256), 0, stream, h2, conv2_w, conv2_b, bn1, h3, p2);
  hipLaunchKernelGGL(k5_bn2,  dim3(16),     dim3(256), 0, stream, p2, bn2_g, bn2_b, bn2);
  hipLaunchKernelGGL(k6_oas,  dim3(NIMG/4), dim3(256), 0, stream, h3, bn2, xd, xo);
  hipLaunchKernelGGL(k0_pack, dim3((PK2_TOT + 255) / 256), dim3(256), 0, stream,
                     ode_w0, ode_w1, ode_w2, ode_w3, wx_o, wh_o, pk);
  hipLaunchKernelGGL(k7_scan, dim3(4),      dim3(256), 0, stream,
                     xd, xo, wx_d, wh_d, bias_d, bias_o, pk,
                     ode_b0, ode_b1, ode_b2, ode_b3, cls_w, cls_b, (float*)d_out);
}

// Round 13
// 2096.477 us; speedup vs baseline: 1.6112x; 1.6112x over previous
//
#include <hip/hip_runtime.h>
#include <math.h>

// ---------------------------------------------------------------------------
// ODERGRU pipeline for MI355X.
//  K1: einsum -> h1 (3200,96,29)
//  K2: conv1d 96->96 k5 + bias -> h2 + BN partials
//  K3: BN1 reduce   K5: BN2 reduce  (f64 tree)
//  K4: conv1d 96->16 k5 (BN1+lrelu on load) -> h3 + BN2 partials
//  K6: OAS + Cholesky -> x_d, x_o
//  K0: pack ODE/GRU weights f32 -> f16 fragments (MFMA lane order)
//  K7: 4 blocks x 8 waves x 16 rows. R9 structure at 512 threads: 2 N-tiles
//      per wave, af shared, bf0+bf1 issued upfront (~104 live VGPR, fits the
//      128 budget -> ONE L2 latency per phase instead of several at R9's
//      64-VGPR cap). Fragment-linear LDS, fast transcendentals, 18 phases.
// ---------------------------------------------------------------------------

#define BB 64
#define NIMG 3200

typedef _Float16 f16;
typedef _Float16 f16x8 __attribute__((ext_vector_type(8)));
typedef float f32x4 __attribute__((ext_vector_type(4)));

#define HS 164   // hcf row stride (f32)
#define GS 516   // GO row stride (f32)

__device__ __forceinline__ float fsigm(float x) {
  return __fdividef(1.f, 1.f + __expf(-x));
}
__device__ __forceinline__ float ftanh(float x) {
  return 1.f - __fdividef(2.f, __expf(2.f * x) + 1.f);
}

// pk region offsets (u32 units)
#define OFF_W0  0
#define OFF_W1  20480
#define OFF_W2  53248
#define OFF_W3  86016
#define OFF_GRZ 104448
#define OFF_GNX 135168
#define OFF_GNH 143360
#define PK2_TOT 151552

// ------------------------------ K1: filterbank ------------------------------
__global__ __launch_bounds__(256) void k1_fb(const float* __restrict__ x,
                                             const float* __restrict__ fw,
                                             const float* __restrict__ st,
                                             float* __restrict__ h1) {
  __shared__ __align__(16) float ws[129 * 32];
  __shared__ __align__(16) float xs[129 * 32];
  const int tid = threadIdx.x;
  const int n = blockIdx.x;
  const float* xp = x + (size_t)n * 11223;

  for (int i = tid; i < 4128; i += 256) ws[i] = fw[i] * st[i];

  float acc[4][4];
#pragma unroll
  for (int i = 0; i < 4; ++i)
#pragma unroll
    for (int j = 0; j < 4; ++j) acc[i][j] = 0.f;

  const int c = tid / 64;
  const int rem = tid % 64;
  const int m0 = (rem / 8) * 4;
  const int t0 = (rem % 8) * 4;

  for (int fc = 0; fc < 3; ++fc) {
    __syncthreads();
    for (int i = tid; i < 3741; i += 256) {
      int cc = i / 1247;
      int r = i - cc * 1247;
      int f = r / 29;
      int t = r - f * 29;
      xs[(cc * 43 + f) * 32 + t] = xp[cc * 3741 + (fc * 43 + f) * 29 + t];
    }
    for (int i = tid; i < 129; i += 256) {
      xs[i * 32 + 29] = 0.f; xs[i * 32 + 30] = 0.f; xs[i * 32 + 31] = 0.f;
    }
    __syncthreads();
    if (tid < 192) {
      const float* xb = xs + (c * 43) * 32 + t0;
      const float* wb = ws + (fc * 43) * 32 + m0;
      for (int f = 0; f < 43; ++f) {
        float4 xv = *(const float4*)(xb + f * 32);
        float4 wv = *(const float4*)(wb + f * 32);
        float xa[4] = {xv.x, xv.y, xv.z, xv.w};
        float wa[4] = {wv.x, wv.y, wv.z, wv.w};
#pragma unroll
        for (int i = 0; i < 4; ++i)
#pragma unroll
          for (int j = 0; j < 4; ++j) acc[i][j] += wa[i] * xa[j];
      }
    }
  }
  if (tid < 192) {
    const int nt = (t0 == 28) ? 1 : 4;
    for (int i = 0; i < 4; ++i)
      for (int j = 0; j < nt; ++j)
        h1[(size_t)n * 2784 + (size_t)(c * 32 + m0 + i) * 29 + (t0 + j)] = acc[i][j];
  }
}

// ------------------------------ K2: conv1 ------------------------------
__global__ __launch_bounds__(256) void k2_conv1(const float* __restrict__ h1,
                                                const float* __restrict__ w,
                                                const float* __restrict__ bias,
                                                float* __restrict__ h2,
                                                float* __restrict__ part1) {
  __shared__ __align__(16) float ins[2 * 96 * 32];
  __shared__ __align__(16) float wls[96 * 81];
  const int tid = threadIdx.x;
  const int wg = blockIdx.x;

  for (int i = tid; i < 2 * 2784; i += 256) {
    int img = i / 2784;
    int e = i - img * 2784;
    int ci = e / 29;
    int t = e - ci * 29;
    ins[img * 3072 + ci * 32 + t] = h1[(size_t)(wg * 2 + img) * 2784 + e];
  }

  const int img = tid / 96;
  const int co = tid - img * 96;
  float acc[25];
#pragma unroll
  for (int t = 0; t < 25; ++t) acc[t] = 0.f;

  for (int cc = 0; cc < 6; ++cc) {
    __syncthreads();
    for (int i = tid; i < 7680; i += 256) {
      int cw = i / 80;
      int r = i - cw * 80;
      wls[cw * 81 + r] = w[cw * 480 + cc * 80 + r];
    }
    __syncthreads();
    if (tid < 192) {
      for (int ci = 0; ci < 16; ++ci) {
        float xv[29];
#pragma unroll
        for (int j = 0; j < 29; ++j) xv[j] = ins[img * 3072 + (cc * 16 + ci) * 32 + j];
        float wv[5];
#pragma unroll
        for (int d = 0; d < 5; ++d) wv[d] = wls[co * 81 + ci * 5 + d];
#pragma unroll
        for (int t = 0; t < 25; ++t) {
          float s = acc[t];
#pragma unroll
          for (int d = 0; d < 5; ++d) s += xv[t + d] * wv[d];
          acc[t] = s;
        }
      }
    }
  }
  if (tid < 192) {
    const int n = wg * 2 + img;
    const float bval = bias[co];
    float s1 = 0.f, s2 = 0.f;
    for (int t = 0; t < 25; ++t) {
      float v = acc[t] + bval;
      h2[(size_t)n * 2400 + co * 25 + t] = v;
      s1 += v;
      s2 += v * v;
    }
    part1[((size_t)n * 96 + co) * 2 + 0] = s1;
    part1[((size_t)n * 96 + co) * 2 + 1] = s2;
  }
}

// ------------------------------ K3/K5: BN reduce -----------------------------
__global__ __launch_bounds__(256) void k3_bn1(const float* __restrict__ part,
                                              const float* __restrict__ gg,
                                              const float* __restrict__ be,
                                              float* __restrict__ ab) {
  __shared__ double sd[256], sq[256];
  const int c = blockIdx.x;
  const int t = threadIdx.x;
  double s = 0.0, q = 0.0;
  for (int n = t; n < NIMG; n += 256) {
    s += (double)part[((size_t)n * 96 + c) * 2 + 0];
    q += (double)part[((size_t)n * 96 + c) * 2 + 1];
  }
  sd[t] = s; sq[t] = q;
  __syncthreads();
  for (int off = 128; off > 0; off >>= 1) {
    if (t < off) { sd[t] += sd[t + off]; sq[t] += sq[t + off]; }
    __syncthreads();
  }
  if (t == 0) {
    double mu = sd[0] / 80000.0;
    double var = sq[0] / 80000.0 - mu * mu;
    float A = (float)((double)gg[c] / sqrt(var + 1e-5));
    ab[c * 2 + 0] = A;
    ab[c * 2 + 1] = (float)((double)be[c] - mu * (double)A);
  }
}

__global__ __launch_bounds__(256) void k5_bn2(const float* __restrict__ part,
                                              const float* __restrict__ gg,
                                              const float* __restrict__ be,
                                              float* __restrict__ ab) {
  __shared__ double sd[256], sq[256];
  const int c = blockIdx.x;
  const int t = threadIdx.x;
  double s = 0.0, q = 0.0;
  for (int n = t; n < 800; n += 256) {
    s += (double)part[((size_t)n * 16 + c) * 2 + 0];
    q += (double)part[((size_t)n * 16 + c) * 2 + 1];
  }
  sd[t] = s; sq[t] = q;
  __syncthreads();
  for (int off = 128; off > 0; off >>= 1) {
    if (t < off) { sd[t] += sd[t + off]; sq[t] += sq[t + off]; }
    __syncthreads();
  }
  if (t == 0) {
    double mu = sd[0] / 67200.0;
    double var = sq[0] / 67200.0 - mu * mu;
    float A = (float)((double)gg[c] / sqrt(var + 1e-5));
    ab[c * 2 + 0] = A;
    ab[c * 2 + 1] = (float)((double)be[c] - mu * (double)A);
  }
}

// ------------------------------ K4: conv2 ------------------------------
__global__ __launch_bounds__(256) void k4_conv2(const float* __restrict__ h2,
                                                const float* __restrict__ w,
                                                const float* __restrict__ bias,
                                                const float* __restrict__ bn1,
                                                float* __restrict__ h3,
                                                float* __restrict__ part2) {
  __shared__ __align__(16) float ins[4 * 96 * 26];
  __shared__ __align__(16) float wls[16 * 241];
  __shared__ float A1s[96], B1s[96];
  __shared__ float red[16 * 16 * 2];
  const int tid = threadIdx.x;
  const int wg = blockIdx.x;

  if (tid < 96) {
    A1s[tid] = bn1[tid * 2 + 0];
    B1s[tid] = bn1[tid * 2 + 1];
  }
  __syncthreads();
  for (int i = tid; i < 9600; i += 256) {
    int img = i / 2400;
    int e = i - img * 2400;
    int ci = e / 25;
    int t = e - ci * 25;
    float v = h2[(size_t)(wg * 4 + img) * 2400 + e];
    v = A1s[ci] * v + B1s[ci];
    v = (v >= 0.f) ? v : 0.01f * v;
    ins[img * 2496 + ci * 26 + t] = v;
  }
  for (int i = tid; i < 4 * 96; i += 256) ins[(i / 96) * 2496 + (i % 96) * 26 + 25] = 0.f;

  const int img = tid >> 6;
  const int co = (tid >> 2) & 15;
  const int tg = tid & 3;
  const int t0s[4] = {0, 6, 11, 16};
  const int t0 = t0s[tg];
  const int tl = (tg == 0) ? 6 : 5;
  float acc[6] = {0.f, 0.f, 0.f, 0.f, 0.f, 0.f};

  for (int cc = 0; cc < 2; ++cc) {
    __syncthreads();
    for (int i = tid; i < 3840; i += 256) {
      int cw = i / 240;
      int r = i - cw * 240;
      wls[cw * 241 + r] = w[cw * 480 + cc * 240 + r];
    }
    __syncthreads();
    for (int ci = 0; ci < 48; ++ci) {
      float xv[10];
#pragma unroll
      for (int j = 0; j < 10; ++j) xv[j] = ins[img * 2496 + (cc * 48 + ci) * 26 + t0 + j];
      float wv[5];
#pragma unroll
      for (int d = 0; d < 5; ++d) wv[d] = wls[co * 241 + ci * 5 + d];
#pragma unroll
      for (int t = 0; t < 6; ++t) {
        float s = acc[t];
#pragma unroll
        for (int d = 0; d < 5; ++d) s += xv[t + d] * wv[d];
        acc[t] = s;
      }
    }
  }
  const float bval = bias[co];
  float s1 = 0.f, s2 = 0.f;
  const int n = wg * 4 + img;
  for (int t = 0; t < 6; ++t) {
    if (t < tl) {
      float v = acc[t] + bval;
      h3[(size_t)n * 336 + co * 21 + t0 + t] = v;
      s1 += v;
      s2 += v * v;
    }
  }
  red[(co * 16 + img * 4 + tg) * 2 + 0] = s1;
  red[(co * 16 + img * 4 + tg) * 2 + 1] = s2;
  __syncthreads();
  if (tid < 16) {
    float s = 0.f, q = 0.f;
    for (int k = 0; k < 16; ++k) {
      s += red[(tid * 16 + k) * 2 + 0];
      q += red[(tid * 16 + k) * 2 + 1];
    }
    part2[((size_t)wg * 16 + tid) * 2 + 0] = s;
    part2[((size_t)wg * 16 + tid) * 2 + 1] = q;
  }
}

// ------------------------------ K6: OAS + Cholesky ---------------------------
__global__ __launch_bounds__(256) void k6_oas(const float* __restrict__ h3,
                                              const float* __restrict__ bn2,
                                              float* __restrict__ xd,
                                              float* __restrict__ xo) {
  __shared__ float X[4][21 * 17 + 3];
  __shared__ float A[4][16 * 17];
  __shared__ float mcol[4][16];
  const int tid = threadIdx.x;
  const int wid = tid >> 6;
  const int lane = tid & 63;
  const int n = blockIdx.x * 4 + wid;
  const float* hp = h3 + (size_t)n * 336;

  for (int e = lane; e < 336; e += 64) {
    int c = e / 21;
    int t = e - c * 21;
    float v = hp[e];
    v = bn2[c * 2 + 0] * v + bn2[c * 2 + 1];
    v = (v >= 0.f) ? v : 0.01f * v;
    X[wid][t * 17 + c] = v;
  }
  __syncthreads();
  if (lane < 16) {
    float s = 0.f;
    for (int t = 0; t < 21; ++t) s += X[wid][t * 17 + lane];
    mcol[wid][lane] = s * (1.f / 21.f);
  }
  __syncthreads();
  for (int e = lane; e < 336; e += 64) {
    int t = e / 16;
    int c = e - t * 16;
    X[wid][t * 17 + c] -= mcol[wid][c];
  }
  __syncthreads();

  float tr_p = 0.f, al_p = 0.f;
  float ent[3];
  int ei[3], ej[3], ne = 0;
  for (int e = lane; e < 136; e += 64) {
    int i = 0, e2 = e;
    while (e2 >= 16 - i) { e2 -= 16 - i; i++; }
    int j = i + e2;
    float s = 0.f;
    for (int t = 0; t < 21; ++t) s += X[wid][t * 17 + i] * X[wid][t * 17 + j];
    s *= (1.f / 20.f);
    ent[ne] = s; ei[ne] = i; ej[ne] = j; ne++;
    if (i == j) tr_p += s;
    al_p += s * s * ((i == j) ? 1.f : 2.f);
  }
  for (int m = 1; m < 64; m <<= 1) {
    tr_p += __shfl_xor(tr_p, m);
    al_p += __shfl_xor(al_p, m);
  }
  const float mu = tr_p * (1.f / 16.f);
  const float alpha = al_p * (1.f / 256.f);
  const float num = alpha + mu * mu;
  const float den = 22.f * (alpha - mu * mu * (1.f / 16.f));
  const float shr = (den == 0.f) ? 1.f : fminf(num / den, 1.f);
  for (int q = 0; q < ne; ++q) {
    float c = (1.f - shr) * ent[q] + ((ei[q] == ej[q]) ? shr * mu : 0.f);
    A[wid][ei[q] * 17 + ej[q]] = c;
    A[wid][ej[q] * 17 + ei[q]] = c;
  }
  __syncthreads();

  for (int k = 0; k < 16; ++k) {
    float akk = A[wid][k * 17 + k];
    __syncthreads();
    float d = sqrtf(akk);
    float rd = 1.f / d;
    if (lane == k) A[wid][k * 17 + k] = d;
    if (lane > k && lane < 16) A[wid][lane * 17 + k] *= rd;
    __syncthreads();
    if (lane > k && lane < 16) {
      float Lik = A[wid][lane * 17 + k];
      for (int j = k + 1; j <= lane; ++j) A[wid][lane * 17 + j] -= Lik * A[wid][j * 17 + k];
    }
    __syncthreads();
  }
  if (lane < 16) xd[(size_t)n * 16 + lane] = A[wid][lane * 17 + lane];
  for (int p = lane; p < 120; p += 64) {
    int i = 1, p2 = p;
    while (p2 >= i) { p2 -= i; i++; }
    xo[(size_t)n * 120 + p] = A[wid][i * 17 + p2];
  }
}

// ------------------------------ K0: pack W fragments ------------------------
// u32 slot within region: tile=(t*NT+nt), rem: lane=rem/4, word=rem%4.
// col = nt*16 + (lane&15), k = t*32 + 8*(lane>>4) + 2*word (+1).
__global__ __launch_bounds__(256) void k0_pack(const float* __restrict__ w0,
                                               const float* __restrict__ w1,
                                               const float* __restrict__ w2,
                                               const float* __restrict__ w3,
                                               const float* __restrict__ wxo,
                                               const float* __restrict__ who,
                                               uint32_t* __restrict__ dst) {
  int i = blockIdx.x * 256 + threadIdx.x;
  if (i >= PK2_TOT) return;
  int j = i, kind, NT;
  if (j < OFF_W1)       { kind = 0; NT = 16; }
  else if (j < OFF_W2)  { kind = 1; NT = 16; j -= OFF_W1; }
  else if (j < OFF_W3)  { kind = 2; NT = 16; j -= OFF_W2; }
  else if (j < OFF_GRZ) { kind = 3; NT = 9;  j -= OFF_W3; }
  else if (j < OFF_GNX) { kind = 4; NT = 15; j -= OFF_GRZ; }
  else if (j < OFF_GNH) { kind = 5; NT = 8;  j -= OFF_GNX; }
  else                  { kind = 6; NT = 8;  j -= OFF_GNH; }
  const int tile = j >> 8;
  const int rem = j & 255;
  const int l = rem >> 2;
  const int wd = rem & 3;
  const int t = tile / NT;
  const int nt = tile - t * NT;
  const int col = nt * 16 + (l & 15);
  const int kk = t * 32 + 8 * (l >> 4) + 2 * wd;

  float v[2];
#pragma unroll
  for (int q = 0; q < 2; ++q) {
    const int k = kk + q;
    float s = 0.f;
    if (kind == 0)      { if (k < 136) s = w0[k * 256 + col]; }
    else if (kind == 1) { s = w1[k * 256 + col]; }
    else if (kind == 2) { s = w2[k * 256 + col]; }
    else if (kind == 3) { if (col < 136) s = w3[k * 136 + col]; }
    else if (kind == 4) {
      if (k < 120) s = wxo[k * 360 + col];
      else if (k >= 128 && k < 248) s = who[(k - 128) * 360 + col];
    } else if (kind == 5) { if (k < 120 && col < 120) s = wxo[k * 360 + 240 + col]; }
    else                  { if (k < 120 && col < 120) s = who[k * 360 + 240 + col]; }
    v[q] = s;
  }
  union { f16 h[2]; uint32_t u; } cv;
  cv.h[0] = (f16)v[0];
  cv.h[1] = (f16)v[1];
  dst[i] = cv.u;
}

// ------------------------------ K7 helpers ----------------------------------
// X buffers: fragment-linear. uint4 slot index = tile*64 + lane.
// Element (row,k): lane = row + 16*((k>>3)&3), tile = k>>5, f16 pos = k&7.
__device__ __forceinline__ uint4 aread_lin(const f16* X, int t, int l) {
  return ((const uint4*)X)[t * 64 + l];
}
__device__ __forceinline__ void xwrite_frag(f16* X, int row, int col, float v) {
  const int slot = row + 16 * ((col >> 3) & 3);
  const int byte = (((col >> 5) * 64 + slot) << 4) + 2 * (col & 7);
  *(f16*)((char*)X + byte) = (f16)v;
}

union UF { uint4 u; f16x8 h; };

// epilogue dispatch (MODE 0: tanh->Xout; 1: hcf+= & mirror XA; 2: hcf+= &
// col>=16 -> XG(col+112), col<16 -> ehl=exp)
template <int MODE>
__device__ __forceinline__ void epi_do(int nt, f32x4 acc,
                                       const float* __restrict__ bias,
                                       f16* __restrict__ Xout,
                                       float* __restrict__ hcf,
                                       f16* __restrict__ Xnext,
                                       float* __restrict__ ehl,
                                       int m, int g) {
  const int col = nt * 16 + m;
  if (MODE == 0) {
    const float bb = bias[col];
#pragma unroll
    for (int i2 = 0; i2 < 4; ++i2)
      xwrite_frag(Xout, 4 * g + i2, col, ftanh(acc[i2] + bb));
  } else {
    if (col < 136) {
      const float bb = bias[col];
#pragma unroll
      for (int i2 = 0; i2 < 4; ++i2) {
        const int row = 4 * g + i2;
        float v = hcf[row * HS + col] + 0.25f * (acc[i2] + bb);
        hcf[row * HS + col] = v;
        if (MODE == 1) {
          xwrite_frag(Xnext, row, col, v);
        } else {
          if (col >= 16) xwrite_frag(Xnext, row, col + 112, v);
          else ehl[row * 16 + col] = __expf(v);
        }
      }
    }
  }
}

// Two tiles per wave (nt0=w, nt1=w+8 if <NT). All bf issued upfront; af
// shared between tiles; 2 independent MFMA chains.
template <int KT, int NT, int MODE>
__device__ __forceinline__ void mlp_two(const f16* __restrict__ Xin,
                                        const uint4* __restrict__ B,
                                        const float* __restrict__ bias,
                                        f16* __restrict__ Xout,
                                        float* __restrict__ hcf,
                                        f16* __restrict__ Xnext,
                                        float* __restrict__ ehl,
                                        int w, int l) {
  const int m = l & 15;
  const int g = l >> 4;
  const int nt0 = w;
  const int nt1 = w + 8;
  const bool has1 = (nt1 < NT);
  uint4 bf0[KT], bf1[KT];
#pragma unroll
  for (int t = 0; t < KT; ++t) bf0[t] = B[(t * NT + nt0) * 64 + l];
  if (has1) {
#pragma unroll
    for (int t = 0; t < KT; ++t) bf1[t] = B[(t * NT + nt1) * 64 + l];
  }
  uint4 af[KT];
#pragma unroll
  for (int t = 0; t < KT; ++t) af[t] = aread_lin(Xin, t, l);
  f32x4 acc0 = {0.f, 0.f, 0.f, 0.f};
  f32x4 acc1 = {0.f, 0.f, 0.f, 0.f};
#pragma unroll
  for (int t = 0; t < KT; ++t) {
    UF a; a.u = af[t];
    UF b; b.u = bf0[t];
    acc0 = __builtin_amdgcn_mfma_f32_16x16x32_f16(a.h, b.h, acc0, 0, 0, 0);
    if (has1) {
      UF c; c.u = bf1[t];
      acc1 = __builtin_amdgcn_mfma_f32_16x16x32_f16(a.h, c.h, acc1, 0, 0, 0);
    }
  }
  epi_do<MODE>(nt0, acc0, bias, Xout, hcf, Xnext, ehl, m, g);
  if (has1) epi_do<MODE>(nt1, acc1, bias, Xout, hcf, Xnext, ehl, m, g);
}

// Gate: two tiles per wave -> GO (nt1 skipped when >= NT).
template <int KT, int NT>
__device__ __forceinline__ void gate_two(const f16* __restrict__ Xin,
                                         const uint4* __restrict__ B,
                                         float* __restrict__ GO,
                                         int w, int ktoff, int gooff, int l) {
  const int m = l & 15;
  const int g = l >> 4;
  const int nt0 = w;
  const int nt1 = w + 8;
  const bool has1 = (nt1 < NT);
  uint4 bf0[KT], bf1[KT];
#pragma unroll
  for (int t = 0; t < KT; ++t) bf0[t] = B[(t * NT + nt0) * 64 + l];
  if (has1) {
#pragma unroll
    for (int t = 0; t < KT; ++t) bf1[t] = B[(t * NT + nt1) * 64 + l];
  }
  uint4 af[KT];
#pragma unroll
  for (int t = 0; t < KT; ++t) af[t] = aread_lin(Xin, t + ktoff, l);
  f32x4 acc0 = {0.f, 0.f, 0.f, 0.f};
  f32x4 acc1 = {0.f, 0.f, 0.f, 0.f};
#pragma unroll
  for (int t = 0; t < KT; ++t) {
    UF a; a.u = af[t];
    UF b; b.u = bf0[t];
    acc0 = __builtin_amdgcn_mfma_f32_16x16x32_f16(a.h, b.h, acc0, 0, 0, 0);
    if (has1) {
      UF c; c.u = bf1[t];
      acc1 = __builtin_amdgcn_mfma_f32_16x16x32_f16(a.h, c.h, acc1, 0, 0, 0);
    }
  }
  {
    const int col = nt0 * 16 + m;
#pragma unroll
    for (int i2 = 0; i2 < 4; ++i2)
      GO[(4 * g + i2) * GS + gooff + col] = acc0[i2];
  }
  if (has1) {
    const int col = nt1 * 16 + m;
#pragma unroll
    for (int i2 = 0; i2 < 4; ++i2)
      GO[(4 * g + i2) * GS + gooff + col] = acc1[i2];
  }
}

// ------------------------------ K7: scan (8 waves, 2 tiles/wave) ------------
__global__ __launch_bounds__(512, 1) void k7_scan(
    const float* __restrict__ xdv, const float* __restrict__ xov,
    const float* __restrict__ wxd, const float* __restrict__ whd,
    const float* __restrict__ bdv, const float* __restrict__ bov,
    const uint32_t* __restrict__ pk,
    const float* __restrict__ b0, const float* __restrict__ b1,
    const float* __restrict__ b2, const float* __restrict__ b3,
    const float* __restrict__ cw, const float* __restrict__ cbv,
    float* __restrict__ out) {
  __shared__ __align__(16) f16 XA[16 * 256];
  __shared__ __align__(16) f16 XB[16 * 256];
  __shared__ __align__(16) f16 XC[16 * 256];
  __shared__ __align__(16) f16 XG[16 * 256];
  __shared__ __align__(16) float GO[16 * GS];
  __shared__ __align__(16) float hcf[16 * HS];
  __shared__ __align__(16) float xdlv[16 * 16];
  __shared__ __align__(16) float ehl[16 * 16];
  __shared__ __align__(16) float G2[16 * 96];
  __shared__ __align__(16) float wdaT[48 * 16], whaT[48 * 16];
  __shared__ float b0l[256], b1l[256], b2l[256], b3l[144], bovl[360], bdvl[48];

  const int tid = threadIdx.x;   // 0..511
  const int w = tid >> 6;        // wave 0..7
  const int l = tid & 63;
  const int blk = blockIdx.x;

  const uint4* BW0 = (const uint4*)(pk + OFF_W0);
  const uint4* BW1 = (const uint4*)(pk + OFF_W1);
  const uint4* BW2 = (const uint4*)(pk + OFF_W2);
  const uint4* BW3 = (const uint4*)(pk + OFF_W3);
  const uint4* BRZ = (const uint4*)(pk + OFF_GRZ);
  const uint4* BNX = (const uint4*)(pk + OFF_GNX);
  const uint4* BNH = (const uint4*)(pk + OFF_GNH);

  // init LDS constants
  for (int i = tid; i < 768; i += 512) {
    int k = i / 48, c = i - k * 48;
    wdaT[c * 16 + k] = fabsf(wxd[i]);
    whaT[c * 16 + k] = fabsf(whd[i]);
  }
  for (int i = tid; i < 256; i += 512) { b0l[i] = b0[i]; b1l[i] = b1[i]; b2l[i] = b2[i]; }
  if (tid < 144) b3l[tid] = (tid < 136) ? b3[tid] : 0.f;
  if (tid < 360) bovl[tid] = bov[tid];
  if (tid < 48) bdvl[tid] = fabsf(bdv[tid]);
  for (int i = tid; i < 16 * HS; i += 512) hcf[i] = 0.f;
  for (int i = tid; i < 16 * 256; i += 512) { XA[i] = (f16)0.f; XG[i] = (f16)0.f; }
  __syncthreads();

#pragma unroll 1
  for (int s = 0; s < 50; ++s) {
    // ---- ODE: 4 Euler steps; 4 phases each ----
#pragma unroll 1
    for (int e = 0; e < 4; ++e) {
      mlp_two<5, 16, 0>(XA, BW0, b0l, XB, nullptr, nullptr, nullptr, w, l);
      if (e == 0) {
        // prefetch this step's gate inputs into XG (xo part) and xdlv
        for (int i = tid; i < 1920; i += 512) {
          int row = i / 120, c = i - row * 120;
          xwrite_frag(XG, row, c, xov[((size_t)(blk * 16 + row) * 50 + s) * 120 + c]);
        }
        if (tid < 256) {
          int row = tid >> 4, k = tid & 15;
          xdlv[tid] = xdv[((size_t)(blk * 16 + row) * 50 + s) * 16 + k];
        }
      }
      __syncthreads();
      mlp_two<8, 16, 0>(XB, BW1, b1l, XC, nullptr, nullptr, nullptr, w, l);
      __syncthreads();
      mlp_two<8, 16, 0>(XC, BW2, b2l, XB, nullptr, nullptr, nullptr, w, l);
      __syncthreads();
      if (e < 3)
        mlp_two<8, 9, 1>(XB, BW3, b3l, nullptr, hcf, XA, nullptr, w, l);
      else
        mlp_two<8, 9, 2>(XB, BW3, b3l, nullptr, hcf, XG, ehl, w, l);
      __syncthreads();
    }

    // ---- gate matmuls (MFMA) + d-gate dots (VALU), one phase ----
    gate_two<8, 15>(XG, BRZ, GO, w, 0, 0, l);
    gate_two<4, 8>(XG, BNX, GO, w, 0, 256, l);
    gate_two<4, 8>(XG, BNH, GO, w, 4, 384, l);
    for (int i = tid; i < 1536; i += 512) {
      int row = i / 96, c = i - row * 96;
      const float4* sv = (const float4*)((c < 48) ? &xdlv[row * 16] : &ehl[row * 16]);
      const float4* wv = (const float4*)((c < 48) ? &wdaT[c * 16] : &whaT[(c - 48) * 16]);
      float a = 0.f;
#pragma unroll
      for (int q = 0; q < 4; ++q) {
        float4 xq = sv[q], wq = wv[q];
        a += xq.x * wq.x + xq.y * wq.y + xq.z * wq.z + xq.w * wq.w;
      }
      G2[row * 96 + c] = a;
    }
    __syncthreads();

    // ---- state update (writes hcf AND next-step XA) ----
    for (int i = tid; i < 1920; i += 512) {
      int row = i / 120, e2 = i - row * 120;
      float rr = fsigm(GO[row * GS + e2] + bovl[e2]);
      float zz = fsigm(GO[row * GS + 120 + e2] + bovl[120 + e2]);
      float ng = ftanh(GO[row * GS + 256 + e2] + rr * GO[row * GS + 384 + e2] + bovl[240 + e2]);
      float ho = hcf[row * HS + 16 + e2];
      float v = ng + zz * (ho - ng);
      hcf[row * HS + 16 + e2] = v;
      xwrite_frag(XA, row, 16 + e2, v);
    }
    if (tid < 256) {
      int row = tid >> 4, t = tid & 15;
      float ixr = G2[row * 96 + t], ixi = G2[row * 96 + 16 + t], ixn = G2[row * 96 + 32 + t];
      float hhr = G2[row * 96 + 48 + t], hhi = G2[row * 96 + 64 + t], hhn = G2[row * 96 + 80 + t];
      float br = bdvl[t], bi = bdvl[16 + t], bn = bdvl[32 + t];
      float rr = fsigm(br * ixr * hhr);
      float zz = fsigm(bi * ixi * hhi);
      float sp = bn * ixn * rr * hhn;
      float ng = (sp > 20.f) ? sp : __logf(1.f + __expf(sp));
      float ldp = hcf[row * HS + t];
      float v = zz * ldp + (1.f - zz) * __logf(ng);
      hcf[row * HS + t] = v;
      xwrite_frag(XA, row, t, v);
    }
    __syncthreads();
  }

  // ---- classifier ----
  if (tid < 80) {
    int row = tid / 5, c = tid - row * 5;
    float a = cbv[c];
    for (int k = 0; k < 136; ++k) a += hcf[row * HS + k] * cw[k * 5 + c];
    out[(size_t)(blk * 16 + row) * 5 + c] = a;
  }
}

// ------------------------------ launch ------------------------------
extern "C" void kernel_launch(void* const* d_in, const int* in_sizes, int n_in,
                              void* d_out, int out_size, void* d_ws, size_t ws_size,
                              hipStream_t stream) {
  const float* x       = (const float*)d_in[0];
  const float* fw      = (const float*)d_in[1];
  const float* s_tri   = (const float*)d_in[2];
  const float* conv1_w = (const float*)d_in[3];
  const float* conv1_b = (const float*)d_in[4];
  const float* bn1_g   = (const float*)d_in[5];
  const float* bn1_b   = (const float*)d_in[6];
  const float* conv2_w = (const float*)d_in[7];
  const float* conv2_b = (const float*)d_in[8];
  const float* bn2_g   = (const float*)d_in[9];
  const float* bn2_b   = (const float*)d_in[10];
  const float* wx_d    = (const float*)d_in[11];
  const float* wh_d    = (const float*)d_in[12];
  const float* bias_d  = (const float*)d_in[13];
  const float* wx_o    = (const float*)d_in[14];
  const float* wh_o    = (const float*)d_in[15];
  const float* bias_o  = (const float*)d_in[16];
  const float* ode_w0  = (const float*)d_in[17];
  const float* ode_b0  = (const float*)d_in[18];
  const float* ode_w1  = (const float*)d_in[19];
  const float* ode_b1  = (const float*)d_in[20];
  const float* ode_w2  = (const float*)d_in[21];
  const float* ode_b2  = (const float*)d_in[22];
  const float* ode_w3  = (const float*)d_in[23];
  const float* ode_b3  = (const float*)d_in[24];
  const float* cls_w   = (const float*)d_in[25];
  const float* cls_b   = (const float*)d_in[26];

  float* ws = (float*)d_ws;
  float* h1  = ws;                    // 8,908,800 floats (K1->K2), then dead
  float* h3  = ws;                    // 1,075,200 floats (K4->K6)
  float* xd  = ws + 1075200;          // 51,200
  float* xo  = ws + 1126400;          // 384,000
  float* h2  = ws + 8908800;          // 7,680,000 (K2->K4), then reused by K0
  float* p1  = ws + 16588800;         // 614,400
  float* bn1 = ws + 17203200;         // 192
  float* p2  = ws + 17203392;         // 25,600
  float* bn2 = ws + 17228992;         // 32
  uint32_t* pk = (uint32_t*)(ws + 8908800);  // packed W-fragments (dead h2)

  hipLaunchKernelGGL(k1_fb,   dim3(NIMG),   dim3(256), 0, stream, x, fw, s_tri, h1);
  hipLaunchKernelGGL(k2_conv1,dim3(NIMG/2), dim3(256), 0, stream, h1, conv1_w, conv1_b, h2, p1);
  hipLaunchKernelGGL(k3_bn1,  dim3(96),     dim3(256), 0, stream, p1, bn1_g, bn1_b, bn1);
  hipLaunchKernelGGL(k4_conv2,dim3(NIMG/4), dim3(256), 0, stream, h2, conv2_w, conv2_b, bn1, h3, p2);
  hipLaunchKernelGGL(k5_bn2,  dim3(16),     dim3(256), 0, stream, p2, bn2_g, bn2_b, bn2);
  hipLaunchKernelGGL(k6_oas,  dim3(NIMG/4), dim3(256), 0, stream, h3, bn2, xd, xo);
  hipLaunchKernelGGL(k0_pack, dim3((PK2_TOT + 255) / 256), dim3(256), 0, stream,
                     ode_w0, ode_w1, ode_w2, ode_w3, wx_o, wh_o, pk);
  hipLaunchKernelGGL(k7_scan, dim3(4),      dim3(512), 0, stream,
                     xd, xo, wx_d, wh_d, bias_d, bias_o, pk,
                     ode_b0, ode_b1, ode_b2, ode_b3, cls_w, cls_b, (float*)d_out);
}

// Round 14
// 1873.522 us; speedup vs baseline: 1.8029x; 1.1190x over previous
//
#include <hip/hip_runtime.h>
#include <math.h>

// ---------------------------------------------------------------------------
// ODERGRU pipeline for MI355X.
//  K1: einsum -> h1 (3200,96,29)
//  K2: conv1d 96->96 k5 + bias -> h2 + BN partials
//  K3: BN1 reduce   K5: BN2 reduce  (f64 tree)
//  K4: conv1d 96->16 k5 (BN1+lrelu on load) -> h3 + BN2 partials
//  K6: OAS + Cholesky -> x_d, x_o
//  K0: pack ODE/GRU weights f32 -> f16 fragments (MFMA lane order)
//  K7: 4 blocks x 16 waves x 16 rows (R9 best-known structure). One N-tile
//      per wave; bf[8] preloaded (32 VGPR), af read INLINE from LDS inside
//      the MFMA loop (drops live set 64 -> ~45, un-fragments the L2 burst).
//      Fragment-linear LDS, fast transcendentals, 18 phases/step.
// ---------------------------------------------------------------------------

#define BB 64
#define NIMG 3200

typedef _Float16 f16;
typedef _Float16 f16x8 __attribute__((ext_vector_type(8)));
typedef float f32x4 __attribute__((ext_vector_type(4)));

#define HS 164   // hcf row stride (f32)
#define GS 516   // GO row stride (f32)

__device__ __forceinline__ float fsigm(float x) {
  return __fdividef(1.f, 1.f + __expf(-x));
}
__device__ __forceinline__ float ftanh(float x) {
  return 1.f - __fdividef(2.f, __expf(2.f * x) + 1.f);
}

// pk region offsets (u32 units)
#define OFF_W0  0
#define OFF_W1  20480
#define OFF_W2  53248
#define OFF_W3  86016
#define OFF_GRZ 104448
#define OFF_GNX 135168
#define OFF_GNH 143360
#define PK2_TOT 151552

// ------------------------------ K1: filterbank ------------------------------
__global__ __launch_bounds__(256) void k1_fb(const float* __restrict__ x,
                                             const float* __restrict__ fw,
                                             const float* __restrict__ st,
                                             float* __restrict__ h1) {
  __shared__ __align__(16) float ws[129 * 32];
  __shared__ __align__(16) float xs[129 * 32];
  const int tid = threadIdx.x;
  const int n = blockIdx.x;
  const float* xp = x + (size_t)n * 11223;

  for (int i = tid; i < 4128; i += 256) ws[i] = fw[i] * st[i];

  float acc[4][4];
#pragma unroll
  for (int i = 0; i < 4; ++i)
#pragma unroll
    for (int j = 0; j < 4; ++j) acc[i][j] = 0.f;

  const int c = tid / 64;
  const int rem = tid % 64;
  const int m0 = (rem / 8) * 4;
  const int t0 = (rem % 8) * 4;

  for (int fc = 0; fc < 3; ++fc) {
    __syncthreads();
    for (int i = tid; i < 3741; i += 256) {
      int cc = i / 1247;
      int r = i - cc * 1247;
      int f = r / 29;
      int t = r - f * 29;
      xs[(cc * 43 + f) * 32 + t] = xp[cc * 3741 + (fc * 43 + f) * 29 + t];
    }
    for (int i = tid; i < 129; i += 256) {
      xs[i * 32 + 29] = 0.f; xs[i * 32 + 30] = 0.f; xs[i * 32 + 31] = 0.f;
    }
    __syncthreads();
    if (tid < 192) {
      const float* xb = xs + (c * 43) * 32 + t0;
      const float* wb = ws + (fc * 43) * 32 + m0;
      for (int f = 0; f < 43; ++f) {
        float4 xv = *(const float4*)(xb + f * 32);
        float4 wv = *(const float4*)(wb + f * 32);
        float xa[4] = {xv.x, xv.y, xv.z, xv.w};
        float wa[4] = {wv.x, wv.y, wv.z, wv.w};
#pragma unroll
        for (int i = 0; i < 4; ++i)
#pragma unroll
          for (int j = 0; j < 4; ++j) acc[i][j] += wa[i] * xa[j];
      }
    }
  }
  if (tid < 192) {
    const int nt = (t0 == 28) ? 1 : 4;
    for (int i = 0; i < 4; ++i)
      for (int j = 0; j < nt; ++j)
        h1[(size_t)n * 2784 + (size_t)(c * 32 + m0 + i) * 29 + (t0 + j)] = acc[i][j];
  }
}

// ------------------------------ K2: conv1 ------------------------------
__global__ __launch_bounds__(256) void k2_conv1(const float* __restrict__ h1,
                                                const float* __restrict__ w,
                                                const float* __restrict__ bias,
                                                float* __restrict__ h2,
                                                float* __restrict__ part1) {
  __shared__ __align__(16) float ins[2 * 96 * 32];
  __shared__ __align__(16) float wls[96 * 81];
  const int tid = threadIdx.x;
  const int wg = blockIdx.x;

  for (int i = tid; i < 2 * 2784; i += 256) {
    int img = i / 2784;
    int e = i - img * 2784;
    int ci = e / 29;
    int t = e - ci * 29;
    ins[img * 3072 + ci * 32 + t] = h1[(size_t)(wg * 2 + img) * 2784 + e];
  }

  const int img = tid / 96;
  const int co = tid - img * 96;
  float acc[25];
#pragma unroll
  for (int t = 0; t < 25; ++t) acc[t] = 0.f;

  for (int cc = 0; cc < 6; ++cc) {
    __syncthreads();
    for (int i = tid; i < 7680; i += 256) {
      int cw = i / 80;
      int r = i - cw * 80;
      wls[cw * 81 + r] = w[cw * 480 + cc * 80 + r];
    }
    __syncthreads();
    if (tid < 192) {
      for (int ci = 0; ci < 16; ++ci) {
        float xv[29];
#pragma unroll
        for (int j = 0; j < 29; ++j) xv[j] = ins[img * 3072 + (cc * 16 + ci) * 32 + j];
        float wv[5];
#pragma unroll
        for (int d = 0; d < 5; ++d) wv[d] = wls[co * 81 + ci * 5 + d];
#pragma unroll
        for (int t = 0; t < 25; ++t) {
          float s = acc[t];
#pragma unroll
          for (int d = 0; d < 5; ++d) s += xv[t + d] * wv[d];
          acc[t] = s;
        }
      }
    }
  }
  if (tid < 192) {
    const int n = wg * 2 + img;
    const float bval = bias[co];
    float s1 = 0.f, s2 = 0.f;
    for (int t = 0; t < 25; ++t) {
      float v = acc[t] + bval;
      h2[(size_t)n * 2400 + co * 25 + t] = v;
      s1 += v;
      s2 += v * v;
    }
    part1[((size_t)n * 96 + co) * 2 + 0] = s1;
    part1[((size_t)n * 96 + co) * 2 + 1] = s2;
  }
}

// ------------------------------ K3/K5: BN reduce -----------------------------
__global__ __launch_bounds__(256) void k3_bn1(const float* __restrict__ part,
                                              const float* __restrict__ gg,
                                              const float* __restrict__ be,
                                              float* __restrict__ ab) {
  __shared__ double sd[256], sq[256];
  const int c = blockIdx.x;
  const int t = threadIdx.x;
  double s = 0.0, q = 0.0;
  for (int n = t; n < NIMG; n += 256) {
    s += (double)part[((size_t)n * 96 + c) * 2 + 0];
    q += (double)part[((size_t)n * 96 + c) * 2 + 1];
  }
  sd[t] = s; sq[t] = q;
  __syncthreads();
  for (int off = 128; off > 0; off >>= 1) {
    if (t < off) { sd[t] += sd[t + off]; sq[t] += sq[t + off]; }
    __syncthreads();
  }
  if (t == 0) {
    double mu = sd[0] / 80000.0;
    double var = sq[0] / 80000.0 - mu * mu;
    float A = (float)((double)gg[c] / sqrt(var + 1e-5));
    ab[c * 2 + 0] = A;
    ab[c * 2 + 1] = (float)((double)be[c] - mu * (double)A);
  }
}

__global__ __launch_bounds__(256) void k5_bn2(const float* __restrict__ part,
                                              const float* __restrict__ gg,
                                              const float* __restrict__ be,
                                              float* __restrict__ ab) {
  __shared__ double sd[256], sq[256];
  const int c = blockIdx.x;
  const int t = threadIdx.x;
  double s = 0.0, q = 0.0;
  for (int n = t; n < 800; n += 256) {
    s += (double)part[((size_t)n * 16 + c) * 2 + 0];
    q += (double)part[((size_t)n * 16 + c) * 2 + 1];
  }
  sd[t] = s; sq[t] = q;
  __syncthreads();
  for (int off = 128; off > 0; off >>= 1) {
    if (t < off) { sd[t] += sd[t + off]; sq[t] += sq[t + off]; }
    __syncthreads();
  }
  if (t == 0) {
    double mu = sd[0] / 67200.0;
    double var = sq[0] / 67200.0 - mu * mu;
    float A = (float)((double)gg[c] / sqrt(var + 1e-5));
    ab[c * 2 + 0] = A;
    ab[c * 2 + 1] = (float)((double)be[c] - mu * (double)A);
  }
}

// ------------------------------ K4: conv2 ------------------------------
__global__ __launch_bounds__(256) void k4_conv2(const float* __restrict__ h2,
                                                const float* __restrict__ w,
                                                const float* __restrict__ bias,
                                                const float* __restrict__ bn1,
                                                float* __restrict__ h3,
                                                float* __restrict__ part2) {
  __shared__ __align__(16) float ins[4 * 96 * 26];
  __shared__ __align__(16) float wls[16 * 241];
  __shared__ float A1s[96], B1s[96];
  __shared__ float red[16 * 16 * 2];
  const int tid = threadIdx.x;
  const int wg = blockIdx.x;

  if (tid < 96) {
    A1s[tid] = bn1[tid * 2 + 0];
    B1s[tid] = bn1[tid * 2 + 1];
  }
  __syncthreads();
  for (int i = tid; i < 9600; i += 256) {
    int img = i / 2400;
    int e = i - img * 2400;
    int ci = e / 25;
    int t = e - ci * 25;
    float v = h2[(size_t)(wg * 4 + img) * 2400 + e];
    v = A1s[ci] * v + B1s[ci];
    v = (v >= 0.f) ? v : 0.01f * v;
    ins[img * 2496 + ci * 26 + t] = v;
  }
  for (int i = tid; i < 4 * 96; i += 256) ins[(i / 96) * 2496 + (i % 96) * 26 + 25] = 0.f;

  const int img = tid >> 6;
  const int co = (tid >> 2) & 15;
  const int tg = tid & 3;
  const int t0s[4] = {0, 6, 11, 16};
  const int t0 = t0s[tg];
  const int tl = (tg == 0) ? 6 : 5;
  float acc[6] = {0.f, 0.f, 0.f, 0.f, 0.f, 0.f};

  for (int cc = 0; cc < 2; ++cc) {
    __syncthreads();
    for (int i = tid; i < 3840; i += 256) {
      int cw = i / 240;
      int r = i - cw * 240;
      wls[cw * 241 + r] = w[cw * 480 + cc * 240 + r];
    }
    __syncthreads();
    for (int ci = 0; ci < 48; ++ci) {
      float xv[10];
#pragma unroll
      for (int j = 0; j < 10; ++j) xv[j] = ins[img * 2496 + (cc * 48 + ci) * 26 + t0 + j];
      float wv[5];
#pragma unroll
      for (int d = 0; d < 5; ++d) wv[d] = wls[co * 241 + ci * 5 + d];
#pragma unroll
      for (int t = 0; t < 6; ++t) {
        float s = acc[t];
#pragma unroll
        for (int d = 0; d < 5; ++d) s += xv[t + d] * wv[d];
        acc[t] = s;
      }
    }
  }
  const float bval = bias[co];
  float s1 = 0.f, s2 = 0.f;
  const int n = wg * 4 + img;
  for (int t = 0; t < 6; ++t) {
    if (t < tl) {
      float v = acc[t] + bval;
      h3[(size_t)n * 336 + co * 21 + t0 + t] = v;
      s1 += v;
      s2 += v * v;
    }
  }
  red[(co * 16 + img * 4 + tg) * 2 + 0] = s1;
  red[(co * 16 + img * 4 + tg) * 2 + 1] = s2;
  __syncthreads();
  if (tid < 16) {
    float s = 0.f, q = 0.f;
    for (int k = 0; k < 16; ++k) {
      s += red[(tid * 16 + k) * 2 + 0];
      q += red[(tid * 16 + k) * 2 + 1];
    }
    part2[((size_t)wg * 16 + tid) * 2 + 0] = s;
    part2[((size_t)wg * 16 + tid) * 2 + 1] = q;
  }
}

// ------------------------------ K6: OAS + Cholesky ---------------------------
__global__ __launch_bounds__(256) void k6_oas(const float* __restrict__ h3,
                                              const float* __restrict__ bn2,
                                              float* __restrict__ xd,
                                              float* __restrict__ xo) {
  __shared__ float X[4][21 * 17 + 3];
  __shared__ float A[4][16 * 17];
  __shared__ float mcol[4][16];
  const int tid = threadIdx.x;
  const int wid = tid >> 6;
  const int lane = tid & 63;
  const int n = blockIdx.x * 4 + wid;
  const float* hp = h3 + (size_t)n * 336;

  for (int e = lane; e < 336; e += 64) {
    int c = e / 21;
    int t = e - c * 21;
    float v = hp[e];
    v = bn2[c * 2 + 0] * v + bn2[c * 2 + 1];
    v = (v >= 0.f) ? v : 0.01f * v;
    X[wid][t * 17 + c] = v;
  }
  __syncthreads();
  if (lane < 16) {
    float s = 0.f;
    for (int t = 0; t < 21; ++t) s += X[wid][t * 17 + lane];
    mcol[wid][lane] = s * (1.f / 21.f);
  }
  __syncthreads();
  for (int e = lane; e < 336; e += 64) {
    int t = e / 16;
    int c = e - t * 16;
    X[wid][t * 17 + c] -= mcol[wid][c];
  }
  __syncthreads();

  float tr_p = 0.f, al_p = 0.f;
  float ent[3];
  int ei[3], ej[3], ne = 0;
  for (int e = lane; e < 136; e += 64) {
    int i = 0, e2 = e;
    while (e2 >= 16 - i) { e2 -= 16 - i; i++; }
    int j = i + e2;
    float s = 0.f;
    for (int t = 0; t < 21; ++t) s += X[wid][t * 17 + i] * X[wid][t * 17 + j];
    s *= (1.f / 20.f);
    ent[ne] = s; ei[ne] = i; ej[ne] = j; ne++;
    if (i == j) tr_p += s;
    al_p += s * s * ((i == j) ? 1.f : 2.f);
  }
  for (int m = 1; m < 64; m <<= 1) {
    tr_p += __shfl_xor(tr_p, m);
    al_p += __shfl_xor(al_p, m);
  }
  const float mu = tr_p * (1.f / 16.f);
  const float alpha = al_p * (1.f / 256.f);
  const float num = alpha + mu * mu;
  const float den = 22.f * (alpha - mu * mu * (1.f / 16.f));
  const float shr = (den == 0.f) ? 1.f : fminf(num / den, 1.f);
  for (int q = 0; q < ne; ++q) {
    float c = (1.f - shr) * ent[q] + ((ei[q] == ej[q]) ? shr * mu : 0.f);
    A[wid][ei[q] * 17 + ej[q]] = c;
    A[wid][ej[q] * 17 + ei[q]] = c;
  }
  __syncthreads();

  for (int k = 0; k < 16; ++k) {
    float akk = A[wid][k * 17 + k];
    __syncthreads();
    float d = sqrtf(akk);
    float rd = 1.f / d;
    if (lane == k) A[wid][k * 17 + k] = d;
    if (lane > k && lane < 16) A[wid][lane * 17 + k] *= rd;
    __syncthreads();
    if (lane > k && lane < 16) {
      float Lik = A[wid][lane * 17 + k];
      for (int j = k + 1; j <= lane; ++j) A[wid][lane * 17 + j] -= Lik * A[wid][j * 17 + k];
    }
    __syncthreads();
  }
  if (lane < 16) xd[(size_t)n * 16 + lane] = A[wid][lane * 17 + lane];
  for (int p = lane; p < 120; p += 64) {
    int i = 1, p2 = p;
    while (p2 >= i) { p2 -= i; i++; }
    xo[(size_t)n * 120 + p] = A[wid][i * 17 + p2];
  }
}

// ------------------------------ K0: pack W fragments ------------------------
// u32 slot within region: tile=(t*NT+nt), rem: lane=rem/4, word=rem%4.
// col = nt*16 + (lane&15), k = t*32 + 8*(lane>>4) + 2*word (+1).
__global__ __launch_bounds__(256) void k0_pack(const float* __restrict__ w0,
                                               const float* __restrict__ w1,
                                               const float* __restrict__ w2,
                                               const float* __restrict__ w3,
                                               const float* __restrict__ wxo,
                                               const float* __restrict__ who,
                                               uint32_t* __restrict__ dst) {
  int i = blockIdx.x * 256 + threadIdx.x;
  if (i >= PK2_TOT) return;
  int j = i, kind, NT;
  if (j < OFF_W1)       { kind = 0; NT = 16; }
  else if (j < OFF_W2)  { kind = 1; NT = 16; j -= OFF_W1; }
  else if (j < OFF_W3)  { kind = 2; NT = 16; j -= OFF_W2; }
  else if (j < OFF_GRZ) { kind = 3; NT = 9;  j -= OFF_W3; }
  else if (j < OFF_GNX) { kind = 4; NT = 15; j -= OFF_GRZ; }
  else if (j < OFF_GNH) { kind = 5; NT = 8;  j -= OFF_GNX; }
  else                  { kind = 6; NT = 8;  j -= OFF_GNH; }
  const int tile = j >> 8;
  const int rem = j & 255;
  const int l = rem >> 2;
  const int wd = rem & 3;
  const int t = tile / NT;
  const int nt = tile - t * NT;
  const int col = nt * 16 + (l & 15);
  const int kk = t * 32 + 8 * (l >> 4) + 2 * wd;

  float v[2];
#pragma unroll
  for (int q = 0; q < 2; ++q) {
    const int k = kk + q;
    float s = 0.f;
    if (kind == 0)      { if (k < 136) s = w0[k * 256 + col]; }
    else if (kind == 1) { s = w1[k * 256 + col]; }
    else if (kind == 2) { s = w2[k * 256 + col]; }
    else if (kind == 3) { if (col < 136) s = w3[k * 136 + col]; }
    else if (kind == 4) {
      if (k < 120) s = wxo[k * 360 + col];
      else if (k >= 128 && k < 248) s = who[(k - 128) * 360 + col];
    } else if (kind == 5) { if (k < 120 && col < 120) s = wxo[k * 360 + 240 + col]; }
    else                  { if (k < 120 && col < 120) s = who[k * 360 + 240 + col]; }
    v[q] = s;
  }
  union { f16 h[2]; uint32_t u; } cv;
  cv.h[0] = (f16)v[0];
  cv.h[1] = (f16)v[1];
  dst[i] = cv.u;
}

// ------------------------------ K7 helpers ----------------------------------
// X buffers: fragment-linear. uint4 slot index = tile*64 + lane.
// Element (row,k): lane = row + 16*((k>>3)&3), tile = k>>5, f16 pos = k&7.
__device__ __forceinline__ uint4 aread_lin(const f16* X, int t, int l) {
  return ((const uint4*)X)[t * 64 + l];
}
__device__ __forceinline__ void xwrite_frag(f16* X, int row, int col, float v) {
  const int slot = row + 16 * ((col >> 3) & 3);
  const int byte = (((col >> 5) * 64 + slot) << 4) + 2 * (col & 7);
  *(f16*)((char*)X + byte) = (f16)v;
}

union UF { uint4 u; f16x8 h; };

// One tile per wave. bf preloaded (32 VGPR); af read INLINE from LDS inside
// the MFMA loop (live set ~45 < 64-cap -> un-fragmented L2 burst).
// MODE 0: tanh -> Xout.  MODE 1: hcf += 0.25*(.+b), mirror to Xnext(=XA).
// MODE 2: hcf += 0.25*(.+b); col>=16 -> Xnext(=XG) at col+112; col<16 -> ehl.
template <int KT, int NT, int MODE>
__device__ __forceinline__ void mlp_one(const f16* __restrict__ Xin,
                                        const uint4* __restrict__ B,
                                        const float* __restrict__ bias,
                                        f16* __restrict__ Xout,
                                        float* __restrict__ hcf,
                                        f16* __restrict__ Xnext,
                                        float* __restrict__ ehl,
                                        int nt, int l) {
  if (nt < 0 || nt >= NT) return;
  const int m = l & 15;
  const int g = l >> 4;
  uint4 bf[KT];
#pragma unroll
  for (int t = 0; t < KT; ++t) bf[t] = B[(t * NT + nt) * 64 + l];   // global first
  f32x4 acc = {0.f, 0.f, 0.f, 0.f};
#pragma unroll
  for (int t = 0; t < KT; ++t) {
    UF a; a.u = aread_lin(Xin, t, l);   // LDS read inline (low liveness)
    UF b; b.u = bf[t];
    acc = __builtin_amdgcn_mfma_f32_16x16x32_f16(a.h, b.h, acc, 0, 0, 0);
  }
  const int col = nt * 16 + m;
  if (MODE == 0) {
    const float bb = bias[col];
#pragma unroll
    for (int i2 = 0; i2 < 4; ++i2)
      xwrite_frag(Xout, 4 * g + i2, col, ftanh(acc[i2] + bb));
  } else {
    if (col < 136) {
      const float bb = bias[col];
#pragma unroll
      for (int i2 = 0; i2 < 4; ++i2) {
        const int row = 4 * g + i2;
        float v = hcf[row * HS + col] + 0.25f * (acc[i2] + bb);
        hcf[row * HS + col] = v;
        if (MODE == 1) {
          xwrite_frag(Xnext, row, col, v);
        } else {
          if (col >= 16) xwrite_frag(Xnext, row, col + 112, v);
          else ehl[row * 16 + col] = __expf(v);
        }
      }
    }
  }
}

// Streamed gate tile -> GO (af inline from LDS as well).
template <int KT, int NT>
__device__ __forceinline__ void gate_tile(const f16* __restrict__ Xin,
                                          const uint4* __restrict__ B,
                                          float* __restrict__ GO,
                                          int nt, int ktoff, int gooff, int l) {
  if (nt < 0) return;
  const int m = l & 15;
  const int g = l >> 4;
  uint4 bf[KT];
#pragma unroll
  for (int t = 0; t < KT; ++t) bf[t] = B[(t * NT + nt) * 64 + l];
  f32x4 acc = {0.f, 0.f, 0.f, 0.f};
#pragma unroll
  for (int t = 0; t < KT; ++t) {
    UF a; a.u = aread_lin(Xin, t + ktoff, l);
    UF b; b.u = bf[t];
    acc = __builtin_amdgcn_mfma_f32_16x16x32_f16(a.h, b.h, acc, 0, 0, 0);
  }
  const int col = nt * 16 + m;
#pragma unroll
  for (int i2 = 0; i2 < 4; ++i2)
    GO[(4 * g + i2) * GS + gooff + col] = acc[i2];
}

// ------------------------------ K7: scan (16 waves, 1 tile/wave) ------------
__global__ __launch_bounds__(1024, 1) void k7_scan(
    const float* __restrict__ xdv, const float* __restrict__ xov,
    const float* __restrict__ wxd, const float* __restrict__ whd,
    const float* __restrict__ bdv, const float* __restrict__ bov,
    const uint32_t* __restrict__ pk,
    const float* __restrict__ b0, const float* __restrict__ b1,
    const float* __restrict__ b2, const float* __restrict__ b3,
    const float* __restrict__ cw, const float* __restrict__ cbv,
    float* __restrict__ out) {
  __shared__ __align__(16) f16 XA[16 * 256];
  __shared__ __align__(16) f16 XB[16 * 256];
  __shared__ __align__(16) f16 XC[16 * 256];
  __shared__ __align__(16) f16 XG[16 * 256];
  __shared__ __align__(16) float GO[16 * GS];
  __shared__ __align__(16) float hcf[16 * HS];
  __shared__ __align__(16) float xdlv[16 * 16];
  __shared__ __align__(16) float ehl[16 * 16];
  __shared__ __align__(16) float G2[16 * 96];
  __shared__ __align__(16) float wdaT[48 * 16], whaT[48 * 16];
  __shared__ float b0l[256], b1l[256], b2l[256], b3l[144], bovl[360], bdvl[48];

  const int tid = threadIdx.x;
  const int w = tid >> 6;
  const int l = tid & 63;
  const int blk = blockIdx.x;

  const uint4* BW0 = (const uint4*)(pk + OFF_W0);
  const uint4* BW1 = (const uint4*)(pk + OFF_W1);
  const uint4* BW2 = (const uint4*)(pk + OFF_W2);
  const uint4* BW3 = (const uint4*)(pk + OFF_W3);
  const uint4* BRZ = (const uint4*)(pk + OFF_GRZ);
  const uint4* BNX = (const uint4*)(pk + OFF_GNX);
  const uint4* BNH = (const uint4*)(pk + OFF_GNH);

  // init LDS constants
  for (int i = tid; i < 768; i += 1024) {
    int k = i / 48, c = i - k * 48;
    wdaT[c * 16 + k] = fabsf(wxd[i]);
    whaT[c * 16 + k] = fabsf(whd[i]);
  }
  for (int i = tid; i < 256; i += 1024) { b0l[i] = b0[i]; b1l[i] = b1[i]; b2l[i] = b2[i]; }
  if (tid < 144) b3l[tid] = (tid < 136) ? b3[tid] : 0.f;
  if (tid < 360) bovl[tid] = bov[tid];
  if (tid < 48) bdvl[tid] = fabsf(bdv[tid]);
  for (int i = tid; i < 16 * HS; i += 1024) hcf[i] = 0.f;
  for (int i = tid; i < 4096; i += 1024) { XA[i] = (f16)0.f; XG[i] = (f16)0.f; }
  __syncthreads();

#pragma unroll 1
  for (int s = 0; s < 50; ++s) {
    // ---- ODE: 4 Euler steps; 4 phases each ----
#pragma unroll 1
    for (int e = 0; e < 4; ++e) {
      mlp_one<5, 16, 0>(XA, BW0, b0l, XB, nullptr, nullptr, nullptr, w, l);
      if (e == 0) {
        // prefetch this step's gate inputs into XG (xo part) and xdlv
        for (int i = tid; i < 1920; i += 1024) {
          int row = i / 120, c = i - row * 120;
          xwrite_frag(XG, row, c, xov[((size_t)(blk * 16 + row) * 50 + s) * 120 + c]);
        }
        if (tid < 256) {
          int row = tid >> 4, k = tid & 15;
          xdlv[tid] = xdv[((size_t)(blk * 16 + row) * 50 + s) * 16 + k];
        }
      }
      __syncthreads();
      mlp_one<8, 16, 0>(XB, BW1, b1l, XC, nullptr, nullptr, nullptr, w, l);
      __syncthreads();
      mlp_one<8, 16, 0>(XC, BW2, b2l, XB, nullptr, nullptr, nullptr, w, l);
      __syncthreads();
      if (e < 3)
        mlp_one<8, 9, 1>(XB, BW3, b3l, nullptr, hcf, XA, nullptr, w, l);
      else
        mlp_one<8, 9, 2>(XB, BW3, b3l, nullptr, hcf, XG, ehl, w, l);
      __syncthreads();
    }

    // ---- gate matmuls (MFMA) + d-gate dots (VALU), one phase ----
    gate_tile<8, 15>(XG, BRZ, GO, (w < 15) ? w : -1, 0, 0, l);
    gate_tile<4, 8>(XG, BNX, GO, (w < 8) ? w : -1, 0, 256, l);
    gate_tile<4, 8>(XG, BNH, GO, (w >= 8) ? (w - 8) : -1, 4, 384, l);
    for (int i = tid; i < 1536; i += 1024) {
      int row = i / 96, c = i - row * 96;
      const float4* sv = (const float4*)((c < 48) ? &xdlv[row * 16] : &ehl[row * 16]);
      const float4* wv = (const float4*)((c < 48) ? &wdaT[c * 16] : &whaT[(c - 48) * 16]);
      float a = 0.f;
#pragma unroll
      for (int q = 0; q < 4; ++q) {
        float4 xq = sv[q], wq = wv[q];
        a += xq.x * wq.x + xq.y * wq.y + xq.z * wq.z + xq.w * wq.w;
      }
      G2[row * 96 + c] = a;
    }
    __syncthreads();

    // ---- state update (writes hcf AND next-step XA) ----
    for (int i = tid; i < 1920; i += 1024) {
      int row = i / 120, e2 = i - row * 120;
      float rr = fsigm(GO[row * GS + e2] + bovl[e2]);
      float zz = fsigm(GO[row * GS + 120 + e2] + bovl[120 + e2]);
      float ng = ftanh(GO[row * GS + 256 + e2] + rr * GO[row * GS + 384 + e2] + bovl[240 + e2]);
      float ho = hcf[row * HS + 16 + e2];
      float v = ng + zz * (ho - ng);
      hcf[row * HS + 16 + e2] = v;
      xwrite_frag(XA, row, 16 + e2, v);
    }
    if (tid < 256) {
      int row = tid >> 4, t = tid & 15;
      float ixr = G2[row * 96 + t], ixi = G2[row * 96 + 16 + t], ixn = G2[row * 96 + 32 + t];
      float hhr = G2[row * 96 + 48 + t], hhi = G2[row * 96 + 64 + t], hhn = G2[row * 96 + 80 + t];
      float br = bdvl[t], bi = bdvl[16 + t], bn = bdvl[32 + t];
      float rr = fsigm(br * ixr * hhr);
      float zz = fsigm(bi * ixi * hhi);
      float sp = bn * ixn * rr * hhn;
      float ng = (sp > 20.f) ? sp : __logf(1.f + __expf(sp));
      float ldp = hcf[row * HS + t];
      float v = zz * ldp + (1.f - zz) * __logf(ng);
      hcf[row * HS + t] = v;
      xwrite_frag(XA, row, t, v);
    }
    __syncthreads();
  }

  // ---- classifier ----
  if (tid < 80) {
    int row = tid / 5, c = tid - row * 5;
    float a = cbv[c];
    for (int k = 0; k < 136; ++k) a += hcf[row * HS + k] * cw[k * 5 + c];
    out[(size_t)(blk * 16 + row) * 5 + c] = a;
  }
}

// ------------------------------ launch ------------------------------
extern "C" void kernel_launch(void* const* d_in, const int* in_sizes, int n_in,
                              void* d_out, int out_size, void* d_ws, size_t ws_size,
                              hipStream_t stream) {
  const float* x       = (const float*)d_in[0];
  const float* fw      = (const float*)d_in[1];
  const float* s_tri   = (const float*)d_in[2];
  const float* conv1_w = (const float*)d_in[3];
  const float* conv1_b = (const float*)d_in[4];
  const float* bn1_g   = (const float*)d_in[5];
  const float* bn1_b   = (const float*)d_in[6];
  const float* conv2_w = (const float*)d_in[7];
  const float* conv2_b = (const float*)d_in[8];
  const float* bn2_g   = (const float*)d_in[9];
  const float* bn2_b   = (const float*)d_in[10];
  const float* wx_d    = (const float*)d_in[11];
  const float* wh_d    = (const float*)d_in[12];
  const float* bias_d  = (const float*)d_in[13];
  const float* wx_o    = (const float*)d_in[14];
  const float* wh_o    = (const float*)d_in[15];
  const float* bias_o  = (const float*)d_in[16];
  const float* ode_w0  = (const float*)d_in[17];
  const float* ode_b0  = (const float*)d_in[18];
  const float* ode_w1  = (const float*)d_in[19];
  const float* ode_b1  = (const float*)d_in[20];
  const float* ode_w2  = (const float*)d_in[21];
  const float* ode_b2  = (const float*)d_in[22];
  const float* ode_w3  = (const float*)d_in[23];
  const float* ode_b3  = (const float*)d_in[24];
  const float* cls_w   = (const float*)d_in[25];
  const float* cls_b   = (const float*)d_in[26];

  float* ws = (float*)d_ws;
  float* h1  = ws;                    // 8,908,800 floats (K1->K2), then dead
  float* h3  = ws;                    // 1,075,200 floats (K4->K6)
  float* xd  = ws + 1075200;          // 51,200
  float* xo  = ws + 1126400;          // 384,000
  float* h2  = ws + 8908800;          // 7,680,000 (K2->K4), then reused by K0
  float* p1  = ws + 16588800;         // 614,400
  float* bn1 = ws + 17203200;         // 192
  float* p2  = ws + 17203392;         // 25,600
  float* bn2 = ws + 17228992;         // 32
  uint32_t* pk = (uint32_t*)(ws + 8908800);  // packed W-fragments (dead h2)

  hipLaunchKernelGGL(k1_fb,   dim3(NIMG),   dim3(256), 0, stream, x, fw, s_tri, h1);
  hipLaunchKernelGGL(k2_conv1,dim3(NIMG/2), dim3(256), 0, stream, h1, conv1_w, conv1_b, h2, p1);
  hipLaunchKernelGGL(k3_bn1,  dim3(96),     dim3(256), 0, stream, p1, bn1_g, bn1_b, bn1);
  hipLaunchKernelGGL(k4_conv2,dim3(NIMG/4), dim3(256), 0, stream, h2, conv2_w, conv2_b, bn1, h3, p2);
  hipLaunchKernelGGL(k5_bn2,  dim3(16),     dim3(256), 0, stream, p2, bn2_g, bn2_b, bn2);
  hipLaunchKernelGGL(k6_oas,  dim3(NIMG/4), dim3(256), 0, stream, h3, bn2, xd, xo);
  hipLaunchKernelGGL(k0_pack, dim3((PK2_TOT + 255) / 256), dim3(256), 0, stream,
                     ode_w0, ode_w1, ode_w2, ode_w3, wx_o, wh_o, pk);
  hipLaunchKernelGGL(k7_scan, dim3(4),      dim3(1024), 0, stream,
                     xd, xo, wx_d, wh_d, bias_d, bias_o, pk,
                     ode_b0, ode_b1, ode_b2, ode_b3, cls_w, cls_b, (float*)d_out);
}

// Round 15
// 1868.115 us; speedup vs baseline: 1.8081x; 1.0029x over previous
//
#include <hip/hip_runtime.h>
#include <math.h>

// ---------------------------------------------------------------------------
// ODERGRU pipeline for MI355X.
//  K1: einsum -> h1 (3200,96,29)
//  K2: conv1d 96->96 k5 + bias -> h2 + BN partials
//  K3: BN1 reduce   K5: BN2 reduce  (f64 tree)
//  K4: conv1d 96->16 k5 (BN1+lrelu on load) -> h3 + BN2 partials
//  K6: OAS + Cholesky -> x_d, x_o
//  K0: pack ODE/GRU weights f32 -> f16 fragments (MFMA lane order)
//  K7: 4 blocks x 16 waves x 16 rows (R14 best structure) + CROSS-BARRIER
//      ROLLING WEIGHT PREFETCH: persistent bf[8] per wave; each phase
//      consumes current fragments and refills with next phase's (vmcnt
//      drain at barrier completes them "for free"). Live set ~40 < 64-cap.
// ---------------------------------------------------------------------------

#define BB 64
#define NIMG 3200

typedef _Float16 f16;
typedef _Float16 f16x8 __attribute__((ext_vector_type(8)));
typedef float f32x4 __attribute__((ext_vector_type(4)));

#define HS 164   // hcf row stride (f32)
#define GS 516   // GO row stride (f32)

__device__ __forceinline__ float fsigm(float x) {
  return __fdividef(1.f, 1.f + __expf(-x));
}
__device__ __forceinline__ float ftanh(float x) {
  return 1.f - __fdividef(2.f, __expf(2.f * x) + 1.f);
}

// pk region offsets (u32 units)
#define OFF_W0  0
#define OFF_W1  20480
#define OFF_W2  53248
#define OFF_W3  86016
#define OFF_GRZ 104448
#define OFF_GNX 135168
#define OFF_GNH 143360
#define PK2_TOT 151552

// ------------------------------ K1: filterbank ------------------------------
__global__ __launch_bounds__(256) void k1_fb(const float* __restrict__ x,
                                             const float* __restrict__ fw,
                                             const float* __restrict__ st,
                                             float* __restrict__ h1) {
  __shared__ __align__(16) float ws[129 * 32];
  __shared__ __align__(16) float xs[129 * 32];
  const int tid = threadIdx.x;
  const int n = blockIdx.x;
  const float* xp = x + (size_t)n * 11223;

  for (int i = tid; i < 4128; i += 256) ws[i] = fw[i] * st[i];

  float acc[4][4];
#pragma unroll
  for (int i = 0; i < 4; ++i)
#pragma unroll
    for (int j = 0; j < 4; ++j) acc[i][j] = 0.f;

  const int c = tid / 64;
  const int rem = tid % 64;
  const int m0 = (rem / 8) * 4;
  const int t0 = (rem % 8) * 4;

  for (int fc = 0; fc < 3; ++fc) {
    __syncthreads();
    for (int i = tid; i < 3741; i += 256) {
      int cc = i / 1247;
      int r = i - cc * 1247;
      int f = r / 29;
      int t = r - f * 29;
      xs[(cc * 43 + f) * 32 + t] = xp[cc * 3741 + (fc * 43 + f) * 29 + t];
    }
    for (int i = tid; i < 129; i += 256) {
      xs[i * 32 + 29] = 0.f; xs[i * 32 + 30] = 0.f; xs[i * 32 + 31] = 0.f;
    }
    __syncthreads();
    if (tid < 192) {
      const float* xb = xs + (c * 43) * 32 + t0;
      const float* wb = ws + (fc * 43) * 32 + m0;
      for (int f = 0; f < 43; ++f) {
        float4 xv = *(const float4*)(xb + f * 32);
        float4 wv = *(const float4*)(wb + f * 32);
        float xa[4] = {xv.x, xv.y, xv.z, xv.w};
        float wa[4] = {wv.x, wv.y, wv.z, wv.w};
#pragma unroll
        for (int i = 0; i < 4; ++i)
#pragma unroll
          for (int j = 0; j < 4; ++j) acc[i][j] += wa[i] * xa[j];
      }
    }
  }
  if (tid < 192) {
    const int nt = (t0 == 28) ? 1 : 4;
    for (int i = 0; i < 4; ++i)
      for (int j = 0; j < nt; ++j)
        h1[(size_t)n * 2784 + (size_t)(c * 32 + m0 + i) * 29 + (t0 + j)] = acc[i][j];
  }
}

// ------------------------------ K2: conv1 ------------------------------
__global__ __launch_bounds__(256) void k2_conv1(const float* __restrict__ h1,
                                                const float* __restrict__ w,
                                                const float* __restrict__ bias,
                                                float* __restrict__ h2,
                                                float* __restrict__ part1) {
  __shared__ __align__(16) float ins[2 * 96 * 32];
  __shared__ __align__(16) float wls[96 * 81];
  const int tid = threadIdx.x;
  const int wg = blockIdx.x;

  for (int i = tid; i < 2 * 2784; i += 256) {
    int img = i / 2784;
    int e = i - img * 2784;
    int ci = e / 29;
    int t = e - ci * 29;
    ins[img * 3072 + ci * 32 + t] = h1[(size_t)(wg * 2 + img) * 2784 + e];
  }

  const int img = tid / 96;
  const int co = tid - img * 96;
  float acc[25];
#pragma unroll
  for (int t = 0; t < 25; ++t) acc[t] = 0.f;

  for (int cc = 0; cc < 6; ++cc) {
    __syncthreads();
    for (int i = tid; i < 7680; i += 256) {
      int cw = i / 80;
      int r = i - cw * 80;
      wls[cw * 81 + r] = w[cw * 480 + cc * 80 + r];
    }
    __syncthreads();
    if (tid < 192) {
      for (int ci = 0; ci < 16; ++ci) {
        float xv[29];
#pragma unroll
        for (int j = 0; j < 29; ++j) xv[j] = ins[img * 3072 + (cc * 16 + ci) * 32 + j];
        float wv[5];
#pragma unroll
        for (int d = 0; d < 5; ++d) wv[d] = wls[co * 81 + ci * 5 + d];
#pragma unroll
        for (int t = 0; t < 25; ++t) {
          float s = acc[t];
#pragma unroll
          for (int d = 0; d < 5; ++d) s += xv[t + d] * wv[d];
          acc[t] = s;
        }
      }
    }
  }
  if (tid < 192) {
    const int n = wg * 2 + img;
    const float bval = bias[co];
    float s1 = 0.f, s2 = 0.f;
    for (int t = 0; t < 25; ++t) {
      float v = acc[t] + bval;
      h2[(size_t)n * 2400 + co * 25 + t] = v;
      s1 += v;
      s2 += v * v;
    }
    part1[((size_t)n * 96 + co) * 2 + 0] = s1;
    part1[((size_t)n * 96 + co) * 2 + 1] = s2;
  }
}

// ------------------------------ K3/K5: BN reduce -----------------------------
__global__ __launch_bounds__(256) void k3_bn1(const float* __restrict__ part,
                                              const float* __restrict__ gg,
                                              const float* __restrict__ be,
                                              float* __restrict__ ab) {
  __shared__ double sd[256], sq[256];
  const int c = blockIdx.x;
  const int t = threadIdx.x;
  double s = 0.0, q = 0.0;
  for (int n = t; n < NIMG; n += 256) {
    s += (double)part[((size_t)n * 96 + c) * 2 + 0];
    q += (double)part[((size_t)n * 96 + c) * 2 + 1];
  }
  sd[t] = s; sq[t] = q;
  __syncthreads();
  for (int off = 128; off > 0; off >>= 1) {
    if (t < off) { sd[t] += sd[t + off]; sq[t] += sq[t + off]; }
    __syncthreads();
  }
  if (t == 0) {
    double mu = sd[0] / 80000.0;
    double var = sq[0] / 80000.0 - mu * mu;
    float A = (float)((double)gg[c] / sqrt(var + 1e-5));
    ab[c * 2 + 0] = A;
    ab[c * 2 + 1] = (float)((double)be[c] - mu * (double)A);
  }
}

__global__ __launch_bounds__(256) void k5_bn2(const float* __restrict__ part,
                                              const float* __restrict__ gg,
                                              const float* __restrict__ be,
                                              float* __restrict__ ab) {
  __shared__ double sd[256], sq[256];
  const int c = blockIdx.x;
  const int t = threadIdx.x;
  double s = 0.0, q = 0.0;
  for (int n = t; n < 800; n += 256) {
    s += (double)part[((size_t)n * 16 + c) * 2 + 0];
    q += (double)part[((size_t)n * 16 + c) * 2 + 1];
  }
  sd[t] = s; sq[t] = q;
  __syncthreads();
  for (int off = 128; off > 0; off >>= 1) {
    if (t < off) { sd[t] += sd[t + off]; sq[t] += sq[t + off]; }
    __syncthreads();
  }
  if (t == 0) {
    double mu = sd[0] / 67200.0;
    double var = sq[0] / 67200.0 - mu * mu;
    float A = (float)((double)gg[c] / sqrt(var + 1e-5));
    ab[c * 2 + 0] = A;
    ab[c * 2 + 1] = (float)((double)be[c] - mu * (double)A);
  }
}

// ------------------------------ K4: conv2 ------------------------------
__global__ __launch_bounds__(256) void k4_conv2(const float* __restrict__ h2,
                                                const float* __restrict__ w,
                                                const float* __restrict__ bias,
                                                const float* __restrict__ bn1,
                                                float* __restrict__ h3,
                                                float* __restrict__ part2) {
  __shared__ __align__(16) float ins[4 * 96 * 26];
  __shared__ __align__(16) float wls[16 * 241];
  __shared__ float A1s[96], B1s[96];
  __shared__ float red[16 * 16 * 2];
  const int tid = threadIdx.x;
  const int wg = blockIdx.x;

  if (tid < 96) {
    A1s[tid] = bn1[tid * 2 + 0];
    B1s[tid] = bn1[tid * 2 + 1];
  }
  __syncthreads();
  for (int i = tid; i < 9600; i += 256) {
    int img = i / 2400;
    int e = i - img * 2400;
    int ci = e / 25;
    int t = e - ci * 25;
    float v = h2[(size_t)(wg * 4 + img) * 2400 + e];
    v = A1s[ci] * v + B1s[ci];
    v = (v >= 0.f) ? v : 0.01f * v;
    ins[img * 2496 + ci * 26 + t] = v;
  }
  for (int i = tid; i < 4 * 96; i += 256) ins[(i / 96) * 2496 + (i % 96) * 26 + 25] = 0.f;

  const int img = tid >> 6;
  const int co = (tid >> 2) & 15;
  const int tg = tid & 3;
  const int t0s[4] = {0, 6, 11, 16};
  const int t0 = t0s[tg];
  const int tl = (tg == 0) ? 6 : 5;
  float acc[6] = {0.f, 0.f, 0.f, 0.f, 0.f, 0.f};

  for (int cc = 0; cc < 2; ++cc) {
    __syncthreads();
    for (int i = tid; i < 3840; i += 256) {
      int cw = i / 240;
      int r = i - cw * 240;
      wls[cw * 241 + r] = w[cw * 480 + cc * 240 + r];
    }
    __syncthreads();
    for (int ci = 0; ci < 48; ++ci) {
      float xv[10];
#pragma unroll
      for (int j = 0; j < 10; ++j) xv[j] = ins[img * 2496 + (cc * 48 + ci) * 26 + t0 + j];
      float wv[5];
#pragma unroll
      for (int d = 0; d < 5; ++d) wv[d] = wls[co * 241 + ci * 5 + d];
#pragma unroll
      for (int t = 0; t < 6; ++t) {
        float s = acc[t];
#pragma unroll
        for (int d = 0; d < 5; ++d) s += xv[t + d] * wv[d];
        acc[t] = s;
      }
    }
  }
  const float bval = bias[co];
  float s1 = 0.f, s2 = 0.f;
  const int n = wg * 4 + img;
  for (int t = 0; t < 6; ++t) {
    if (t < tl) {
      float v = acc[t] + bval;
      h3[(size_t)n * 336 + co * 21 + t0 + t] = v;
      s1 += v;
      s2 += v * v;
    }
  }
  red[(co * 16 + img * 4 + tg) * 2 + 0] = s1;
  red[(co * 16 + img * 4 + tg) * 2 + 1] = s2;
  __syncthreads();
  if (tid < 16) {
    float s = 0.f, q = 0.f;
    for (int k = 0; k < 16; ++k) {
      s += red[(tid * 16 + k) * 2 + 0];
      q += red[(tid * 16 + k) * 2 + 1];
    }
    part2[((size_t)wg * 16 + tid) * 2 + 0] = s;
    part2[((size_t)wg * 16 + tid) * 2 + 1] = q;
  }
}

// ------------------------------ K6: OAS + Cholesky ---------------------------
__global__ __launch_bounds__(256) void k6_oas(const float* __restrict__ h3,
                                              const float* __restrict__ bn2,
                                              float* __restrict__ xd,
                                              float* __restrict__ xo) {
  __shared__ float X[4][21 * 17 + 3];
  __shared__ float A[4][16 * 17];
  __shared__ float mcol[4][16];
  const int tid = threadIdx.x;
  const int wid = tid >> 6;
  const int lane = tid & 63;
  const int n = blockIdx.x * 4 + wid;
  const float* hp = h3 + (size_t)n * 336;

  for (int e = lane; e < 336; e += 64) {
    int c = e / 21;
    int t = e - c * 21;
    float v = hp[e];
    v = bn2[c * 2 + 0] * v + bn2[c * 2 + 1];
    v = (v >= 0.f) ? v : 0.01f * v;
    X[wid][t * 17 + c] = v;
  }
  __syncthreads();
  if (lane < 16) {
    float s = 0.f;
    for (int t = 0; t < 21; ++t) s += X[wid][t * 17 + lane];
    mcol[wid][lane] = s * (1.f / 21.f);
  }
  __syncthreads();
  for (int e = lane; e < 336; e += 64) {
    int t = e / 16;
    int c = e - t * 16;
    X[wid][t * 17 + c] -= mcol[wid][c];
  }
  __syncthreads();

  float tr_p = 0.f, al_p = 0.f;
  float ent[3];
  int ei[3], ej[3], ne = 0;
  for (int e = lane; e < 136; e += 64) {
    int i = 0, e2 = e;
    while (e2 >= 16 - i) { e2 -= 16 - i; i++; }
    int j = i + e2;
    float s = 0.f;
    for (int t = 0; t < 21; ++t) s += X[wid][t * 17 + i] * X[wid][t * 17 + j];
    s *= (1.f / 20.f);
    ent[ne] = s; ei[ne] = i; ej[ne] = j; ne++;
    if (i == j) tr_p += s;
    al_p += s * s * ((i == j) ? 1.f : 2.f);
  }
  for (int m = 1; m < 64; m <<= 1) {
    tr_p += __shfl_xor(tr_p, m);
    al_p += __shfl_xor(al_p, m);
  }
  const float mu = tr_p * (1.f / 16.f);
  const float alpha = al_p * (1.f / 256.f);
  const float num = alpha + mu * mu;
  const float den = 22.f * (alpha - mu * mu * (1.f / 16.f));
  const float shr = (den == 0.f) ? 1.f : fminf(num / den, 1.f);
  for (int q = 0; q < ne; ++q) {
    float c = (1.f - shr) * ent[q] + ((ei[q] == ej[q]) ? shr * mu : 0.f);
    A[wid][ei[q] * 17 + ej[q]] = c;
    A[wid][ej[q] * 17 + ei[q]] = c;
  }
  __syncthreads();

  for (int k = 0; k < 16; ++k) {
    float akk = A[wid][k * 17 + k];
    __syncthreads();
    float d = sqrtf(akk);
    float rd = 1.f / d;
    if (lane == k) A[wid][k * 17 + k] = d;
    if (lane > k && lane < 16) A[wid][lane * 17 + k] *= rd;
    __syncthreads();
    if (lane > k && lane < 16) {
      float Lik = A[wid][lane * 17 + k];
      for (int j = k + 1; j <= lane; ++j) A[wid][lane * 17 + j] -= Lik * A[wid][j * 17 + k];
    }
    __syncthreads();
  }
  if (lane < 16) xd[(size_t)n * 16 + lane] = A[wid][lane * 17 + lane];
  for (int p = lane; p < 120; p += 64) {
    int i = 1, p2 = p;
    while (p2 >= i) { p2 -= i; i++; }
    xo[(size_t)n * 120 + p] = A[wid][i * 17 + p2];
  }
}

// ------------------------------ K0: pack W fragments ------------------------
// u32 slot within region: tile=(t*NT+nt), rem: lane=rem/4, word=rem%4.
// col = nt*16 + (lane&15), k = t*32 + 8*(lane>>4) + 2*word (+1).
__global__ __launch_bounds__(256) void k0_pack(const float* __restrict__ w0,
                                               const float* __restrict__ w1,
                                               const float* __restrict__ w2,
                                               const float* __restrict__ w3,
                                               const float* __restrict__ wxo,
                                               const float* __restrict__ who,
                                               uint32_t* __restrict__ dst) {
  int i = blockIdx.x * 256 + threadIdx.x;
  if (i >= PK2_TOT) return;
  int j = i, kind, NT;
  if (j < OFF_W1)       { kind = 0; NT = 16; }
  else if (j < OFF_W2)  { kind = 1; NT = 16; j -= OFF_W1; }
  else if (j < OFF_W3)  { kind = 2; NT = 16; j -= OFF_W2; }
  else if (j < OFF_GRZ) { kind = 3; NT = 9;  j -= OFF_W3; }
  else if (j < OFF_GNX) { kind = 4; NT = 15; j -= OFF_GRZ; }
  else if (j < OFF_GNH) { kind = 5; NT = 8;  j -= OFF_GNX; }
  else                  { kind = 6; NT = 8;  j -= OFF_GNH; }
  const int tile = j >> 8;
  const int rem = j & 255;
  const int l = rem >> 2;
  const int wd = rem & 3;
  const int t = tile / NT;
  const int nt = tile - t * NT;
  const int col = nt * 16 + (l & 15);
  const int kk = t * 32 + 8 * (l >> 4) + 2 * wd;

  float v[2];
#pragma unroll
  for (int q = 0; q < 2; ++q) {
    const int k = kk + q;
    float s = 0.f;
    if (kind == 0)      { if (k < 136) s = w0[k * 256 + col]; }
    else if (kind == 1) { s = w1[k * 256 + col]; }
    else if (kind == 2) { s = w2[k * 256 + col]; }
    else if (kind == 3) { if (col < 136) s = w3[k * 136 + col]; }
    else if (kind == 4) {
      if (k < 120) s = wxo[k * 360 + col];
      else if (k >= 128 && k < 248) s = who[(k - 128) * 360 + col];
    } else if (kind == 5) { if (k < 120 && col < 120) s = wxo[k * 360 + 240 + col]; }
    else                  { if (k < 120 && col < 120) s = who[k * 360 + 240 + col]; }
    v[q] = s;
  }
  union { f16 h[2]; uint32_t u; } cv;
  cv.h[0] = (f16)v[0];
  cv.h[1] = (f16)v[1];
  dst[i] = cv.u;
}

// ------------------------------ K7 helpers ----------------------------------
// X buffers: fragment-linear. uint4 slot index = tile*64 + lane.
// Element (row,k): lane = row + 16*((k>>3)&3), tile = k>>5, f16 pos = k&7.
__device__ __forceinline__ uint4 aread_lin(const f16* X, int t, int l) {
  return ((const uint4*)X)[t * 64 + l];
}
__device__ __forceinline__ void xwrite_frag(f16* X, int row, int col, float v) {
  const int slot = row + 16 * ((col >> 3) & 3);
  const int byte = (((col >> 5) * 64 + slot) << 4) + 2 * (col & 7);
  *(f16*)((char*)X + byte) = (f16)v;
}

union UF { uint4 u; f16x8 h; };

// MLP phase with cross-barrier rolling prefetch: consumes persistent bf
// (current phase's fragments, preloaded by the PREVIOUS phase) and refills
// bf[t<nkt2] with B2's fragments for tile nt2 (next phase). nt2<0 => keep.
// MODE 0: tanh -> Xout.  MODE 1: hcf += 0.25*(.+b), mirror to Xnext(=XA).
// MODE 2: hcf += 0.25*(.+b); col>=16 -> Xnext(=XG) at col+112; col<16 -> ehl.
template <int KT, int NT, int MODE>
__device__ __forceinline__ void mlp_pf(const f16* __restrict__ Xin,
                                       const float* __restrict__ bias,
                                       f16* __restrict__ Xout,
                                       float* __restrict__ hcf,
                                       f16* __restrict__ Xnext,
                                       float* __restrict__ ehl,
                                       int nt, int l,
                                       uint4 (&bf)[8],
                                       const uint4* __restrict__ B2,
                                       int NT2, int nt2, int nkt2) {
  const int m = l & 15;
  const int g = l >> 4;
  const bool act = (nt >= 0 && nt < NT);
  f32x4 acc = {0.f, 0.f, 0.f, 0.f};
#pragma unroll
  for (int t = 0; t < 8; ++t) {
    if (t < KT && act) {
      UF a; a.u = aread_lin(Xin, t, l);
      UF b; b.u = bf[t];
      acc = __builtin_amdgcn_mfma_f32_16x16x32_f16(a.h, b.h, acc, 0, 0, 0);
    }
    if (nt2 >= 0 && t < nkt2) bf[t] = B2[(t * NT2 + nt2) * 64 + l];
  }
  if (!act) return;
  const int col = nt * 16 + m;
  if (MODE == 0) {
    const float bb = bias[col];
#pragma unroll
    for (int i2 = 0; i2 < 4; ++i2)
      xwrite_frag(Xout, 4 * g + i2, col, ftanh(acc[i2] + bb));
  } else {
    if (col < 136) {
      const float bb = bias[col];
#pragma unroll
      for (int i2 = 0; i2 < 4; ++i2) {
        const int row = 4 * g + i2;
        float v = hcf[row * HS + col] + 0.25f * (acc[i2] + bb);
        hcf[row * HS + col] = v;
        if (MODE == 1) {
          xwrite_frag(Xnext, row, col, v);
        } else {
          if (col >= 16) xwrite_frag(Xnext, row, col + 112, v);
          else ehl[row * 16 + col] = __expf(v);
        }
      }
    }
  }
}

// Gate RZ: consumes persistent bf (prefetched at L2/L3 of e==3), no refill.
template <int KT, int NT>
__device__ __forceinline__ void gate_rz(const f16* __restrict__ Xin,
                                        float* __restrict__ GO,
                                        int nt, int gooff, int l,
                                        uint4 (&bf)[8]) {
  if (nt < 0) return;
  const int m = l & 15;
  const int g = l >> 4;
  f32x4 acc = {0.f, 0.f, 0.f, 0.f};
#pragma unroll
  for (int t = 0; t < KT; ++t) {
    UF a; a.u = aread_lin(Xin, t, l);
    UF b; b.u = bf[t];
    acc = __builtin_amdgcn_mfma_f32_16x16x32_f16(a.h, b.h, acc, 0, 0, 0);
  }
  const int col = nt * 16 + m;
#pragma unroll
  for (int i2 = 0; i2 < 4; ++i2)
    GO[(4 * g + i2) * GS + gooff + col] = acc[i2];
}

// Self-loading gate tile (NX/NH, small KT).
template <int KT, int NT>
__device__ __forceinline__ void gate_tile(const f16* __restrict__ Xin,
                                          const uint4* __restrict__ B,
                                          float* __restrict__ GO,
                                          int nt, int ktoff, int gooff, int l) {
  if (nt < 0) return;
  const int m = l & 15;
  const int g = l >> 4;
  uint4 bfx[KT];
#pragma unroll
  for (int t = 0; t < KT; ++t) bfx[t] = B[(t * NT + nt) * 64 + l];
  f32x4 acc = {0.f, 0.f, 0.f, 0.f};
#pragma unroll
  for (int t = 0; t < KT; ++t) {
    UF a; a.u = aread_lin(Xin, t + ktoff, l);
    UF b; b.u = bfx[t];
    acc = __builtin_amdgcn_mfma_f32_16x16x32_f16(a.h, b.h, acc, 0, 0, 0);
  }
  const int col = nt * 16 + m;
#pragma unroll
  for (int i2 = 0; i2 < 4; ++i2)
    GO[(4 * g + i2) * GS + gooff + col] = acc[i2];
}

// ------------------------------ K7: scan (16 waves, rolling prefetch) -------
__global__ __launch_bounds__(1024, 1) void k7_scan(
    const float* __restrict__ xdv, const float* __restrict__ xov,
    const float* __restrict__ wxd, const float* __restrict__ whd,
    const float* __restrict__ bdv, const float* __restrict__ bov,
    const uint32_t* __restrict__ pk,
    const float* __restrict__ b0, const float* __restrict__ b1,
    const float* __restrict__ b2, const float* __restrict__ b3,
    const float* __restrict__ cw, const float* __restrict__ cbv,
    float* __restrict__ out) {
  __shared__ __align__(16) f16 XA[16 * 256];
  __shared__ __align__(16) f16 XB[16 * 256];
  __shared__ __align__(16) f16 XC[16 * 256];
  __shared__ __align__(16) f16 XG[16 * 256];
  __shared__ __align__(16) float GO[16 * GS];
  __shared__ __align__(16) float hcf[16 * HS];
  __shared__ __align__(16) float xdlv[16 * 16];
  __shared__ __align__(16) float ehl[16 * 16];
  __shared__ __align__(16) float G2[16 * 96];
  __shared__ __align__(16) float wdaT[48 * 16], whaT[48 * 16];
  __shared__ float b0l[256], b1l[256], b2l[256], b3l[144], bovl[360], bdvl[48];

  const int tid = threadIdx.x;
  const int w = tid >> 6;
  const int l = tid & 63;
  const int blk = blockIdx.x;

  const uint4* BW0 = (const uint4*)(pk + OFF_W0);
  const uint4* BW1 = (const uint4*)(pk + OFF_W1);
  const uint4* BW2 = (const uint4*)(pk + OFF_W2);
  const uint4* BW3 = (const uint4*)(pk + OFF_W3);
  const uint4* BRZ = (const uint4*)(pk + OFF_GRZ);
  const uint4* BNX = (const uint4*)(pk + OFF_GNX);
  const uint4* BNH = (const uint4*)(pk + OFF_GNH);

  // init LDS constants
  for (int i = tid; i < 768; i += 1024) {
    int k = i / 48, c = i - k * 48;
    wdaT[c * 16 + k] = fabsf(wxd[i]);
    whaT[c * 16 + k] = fabsf(whd[i]);
  }
  for (int i = tid; i < 256; i += 1024) { b0l[i] = b0[i]; b1l[i] = b1[i]; b2l[i] = b2[i]; }
  if (tid < 144) b3l[tid] = (tid < 136) ? b3[tid] : 0.f;
  if (tid < 360) bovl[tid] = bov[tid];
  if (tid < 48) bdvl[tid] = fabsf(bdv[tid]);
  for (int i = tid; i < 16 * HS; i += 1024) hcf[i] = 0.f;
  for (int i = tid; i < 4096; i += 1024) { XA[i] = (f16)0.f; XG[i] = (f16)0.f; }

  // persistent weight fragments; preload e0-L0 (BW0, tile w)
  uint4 bf[8];
#pragma unroll
  for (int t = 0; t < 5; ++t) bf[t] = BW0[(t * 16 + w) * 64 + l];
  __syncthreads();

#pragma unroll 1
  for (int s = 0; s < 50; ++s) {
    // ---- ODE: 4 Euler steps; 4 phases each ----
#pragma unroll 1
    for (int e = 0; e < 4; ++e) {
      // L0: consume BW0, prefetch BW1
      mlp_pf<5, 16, 0>(XA, b0l, XB, nullptr, nullptr, nullptr, w, l, bf, BW1, 16, w, 8);
      if (e == 0) {
        for (int i = tid; i < 1920; i += 1024) {
          int row = i / 120, c = i - row * 120;
          xwrite_frag(XG, row, c, xov[((size_t)(blk * 16 + row) * 50 + s) * 120 + c]);
        }
        if (tid < 256) {
          int row = tid >> 4, k = tid & 15;
          xdlv[tid] = xdv[((size_t)(blk * 16 + row) * 50 + s) * 16 + k];
        }
      }
      __syncthreads();
      // L1: consume BW1, prefetch BW2
      mlp_pf<8, 16, 0>(XB, b1l, XC, nullptr, nullptr, nullptr, w, l, bf, BW2, 16, w, 8);
      __syncthreads();
      // L2: consume BW2, prefetch per-wave next (BW3 | BW0 | BRZ)
      {
        const uint4* nb; int nNT, nnt, nk;
        if (w < 9)       { nb = BW3; nNT = 9;  nnt = w;                  nk = 8; }
        else if (e == 3) { nb = BRZ; nNT = 15; nnt = (w < 15) ? w : -1;  nk = 8; }
        else             { nb = BW0; nNT = 16; nnt = w;                  nk = 5; }
        mlp_pf<8, 16, 0>(XC, b2l, XB, nullptr, nullptr, nullptr, w, l, bf, nb, nNT, nnt, nk);
      }
      __syncthreads();
      // L3: consume BW3 (w<9), prefetch (BW0 | BRZ) for active waves
      {
        const uint4* nb = (e == 3) ? BRZ : BW0;
        const int nNT = (e == 3) ? 15 : 16;
        const int nnt = (w < 9) ? w : -1;   // idle waves keep their L2 prefetch
        const int nk = (e == 3) ? 8 : 5;
        if (e < 3)
          mlp_pf<8, 9, 1>(XB, b3l, nullptr, hcf, XA, nullptr, (w < 9) ? w : -1, l, bf, nb, nNT, nnt, nk);
        else
          mlp_pf<8, 9, 2>(XB, b3l, nullptr, hcf, XG, ehl, (w < 9) ? w : -1, l, bf, nb, nNT, nnt, nk);
      }
      __syncthreads();
    }

    // ---- gate matmuls (RZ consumes persistent bf) + d-gate dots ----
    gate_rz<8, 15>(XG, GO, (w < 15) ? w : -1, 0, l, bf);
    gate_tile<4, 8>(XG, BNX, GO, (w < 8) ? w : -1, 0, 256, l);
    gate_tile<4, 8>(XG, BNH, GO, (w >= 8) ? (w - 8) : -1, 4, 384, l);
    for (int i = tid; i < 1536; i += 1024) {
      int row = i / 96, c = i - row * 96;
      const float4* sv = (const float4*)((c < 48) ? &xdlv[row * 16] : &ehl[row * 16]);
      const float4* wv = (const float4*)((c < 48) ? &wdaT[c * 16] : &whaT[(c - 48) * 16]);
      float a = 0.f;
#pragma unroll
      for (int q = 0; q < 4; ++q) {
        float4 xq = sv[q], wq = wv[q];
        a += xq.x * wq.x + xq.y * wq.y + xq.z * wq.z + xq.w * wq.w;
      }
      G2[row * 96 + c] = a;
    }
    __syncthreads();

    // ---- state update (prefetch next step's BW0 first, loads overlap VALU) --
#pragma unroll
    for (int t = 0; t < 5; ++t) bf[t] = BW0[(t * 16 + w) * 64 + l];
    for (int i = tid; i < 1920; i += 1024) {
      int row = i / 120, e2 = i - row * 120;
      float rr = fsigm(GO[row * GS + e2] + bovl[e2]);
      float zz = fsigm(GO[row * GS + 120 + e2] + bovl[120 + e2]);
      float ng = ftanh(GO[row * GS + 256 + e2] + rr * GO[row * GS + 384 + e2] + bovl[240 + e2]);
      float ho = hcf[row * HS + 16 + e2];
      float v = ng + zz * (ho - ng);
      hcf[row * HS + 16 + e2] = v;
      xwrite_frag(XA, row, 16 + e2, v);
    }
    if (tid < 256) {
      int row = tid >> 4, t = tid & 15;
      float ixr = G2[row * 96 + t], ixi = G2[row * 96 + 16 + t], ixn = G2[row * 96 + 32 + t];
      float hhr = G2[row * 96 + 48 + t], hhi = G2[row * 96 + 64 + t], hhn = G2[row * 96 + 80 + t];
      float br = bdvl[t], bi = bdvl[16 + t], bn = bdvl[32 + t];
      float rr = fsigm(br * ixr * hhr);
      float zz = fsigm(bi * ixi * hhi);
      float sp = bn * ixn * rr * hhn;
      float ng = (sp > 20.f) ? sp : __logf(1.f + __expf(sp));
      float ldp = hcf[row * HS + t];
      float v = zz * ldp + (1.f - zz) * __logf(ng);
      hcf[row * HS + t] = v;
      xwrite_frag(XA, row, t, v);
    }
    __syncthreads();
  }

  // ---- classifier ----
  if (tid < 80) {
    int row = tid / 5, c = tid - row * 5;
    float a = cbv[c];
    for (int k = 0; k < 136; ++k) a += hcf[row * HS + k] * cw[k * 5 + c];
    out[(size_t)(blk * 16 + row) * 5 + c] = a;
  }
}

// ------------------------------ launch ------------------------------
extern "C" void kernel_launch(void* const* d_in, const int* in_sizes, int n_in,
                              void* d_out, int out_size, void* d_ws, size_t ws_size,
                              hipStream_t stream) {
  const float* x       = (const float*)d_in[0];
  const float* fw      = (const float*)d_in[1];
  const float* s_tri   = (const float*)d_in[2];
  const float* conv1_w = (const float*)d_in[3];
  const float* conv1_b = (const float*)d_in[4];
  const float* bn1_g   = (const float*)d_in[5];
  const float* bn1_b   = (const float*)d_in[6];
  const float* conv2_w = (const float*)d_in[7];
  const float* conv2_b = (const float*)d_in[8];
  const float* bn2_g   = (const float*)d_in[9];
  const float* bn2_b   = (const float*)d_in[10];
  const float* wx_d    = (const float*)d_in[11];
  const float* wh_d    = (const float*)d_in[12];
  const float* bias_d  = (const float*)d_in[13];
  const float* wx_o    = (const float*)d_in[14];
  const float* wh_o    = (const float*)d_in[15];
  const float* bias_o  = (const float*)d_in[16];
  const float* ode_w0  = (const float*)d_in[17];
  const float* ode_b0  = (const float*)d_in[18];
  const float* ode_w1  = (const float*)d_in[19];
  const float* ode_b1  = (const float*)d_in[20];
  const float* ode_w2  = (const float*)d_in[21];
  const float* ode_b2  = (const float*)d_in[22];
  const float* ode_w3  = (const float*)d_in[23];
  const float* ode_b3  = (const float*)d_in[24];
  const float* cls_w   = (const float*)d_in[25];
  const float* cls_b   = (const float*)d_in[26];

  float* ws = (float*)d_ws;
  float* h1  = ws;                    // 8,908,800 floats (K1->K2), then dead
  float* h3  = ws;                    // 1,075,200 floats (K4->K6)
  float* xd  = ws + 1075200;          // 51,200
  float* xo  = ws + 1126400;          // 384,000
  float* h2  = ws + 8908800;          // 7,680,000 (K2->K4), then reused by K0
  float* p1  = ws + 16588800;         // 614,400
  float* bn1 = ws + 17203200;         // 192
  float* p2  = ws + 17203392;         // 25,600
  float* bn2 = ws + 17228992;         // 32
  uint32_t* pk = (uint32_t*)(ws + 8908800);  // packed W-fragments (dead h2)

  hipLaunchKernelGGL(k1_fb,   dim3(NIMG),   dim3(256), 0, stream, x, fw, s_tri, h1);
  hipLaunchKernelGGL(k2_conv1,dim3(NIMG/2), dim3(256), 0, stream, h1, conv1_w, conv1_b, h2, p1);
  hipLaunchKernelGGL(k3_bn1,  dim3(96),     dim3(256), 0, stream, p1, bn1_g, bn1_b, bn1);
  hipLaunchKernelGGL(k4_conv2,dim3(NIMG/4), dim3(256), 0, stream, h2, conv2_w, conv2_b, bn1, h3, p2);
  hipLaunchKernelGGL(k5_bn2,  dim3(16),     dim3(256), 0, stream, p2, bn2_g, bn2_b, bn2);
  hipLaunchKernelGGL(k6_oas,  dim3(NIMG/4), dim3(256), 0, stream, h3, bn2, xd, xo);
  hipLaunchKernelGGL(k0_pack, dim3((PK2_TOT + 255) / 256), dim3(256), 0, stream,
                     ode_w0, ode_w1, ode_w2, ode_w3, wx_o, wh_o, pk);
  hipLaunchKernelGGL(k7_scan, dim3(4),      dim3(1024), 0, stream,
                     xd, xo, wx_d, wh_d, bias_d, bias_o, pk,
                     ode_b0, ode_b1, ode_b2, ode_b3, cls_w, cls_b, (float*)d_out);
}

// Round 16
// 1552.472 us; speedup vs baseline: 2.1757x; 1.2033x over previous
//
#include <hip/hip_runtime.h>
#include <math.h>

// ---------------------------------------------------------------------------
// ODERGRU pipeline for MI355X.
//  K1: einsum -> h1 (3200,96,29)
//  K2: conv1d 96->96 k5 + bias -> h2 + BN partials
//  K3: BN1 reduce   K5: BN2 reduce  (f64 tree)
//  K4: conv1d 96->16 k5 (BN1+lrelu on load) -> h3 + BN2 partials
//  K6: OAS + Cholesky -> x_d, x_o
//  K0: pack ODE/GRU weights f32 -> f16 fragments (MFMA lane order)
//  K7: 4 blocks x 16 waves x 16 rows + rolling prefetch. NEW: W3 RESIDENT IN
//      LDS (73.7KB; consumed 4x/step -> saves 295KB/step = 16% of L2 draw;
//      L3 phase has zero global loads). XC eliminated (L1 writes XA in
//      place) to free the LDS. Total LDS 158KB <= 160KB.
// ---------------------------------------------------------------------------

#define BB 64
#define NIMG 3200

typedef _Float16 f16;
typedef _Float16 f16x8 __attribute__((ext_vector_type(8)));
typedef float f32x4 __attribute__((ext_vector_type(4)));

#define HS 164   // hcf row stride (f32)
#define GS 516   // GO row stride (f32)

__device__ __forceinline__ float fsigm(float x) {
  return __fdividef(1.f, 1.f + __expf(-x));
}
__device__ __forceinline__ float ftanh(float x) {
  return 1.f - __fdividef(2.f, __expf(2.f * x) + 1.f);
}

// pk region offsets (u32 units)
#define OFF_W0  0
#define OFF_W1  20480
#define OFF_W2  53248
#define OFF_W3  86016
#define OFF_GRZ 104448
#define OFF_GNX 135168
#define OFF_GNH 143360
#define PK2_TOT 151552

// ------------------------------ K1: filterbank ------------------------------
__global__ __launch_bounds__(256) void k1_fb(const float* __restrict__ x,
                                             const float* __restrict__ fw,
                                             const float* __restrict__ st,
                                             float* __restrict__ h1) {
  __shared__ __align__(16) float ws[129 * 32];
  __shared__ __align__(16) float xs[129 * 32];
  const int tid = threadIdx.x;
  const int n = blockIdx.x;
  const float* xp = x + (size_t)n * 11223;

  for (int i = tid; i < 4128; i += 256) ws[i] = fw[i] * st[i];

  float acc[4][4];
#pragma unroll
  for (int i = 0; i < 4; ++i)
#pragma unroll
    for (int j = 0; j < 4; ++j) acc[i][j] = 0.f;

  const int c = tid / 64;
  const int rem = tid % 64;
  const int m0 = (rem / 8) * 4;
  const int t0 = (rem % 8) * 4;

  for (int fc = 0; fc < 3; ++fc) {
    __syncthreads();
    for (int i = tid; i < 3741; i += 256) {
      int cc = i / 1247;
      int r = i - cc * 1247;
      int f = r / 29;
      int t = r - f * 29;
      xs[(cc * 43 + f) * 32 + t] = xp[cc * 3741 + (fc * 43 + f) * 29 + t];
    }
    for (int i = tid; i < 129; i += 256) {
      xs[i * 32 + 29] = 0.f; xs[i * 32 + 30] = 0.f; xs[i * 32 + 31] = 0.f;
    }
    __syncthreads();
    if (tid < 192) {
      const float* xb = xs + (c * 43) * 32 + t0;
      const float* wb = ws + (fc * 43) * 32 + m0;
      for (int f = 0; f < 43; ++f) {
        float4 xv = *(const float4*)(xb + f * 32);
        float4 wv = *(const float4*)(wb + f * 32);
        float xa[4] = {xv.x, xv.y, xv.z, xv.w};
        float wa[4] = {wv.x, wv.y, wv.z, wv.w};
#pragma unroll
        for (int i = 0; i < 4; ++i)
#pragma unroll
          for (int j = 0; j < 4; ++j) acc[i][j] += wa[i] * xa[j];
      }
    }
  }
  if (tid < 192) {
    const int nt = (t0 == 28) ? 1 : 4;
    for (int i = 0; i < 4; ++i)
      for (int j = 0; j < nt; ++j)
        h1[(size_t)n * 2784 + (size_t)(c * 32 + m0 + i) * 29 + (t0 + j)] = acc[i][j];
  }
}

// ------------------------------ K2: conv1 ------------------------------
__global__ __launch_bounds__(256) void k2_conv1(const float* __restrict__ h1,
                                                const float* __restrict__ w,
                                                const float* __restrict__ bias,
                                                float* __restrict__ h2,
                                                float* __restrict__ part1) {
  __shared__ __align__(16) float ins[2 * 96 * 32];
  __shared__ __align__(16) float wls[96 * 81];
  const int tid = threadIdx.x;
  const int wg = blockIdx.x;

  for (int i = tid; i < 2 * 2784; i += 256) {
    int img = i / 2784;
    int e = i - img * 2784;
    int ci = e / 29;
    int t = e - ci * 29;
    ins[img * 3072 + ci * 32 + t] = h1[(size_t)(wg * 2 + img) * 2784 + e];
  }

  const int img = tid / 96;
  const int co = tid - img * 96;
  float acc[25];
#pragma unroll
  for (int t = 0; t < 25; ++t) acc[t] = 0.f;

  for (int cc = 0; cc < 6; ++cc) {
    __syncthreads();
    for (int i = tid; i < 7680; i += 256) {
      int cw = i / 80;
      int r = i - cw * 80;
      wls[cw * 81 + r] = w[cw * 480 + cc * 80 + r];
    }
    __syncthreads();
    if (tid < 192) {
      for (int ci = 0; ci < 16; ++ci) {
        float xv[29];
#pragma unroll
        for (int j = 0; j < 29; ++j) xv[j] = ins[img * 3072 + (cc * 16 + ci) * 32 + j];
        float wv[5];
#pragma unroll
        for (int d = 0; d < 5; ++d) wv[d] = wls[co * 81 + ci * 5 + d];
#pragma unroll
        for (int t = 0; t < 25; ++t) {
          float s = acc[t];
#pragma unroll
          for (int d = 0; d < 5; ++d) s += xv[t + d] * wv[d];
          acc[t] = s;
        }
      }
    }
  }
  if (tid < 192) {
    const int n = wg * 2 + img;
    const float bval = bias[co];
    float s1 = 0.f, s2 = 0.f;
    for (int t = 0; t < 25; ++t) {
      float v = acc[t] + bval;
      h2[(size_t)n * 2400 + co * 25 + t] = v;
      s1 += v;
      s2 += v * v;
    }
    part1[((size_t)n * 96 + co) * 2 + 0] = s1;
    part1[((size_t)n * 96 + co) * 2 + 1] = s2;
  }
}

// ------------------------------ K3/K5: BN reduce -----------------------------
__global__ __launch_bounds__(256) void k3_bn1(const float* __restrict__ part,
                                              const float* __restrict__ gg,
                                              const float* __restrict__ be,
                                              float* __restrict__ ab) {
  __shared__ double sd[256], sq[256];
  const int c = blockIdx.x;
  const int t = threadIdx.x;
  double s = 0.0, q = 0.0;
  for (int n = t; n < NIMG; n += 256) {
    s += (double)part[((size_t)n * 96 + c) * 2 + 0];
    q += (double)part[((size_t)n * 96 + c) * 2 + 1];
  }
  sd[t] = s; sq[t] = q;
  __syncthreads();
  for (int off = 128; off > 0; off >>= 1) {
    if (t < off) { sd[t] += sd[t + off]; sq[t] += sq[t + off]; }
    __syncthreads();
  }
  if (t == 0) {
    double mu = sd[0] / 80000.0;
    double var = sq[0] / 80000.0 - mu * mu;
    float A = (float)((double)gg[c] / sqrt(var + 1e-5));
    ab[c * 2 + 0] = A;
    ab[c * 2 + 1] = (float)((double)be[c] - mu * (double)A);
  }
}

__global__ __launch_bounds__(256) void k5_bn2(const float* __restrict__ part,
                                              const float* __restrict__ gg,
                                              const float* __restrict__ be,
                                              float* __restrict__ ab) {
  __shared__ double sd[256], sq[256];
  const int c = blockIdx.x;
  const int t = threadIdx.x;
  double s = 0.0, q = 0.0;
  for (int n = t; n < 800; n += 256) {
    s += (double)part[((size_t)n * 16 + c) * 2 + 0];
    q += (double)part[((size_t)n * 16 + c) * 2 + 1];
  }
  sd[t] = s; sq[t] = q;
  __syncthreads();
  for (int off = 128; off > 0; off >>= 1) {
    if (t < off) { sd[t] += sd[t + off]; sq[t] += sq[t + off]; }
    __syncthreads();
  }
  if (t == 0) {
    double mu = sd[0] / 67200.0;
    double var = sq[0] / 67200.0 - mu * mu;
    float A = (float)((double)gg[c] / sqrt(var + 1e-5));
    ab[c * 2 + 0] = A;
    ab[c * 2 + 1] = (float)((double)be[c] - mu * (double)A);
  }
}

// ------------------------------ K4: conv2 ------------------------------
__global__ __launch_bounds__(256) void k4_conv2(const float* __restrict__ h2,
                                                const float* __restrict__ w,
                                                const float* __restrict__ bias,
                                                const float* __restrict__ bn1,
                                                float* __restrict__ h3,
                                                float* __restrict__ part2) {
  __shared__ __align__(16) float ins[4 * 96 * 26];
  __shared__ __align__(16) float wls[16 * 241];
  __shared__ float A1s[96], B1s[96];
  __shared__ float red[16 * 16 * 2];
  const int tid = threadIdx.x;
  const int wg = blockIdx.x;

  if (tid < 96) {
    A1s[tid] = bn1[tid * 2 + 0];
    B1s[tid] = bn1[tid * 2 + 1];
  }
  __syncthreads();
  for (int i = tid; i < 9600; i += 256) {
    int img = i / 2400;
    int e = i - img * 2400;
    int ci = e / 25;
    int t = e - ci * 25;
    float v = h2[(size_t)(wg * 4 + img) * 2400 + e];
    v = A1s[ci] * v + B1s[ci];
    v = (v >= 0.f) ? v : 0.01f * v;
    ins[img * 2496 + ci * 26 + t] = v;
  }
  for (int i = tid; i < 4 * 96; i += 256) ins[(i / 96) * 2496 + (i % 96) * 26 + 25] = 0.f;

  const int img = tid >> 6;
  const int co = (tid >> 2) & 15;
  const int tg = tid & 3;
  const int t0s[4] = {0, 6, 11, 16};
  const int t0 = t0s[tg];
  const int tl = (tg == 0) ? 6 : 5;
  float acc[6] = {0.f, 0.f, 0.f, 0.f, 0.f, 0.f};

  for (int cc = 0; cc < 2; ++cc) {
    __syncthreads();
    for (int i = tid; i < 3840; i += 256) {
      int cw = i / 240;
      int r = i - cw * 240;
      wls[cw * 241 + r] = w[cw * 480 + cc * 240 + r];
    }
    __syncthreads();
    for (int ci = 0; ci < 48; ++ci) {
      float xv[10];
#pragma unroll
      for (int j = 0; j < 10; ++j) xv[j] = ins[img * 2496 + (cc * 48 + ci) * 26 + t0 + j];
      float wv[5];
#pragma unroll
      for (int d = 0; d < 5; ++d) wv[d] = wls[co * 241 + ci * 5 + d];
#pragma unroll
      for (int t = 0; t < 6; ++t) {
        float s = acc[t];
#pragma unroll
        for (int d = 0; d < 5; ++d) s += xv[t + d] * wv[d];
        acc[t] = s;
      }
    }
  }
  const float bval = bias[co];
  float s1 = 0.f, s2 = 0.f;
  const int n = wg * 4 + img;
  for (int t = 0; t < 6; ++t) {
    if (t < tl) {
      float v = acc[t] + bval;
      h3[(size_t)n * 336 + co * 21 + t0 + t] = v;
      s1 += v;
      s2 += v * v;
    }
  }
  red[(co * 16 + img * 4 + tg) * 2 + 0] = s1;
  red[(co * 16 + img * 4 + tg) * 2 + 1] = s2;
  __syncthreads();
  if (tid < 16) {
    float s = 0.f, q = 0.f;
    for (int k = 0; k < 16; ++k) {
      s += red[(tid * 16 + k) * 2 + 0];
      q += red[(tid * 16 + k) * 2 + 1];
    }
    part2[((size_t)wg * 16 + tid) * 2 + 0] = s;
    part2[((size_t)wg * 16 + tid) * 2 + 1] = q;
  }
}

// ------------------------------ K6: OAS + Cholesky ---------------------------
__global__ __launch_bounds__(256) void k6_oas(const float* __restrict__ h3,
                                              const float* __restrict__ bn2,
                                              float* __restrict__ xd,
                                              float* __restrict__ xo) {
  __shared__ float X[4][21 * 17 + 3];
  __shared__ float A[4][16 * 17];
  __shared__ float mcol[4][16];
  const int tid = threadIdx.x;
  const int wid = tid >> 6;
  const int lane = tid & 63;
  const int n = blockIdx.x * 4 + wid;
  const float* hp = h3 + (size_t)n * 336;

  for (int e = lane; e < 336; e += 64) {
    int c = e / 21;
    int t = e - c * 21;
    float v = hp[e];
    v = bn2[c * 2 + 0] * v + bn2[c * 2 + 1];
    v = (v >= 0.f) ? v : 0.01f * v;
    X[wid][t * 17 + c] = v;
  }
  __syncthreads();
  if (lane < 16) {
    float s = 0.f;
    for (int t = 0; t < 21; ++t) s += X[wid][t * 17 + lane];
    mcol[wid][lane] = s * (1.f / 21.f);
  }
  __syncthreads();
  for (int e = lane; e < 336; e += 64) {
    int t = e / 16;
    int c = e - t * 16;
    X[wid][t * 17 + c] -= mcol[wid][c];
  }
  __syncthreads();

  float tr_p = 0.f, al_p = 0.f;
  float ent[3];
  int ei[3], ej[3], ne = 0;
  for (int e = lane; e < 136; e += 64) {
    int i = 0, e2 = e;
    while (e2 >= 16 - i) { e2 -= 16 - i; i++; }
    int j = i + e2;
    float s = 0.f;
    for (int t = 0; t < 21; ++t) s += X[wid][t * 17 + i] * X[wid][t * 17 + j];
    s *= (1.f / 20.f);
    ent[ne] = s; ei[ne] = i; ej[ne] = j; ne++;
    if (i == j) tr_p += s;
    al_p += s * s * ((i == j) ? 1.f : 2.f);
  }
  for (int m = 1; m < 64; m <<= 1) {
    tr_p += __shfl_xor(tr_p, m);
    al_p += __shfl_xor(al_p, m);
  }
  const float mu = tr_p * (1.f / 16.f);
  const float alpha = al_p * (1.f / 256.f);
  const float num = alpha + mu * mu;
  const float den = 22.f * (alpha - mu * mu * (1.f / 16.f));
  const float shr = (den == 0.f) ? 1.f : fminf(num / den, 1.f);
  for (int q = 0; q < ne; ++q) {
    float c = (1.f - shr) * ent[q] + ((ei[q] == ej[q]) ? shr * mu : 0.f);
    A[wid][ei[q] * 17 + ej[q]] = c;
    A[wid][ej[q] * 17 + ei[q]] = c;
  }
  __syncthreads();

  for (int k = 0; k < 16; ++k) {
    float akk = A[wid][k * 17 + k];
    __syncthreads();
    float d = sqrtf(akk);
    float rd = 1.f / d;
    if (lane == k) A[wid][k * 17 + k] = d;
    if (lane > k && lane < 16) A[wid][lane * 17 + k] *= rd;
    __syncthreads();
    if (lane > k && lane < 16) {
      float Lik = A[wid][lane * 17 + k];
      for (int j = k + 1; j <= lane; ++j) A[wid][lane * 17 + j] -= Lik * A[wid][j * 17 + k];
    }
    __syncthreads();
  }
  if (lane < 16) xd[(size_t)n * 16 + lane] = A[wid][lane * 17 + lane];
  for (int p = lane; p < 120; p += 64) {
    int i = 1, p2 = p;
    while (p2 >= i) { p2 -= i; i++; }
    xo[(size_t)n * 120 + p] = A[wid][i * 17 + p2];
  }
}

// ------------------------------ K0: pack W fragments ------------------------
// u32 slot within region: tile=(t*NT+nt), rem: lane=rem/4, word=rem%4.
// col = nt*16 + (lane&15), k = t*32 + 8*(lane>>4) + 2*word (+1).
__global__ __launch_bounds__(256) void k0_pack(const float* __restrict__ w0,
                                               const float* __restrict__ w1,
                                               const float* __restrict__ w2,
                                               const float* __restrict__ w3,
                                               const float* __restrict__ wxo,
                                               const float* __restrict__ who,
                                               uint32_t* __restrict__ dst) {
  int i = blockIdx.x * 256 + threadIdx.x;
  if (i >= PK2_TOT) return;
  int j = i, kind, NT;
  if (j < OFF_W1)       { kind = 0; NT = 16; }
  else if (j < OFF_W2)  { kind = 1; NT = 16; j -= OFF_W1; }
  else if (j < OFF_W3)  { kind = 2; NT = 16; j -= OFF_W2; }
  else if (j < OFF_GRZ) { kind = 3; NT = 9;  j -= OFF_W3; }
  else if (j < OFF_GNX) { kind = 4; NT = 15; j -= OFF_GRZ; }
  else if (j < OFF_GNH) { kind = 5; NT = 8;  j -= OFF_GNX; }
  else                  { kind = 6; NT = 8;  j -= OFF_GNH; }
  const int tile = j >> 8;
  const int rem = j & 255;
  const int l = rem >> 2;
  const int wd = rem & 3;
  const int t = tile / NT;
  const int nt = tile - t * NT;
  const int col = nt * 16 + (l & 15);
  const int kk = t * 32 + 8 * (l >> 4) + 2 * wd;

  float v[2];
#pragma unroll
  for (int q = 0; q < 2; ++q) {
    const int k = kk + q;
    float s = 0.f;
    if (kind == 0)      { if (k < 136) s = w0[k * 256 + col]; }
    else if (kind == 1) { s = w1[k * 256 + col]; }
    else if (kind == 2) { s = w2[k * 256 + col]; }
    else if (kind == 3) { if (col < 136) s = w3[k * 136 + col]; }
    else if (kind == 4) {
      if (k < 120) s = wxo[k * 360 + col];
      else if (k >= 128 && k < 248) s = who[(k - 128) * 360 + col];
    } else if (kind == 5) { if (k < 120 && col < 120) s = wxo[k * 360 + 240 + col]; }
    else                  { if (k < 120 && col < 120) s = who[k * 360 + 240 + col]; }
    v[q] = s;
  }
  union { f16 h[2]; uint32_t u; } cv;
  cv.h[0] = (f16)v[0];
  cv.h[1] = (f16)v[1];
  dst[i] = cv.u;
}

// ------------------------------ K7 helpers ----------------------------------
// X buffers: fragment-linear. uint4 slot index = tile*64 + lane.
// Element (row,k): lane = row + 16*((k>>3)&3), tile = k>>5, f16 pos = k&7.
__device__ __forceinline__ uint4 aread_lin(const f16* X, int t, int l) {
  return ((const uint4*)X)[t * 64 + l];
}
__device__ __forceinline__ void xwrite_frag(f16* X, int row, int col, float v) {
  const int slot = row + 16 * ((col >> 3) & 3);
  const int byte = (((col >> 5) * 64 + slot) << 4) + 2 * (col & 7);
  *(f16*)((char*)X + byte) = (f16)v;
}

union UF { uint4 u; f16x8 h; };

// MLP phase with cross-barrier rolling prefetch: consumes persistent bf and
// refills bf[t<nkt2] with B2's fragments for tile nt2. nt2<0 => keep.
// MODE 0 only (tanh -> Xout).
template <int KT, int NT>
__device__ __forceinline__ void mlp_pf(const f16* __restrict__ Xin,
                                       const float* __restrict__ bias,
                                       f16* __restrict__ Xout,
                                       int nt, int l,
                                       uint4 (&bf)[8],
                                       const uint4* __restrict__ B2,
                                       int NT2, int nt2, int nkt2) {
  const int m = l & 15;
  const int g = l >> 4;
  const bool act = (nt >= 0 && nt < NT);
  f32x4 acc = {0.f, 0.f, 0.f, 0.f};
#pragma unroll
  for (int t = 0; t < 8; ++t) {
    if (t < KT && act) {
      UF a; a.u = aread_lin(Xin, t, l);
      UF b; b.u = bf[t];
      acc = __builtin_amdgcn_mfma_f32_16x16x32_f16(a.h, b.h, acc, 0, 0, 0);
    }
    if (nt2 >= 0 && t < nkt2) bf[t] = B2[(t * NT2 + nt2) * 64 + l];
  }
  if (!act) return;
  const int col = nt * 16 + m;
  const float bb = bias[col];
#pragma unroll
  for (int i2 = 0; i2 < 4; ++i2)
    xwrite_frag(Xout, 4 * g + i2, col, ftanh(acc[i2] + bb));
}

// L3 phase: consumes W3 from LDS (zero global loads). bf untouched.
// MODE 1: hcf += 0.25*(.+b), mirror to Xnext(=XA). MODE 2: hcf += ...;
// col>=16 -> Xnext(=XG) at col+112; col<16 -> ehl = exp.
template <int MODE>
__device__ __forceinline__ void mlp_lds(const f16* __restrict__ Xin,
                                        const uint4* __restrict__ W3s,
                                        const float* __restrict__ bias,
                                        float* __restrict__ hcf,
                                        f16* __restrict__ Xnext,
                                        float* __restrict__ ehl,
                                        int nt, int l) {
  if (nt < 0) return;
  const int m = l & 15;
  const int g = l >> 4;
  f32x4 acc = {0.f, 0.f, 0.f, 0.f};
#pragma unroll
  for (int t = 0; t < 8; ++t) {
    UF a; a.u = aread_lin(Xin, t, l);
    UF b; b.u = W3s[(t * 9 + nt) * 64 + l];
    acc = __builtin_amdgcn_mfma_f32_16x16x32_f16(a.h, b.h, acc, 0, 0, 0);
  }
  const int col = nt * 16 + m;
  if (col < 136) {
    const float bb = bias[col];
#pragma unroll
    for (int i2 = 0; i2 < 4; ++i2) {
      const int row = 4 * g + i2;
      float v = hcf[row * HS + col] + 0.25f * (acc[i2] + bb);
      hcf[row * HS + col] = v;
      if (MODE == 1) {
        xwrite_frag(Xnext, row, col, v);
      } else {
        if (col >= 16) xwrite_frag(Xnext, row, col + 112, v);
        else ehl[row * 16 + col] = __expf(v);
      }
    }
  }
}

// Gate RZ: consumes persistent bf (prefetched at e==3 L2), no refill.
template <int KT, int NT>
__device__ __forceinline__ void gate_rz(const f16* __restrict__ Xin,
                                        float* __restrict__ GO,
                                        int nt, int gooff, int l,
                                        uint4 (&bf)[8]) {
  if (nt < 0) return;
  const int m = l & 15;
  const int g = l >> 4;
  f32x4 acc = {0.f, 0.f, 0.f, 0.f};
#pragma unroll
  for (int t = 0; t < KT; ++t) {
    UF a; a.u = aread_lin(Xin, t, l);
    UF b; b.u = bf[t];
    acc = __builtin_amdgcn_mfma_f32_16x16x32_f16(a.h, b.h, acc, 0, 0, 0);
  }
  const int col = nt * 16 + m;
#pragma unroll
  for (int i2 = 0; i2 < 4; ++i2)
    GO[(4 * g + i2) * GS + gooff + col] = acc[i2];
}

// Self-loading gate tile (NX/NH, small KT).
template <int KT, int NT>
__device__ __forceinline__ void gate_tile(const f16* __restrict__ Xin,
                                          const uint4* __restrict__ B,
                                          float* __restrict__ GO,
                                          int nt, int ktoff, int gooff, int l) {
  if (nt < 0) return;
  const int m = l & 15;
  const int g = l >> 4;
  uint4 bfx[KT];
#pragma unroll
  for (int t = 0; t < KT; ++t) bfx[t] = B[(t * NT + nt) * 64 + l];
  f32x4 acc = {0.f, 0.f, 0.f, 0.f};
#pragma unroll
  for (int t = 0; t < KT; ++t) {
    UF a; a.u = aread_lin(Xin, t + ktoff, l);
    UF b; b.u = bfx[t];
    acc = __builtin_amdgcn_mfma_f32_16x16x32_f16(a.h, b.h, acc, 0, 0, 0);
  }
  const int col = nt * 16 + m;
#pragma unroll
  for (int i2 = 0; i2 < 4; ++i2)
    GO[(4 * g + i2) * GS + gooff + col] = acc[i2];
}

// ------------------------------ K7: scan (W3 LDS-resident) ------------------
__global__ __launch_bounds__(1024, 1) void k7_scan(
    const float* __restrict__ xdv, const float* __restrict__ xov,
    const float* __restrict__ wxd, const float* __restrict__ whd,
    const float* __restrict__ bdv, const float* __restrict__ bov,
    const uint32_t* __restrict__ pk,
    const float* __restrict__ b0, const float* __restrict__ b1,
    const float* __restrict__ b2, const float* __restrict__ b3,
    const float* __restrict__ cw, const float* __restrict__ cbv,
    float* __restrict__ out) {
  __shared__ __align__(16) f16 XA[16 * 256];
  __shared__ __align__(16) f16 XB[16 * 256];
  __shared__ __align__(16) f16 XG[16 * 256];
  __shared__ __align__(16) uint4 W3s[4608];       // 73728 B: W3 resident
  __shared__ __align__(16) float GO[16 * GS];
  __shared__ __align__(16) float hcf[16 * HS];
  __shared__ __align__(16) float xdlv[16 * 16];
  __shared__ __align__(16) float ehl[16 * 16];
  __shared__ __align__(16) float G2[16 * 96];
  __shared__ __align__(16) float wdaT[48 * 16], whaT[48 * 16];
  __shared__ float b0l[256], b1l[256], b2l[256], b3l[144], bovl[360], bdvl[48];

  const int tid = threadIdx.x;
  const int w = tid >> 6;
  const int l = tid & 63;
  const int blk = blockIdx.x;

  const uint4* BW0 = (const uint4*)(pk + OFF_W0);
  const uint4* BW1 = (const uint4*)(pk + OFF_W1);
  const uint4* BW2 = (const uint4*)(pk + OFF_W2);
  const uint4* BW3 = (const uint4*)(pk + OFF_W3);
  const uint4* BRZ = (const uint4*)(pk + OFF_GRZ);
  const uint4* BNX = (const uint4*)(pk + OFF_GNX);
  const uint4* BNH = (const uint4*)(pk + OFF_GNH);

  // init LDS constants + resident W3
  for (int i = tid; i < 4608; i += 1024) W3s[i] = BW3[i];
  for (int i = tid; i < 768; i += 1024) {
    int k = i / 48, c = i - k * 48;
    wdaT[c * 16 + k] = fabsf(wxd[i]);
    whaT[c * 16 + k] = fabsf(whd[i]);
  }
  for (int i = tid; i < 256; i += 1024) { b0l[i] = b0[i]; b1l[i] = b1[i]; b2l[i] = b2[i]; }
  if (tid < 144) b3l[tid] = (tid < 136) ? b3[tid] : 0.f;
  if (tid < 360) bovl[tid] = bov[tid];
  if (tid < 48) bdvl[tid] = fabsf(bdv[tid]);
  for (int i = tid; i < 16 * HS; i += 1024) hcf[i] = 0.f;
  for (int i = tid; i < 4096; i += 1024) { XA[i] = (f16)0.f; XG[i] = (f16)0.f; }

  // persistent weight fragments; preload e0-L0 (BW0, tile w)
  uint4 bf[8];
#pragma unroll
  for (int t = 0; t < 5; ++t) bf[t] = BW0[(t * 16 + w) * 64 + l];
  __syncthreads();

#pragma unroll 1
  for (int s = 0; s < 50; ++s) {
    // ---- ODE: 4 Euler steps; 4 phases each ----
#pragma unroll 1
    for (int e = 0; e < 4; ++e) {
      // L0: read XA -> write XB. consume BW0, prefetch BW1.
      mlp_pf<5, 16>(XA, b0l, XB, w, l, bf, BW1, 16, w, 8);
      if (e == 0) {
        for (int i = tid; i < 1920; i += 1024) {
          int row = i / 120, c = i - row * 120;
          xwrite_frag(XG, row, c, xov[((size_t)(blk * 16 + row) * 50 + s) * 120 + c]);
        }
        if (tid < 256) {
          int row = tid >> 4, k = tid & 15;
          xdlv[tid] = xdv[((size_t)(blk * 16 + row) * 50 + s) * 16 + k];
        }
      }
      __syncthreads();
      // L1: read XB -> write XA. consume BW1, prefetch BW2.
      mlp_pf<8, 16>(XB, b1l, XA, w, l, bf, BW2, 16, w, 8);
      __syncthreads();
      // L2: read XA -> write XB. consume BW2, prefetch (BW0 | BRZ).
      {
        const uint4* nb = (e == 3) ? BRZ : BW0;
        const int nNT = (e == 3) ? 15 : 16;
        const int nnt = (e == 3) ? ((w < 15) ? w : -1) : w;
        const int nk = (e == 3) ? 8 : 5;
        mlp_pf<8, 16>(XA, b2l, XB, w, l, bf, nb, nNT, nnt, nk);
      }
      __syncthreads();
      // L3: read XB, W3 from LDS (zero global loads); bf untouched.
      if (e < 3)
        mlp_lds<1>(XB, W3s, b3l, hcf, XA, nullptr, (w < 9) ? w : -1, l);
      else
        mlp_lds<2>(XB, W3s, b3l, hcf, XG, ehl, (w < 9) ? w : -1, l);
      __syncthreads();
    }

    // ---- gate matmuls (RZ consumes persistent bf) + d-gate dots ----
    gate_rz<8, 15>(XG, GO, (w < 15) ? w : -1, 0, l, bf);
    gate_tile<4, 8>(XG, BNX, GO, (w < 8) ? w : -1, 0, 256, l);
    gate_tile<4, 8>(XG, BNH, GO, (w >= 8) ? (w - 8) : -1, 4, 384, l);
    for (int i = tid; i < 1536; i += 1024) {
      int row = i / 96, c = i - row * 96;
      const float4* sv = (const float4*)((c < 48) ? &xdlv[row * 16] : &ehl[row * 16]);
      const float4* wv = (const float4*)((c < 48) ? &wdaT[c * 16] : &whaT[(c - 48) * 16]);
      float a = 0.f;
#pragma unroll
      for (int q = 0; q < 4; ++q) {
        float4 xq = sv[q], wq = wv[q];
        a += xq.x * wq.x + xq.y * wq.y + xq.z * wq.z + xq.w * wq.w;
      }
      G2[row * 96 + c] = a;
    }
    __syncthreads();

    // ---- state update (prefetch next step's BW0 first; writes hcf + XA) ----
#pragma unroll
    for (int t = 0; t < 5; ++t) bf[t] = BW0[(t * 16 + w) * 64 + l];
    for (int i = tid; i < 1920; i += 1024) {
      int row = i / 120, e2 = i - row * 120;
      float rr = fsigm(GO[row * GS + e2] + bovl[e2]);
      float zz = fsigm(GO[row * GS + 120 + e2] + bovl[120 + e2]);
      float ng = ftanh(GO[row * GS + 256 + e2] + rr * GO[row * GS + 384 + e2] + bovl[240 + e2]);
      float ho = hcf[row * HS + 16 + e2];
      float v = ng + zz * (ho - ng);
      hcf[row * HS + 16 + e2] = v;
      xwrite_frag(XA, row, 16 + e2, v);
    }
    if (tid < 256) {
      int row = tid >> 4, t = tid & 15;
      float ixr = G2[row * 96 + t], ixi = G2[row * 96 + 16 + t], ixn = G2[row * 96 + 32 + t];
      float hhr = G2[row * 96 + 48 + t], hhi = G2[row * 96 + 64 + t], hhn = G2[row * 96 + 80 + t];
      float br = bdvl[t], bi = bdvl[16 + t], bn = bdvl[32 + t];
      float rr = fsigm(br * ixr * hhr);
      float zz = fsigm(bi * ixi * hhi);
      float sp = bn * ixn * rr * hhn;
      float ng = (sp > 20.f) ? sp : __logf(1.f + __expf(sp));
      float ldp = hcf[row * HS + t];
      float v = zz * ldp + (1.f - zz) * __logf(ng);
      hcf[row * HS + t] = v;
      xwrite_frag(XA, row, t, v);
    }
    __syncthreads();
  }

  // ---- classifier ----
  if (tid < 80) {
    int row = tid / 5, c = tid - row * 5;
    float a = cbv[c];
    for (int k = 0; k < 136; ++k) a += hcf[row * HS + k] * cw[k * 5 + c];
    out[(size_t)(blk * 16 + row) * 5 + c] = a;
  }
}

// ------------------------------ launch ------------------------------
extern "C" void kernel_launch(void* const* d_in, const int* in_sizes, int n_in,
                              void* d_out, int out_size, void* d_ws, size_t ws_size,
                              hipStream_t stream) {
  const float* x       = (const float*)d_in[0];
  const float* fw      = (const float*)d_in[1];
  const float* s_tri   = (const float*)d_in[2];
  const float* conv1_w = (const float*)d_in[3];
  const float* conv1_b = (const float*)d_in[4];
  const float* bn1_g   = (const float*)d_in[5];
  const float* bn1_b   = (const float*)d_in[6];
  const float* conv2_w = (const float*)d_in[7];
  const float* conv2_b = (const float*)d_in[8];
  const float* bn2_g   = (const float*)d_in[9];
  const float* bn2_b   = (const float*)d_in[10];
  const float* wx_d    = (const float*)d_in[11];
  const float* wh_d    = (const float*)d_in[12];
  const float* bias_d  = (const float*)d_in[13];
  const float* wx_o    = (const float*)d_in[14];
  const float* wh_o    = (const float*)d_in[15];
  const float* bias_o  = (const float*)d_in[16];
  const float* ode_w0  = (const float*)d_in[17];
  const float* ode_b0  = (const float*)d_in[18];
  const float* ode_w1  = (const float*)d_in[19];
  const float* ode_b1  = (const float*)d_in[20];
  const float* ode_w2  = (const float*)d_in[21];
  const float* ode_b2  = (const float*)d_in[22];
  const float* ode_w3  = (const float*)d_in[23];
  const float* ode_b3  = (const float*)d_in[24];
  const float* cls_w   = (const float*)d_in[25];
  const float* cls_b   = (const float*)d_in[26];

  float* ws = (float*)d_ws;
  float* h1  = ws;                    // 8,908,800 floats (K1->K2), then dead
  float* h3  = ws;                    // 1,075,200 floats (K4->K6)
  float* xd  = ws + 1075200;          // 51,200
  float* xo  = ws + 1126400;          // 384,000
  float* h2  = ws + 8908800;          // 7,680,000 (K2->K4), then reused by K0
  float* p1  = ws + 16588800;         // 614,400
  float* bn1 = ws + 17203200;         // 192
  float* p2  = ws + 17203392;         // 25,600
  float* bn2 = ws + 17228992;         // 32
  uint32_t* pk = (uint32_t*)(ws + 8908800);  // packed W-fragments (dead h2)

  hipLaunchKernelGGL(k1_fb,   dim3(NIMG),   dim3(256), 0, stream, x, fw, s_tri, h1);
  hipLaunchKernelGGL(k2_conv1,dim3(NIMG/2), dim3(256), 0, stream, h1, conv1_w, conv1_b, h2, p1);
  hipLaunchKernelGGL(k3_bn1,  dim3(96),     dim3(256), 0, stream, p1, bn1_g, bn1_b, bn1);
  hipLaunchKernelGGL(k4_conv2,dim3(NIMG/4), dim3(256), 0, stream, h2, conv2_w, conv2_b, bn1, h3, p2);
  hipLaunchKernelGGL(k5_bn2,  dim3(16),     dim3(256), 0, stream, p2, bn2_g, bn2_b, bn2);
  hipLaunchKernelGGL(k6_oas,  dim3(NIMG/4), dim3(256), 0, stream, h3, bn2, xd, xo);
  hipLaunchKernelGGL(k0_pack, dim3((PK2_TOT + 255) / 256), dim3(256), 0, stream,
                     ode_w0, ode_w1, ode_w2, ode_w3, wx_o, wh_o, pk);
  hipLaunchKernelGGL(k7_scan, dim3(4),      dim3(1024), 0, stream,
                     xd, xo, wx_d, wh_d, bias_d, bias_o, pk,
                     ode_b0, ode_b1, ode_b2, ode_b3, cls_w, cls_b, (float*)d_out);
}

// Round 17
// 1542.857 us; speedup vs baseline: 2.1893x; 1.0062x over previous
//
#include <hip/hip_runtime.h>
#include <math.h>

// ---------------------------------------------------------------------------
// ODERGRU pipeline for MI355X.
//  K0b: pack conv1_w f32 -> f16 (halves k2 weight staging)
//  K1: einsum -> h1 (3200,96,29)
//  K2: conv1d 96->96 k5 + bias -> h2 + BN partials (f16 weights, float4 reads)
//  K3: BN1 reduce   K5: BN2 reduce  (f64 tree)
//  K4: conv1d 96->16 k5 (BN1+lrelu on load) -> h3 + BN2 partials
//  K6: OAS + Cholesky -> x_d, x_o
//  K0: pack ODE/GRU weights f32 -> f16 fragments (MFMA lane order)
//  K7: (R16 best, untouched) 4 blocks x 16 waves x 16 rows, W3 LDS-resident,
//      rolling prefetch, fragment-linear LDS, fast transcendentals.
// ---------------------------------------------------------------------------

#define BB 64
#define NIMG 3200

typedef _Float16 f16;
typedef _Float16 f16x8 __attribute__((ext_vector_type(8)));
typedef float f32x4 __attribute__((ext_vector_type(4)));

#define HS 164   // hcf row stride (f32)
#define GS 516   // GO row stride (f32)

__device__ __forceinline__ float fsigm(float x) {
  return __fdividef(1.f, 1.f + __expf(-x));
}
__device__ __forceinline__ float ftanh(float x) {
  return 1.f - __fdividef(2.f, __expf(2.f * x) + 1.f);
}

// pk region offsets (u32 units)
#define OFF_W0  0
#define OFF_W1  20480
#define OFF_W2  53248
#define OFF_W3  86016
#define OFF_GRZ 104448
#define OFF_GNX 135168
#define OFF_GNH 143360
#define PK2_TOT 151552

// ------------------------------ K0b: conv1 weight f16 pack ------------------
__global__ __launch_bounds__(256) void k0b_w1h(const float* __restrict__ w,
                                               f16* __restrict__ dst) {
  int i = blockIdx.x * 256 + threadIdx.x;
  if (i < 46080) dst[i] = (f16)w[i];
}

// ------------------------------ K1: filterbank ------------------------------
__global__ __launch_bounds__(256) void k1_fb(const float* __restrict__ x,
                                             const float* __restrict__ fw,
                                             const float* __restrict__ st,
                                             float* __restrict__ h1) {
  __shared__ __align__(16) float ws[129 * 32];
  __shared__ __align__(16) float xs[129 * 32];
  const int tid = threadIdx.x;
  const int n = blockIdx.x;
  const float* xp = x + (size_t)n * 11223;

  for (int i = tid; i < 4128; i += 256) ws[i] = fw[i] * st[i];

  float acc[4][4];
#pragma unroll
  for (int i = 0; i < 4; ++i)
#pragma unroll
    for (int j = 0; j < 4; ++j) acc[i][j] = 0.f;

  const int c = tid / 64;
  const int rem = tid % 64;
  const int m0 = (rem / 8) * 4;
  const int t0 = (rem % 8) * 4;

  for (int fc = 0; fc < 3; ++fc) {
    __syncthreads();
    for (int i = tid; i < 3741; i += 256) {
      int cc = i / 1247;
      int r = i - cc * 1247;
      int f = r / 29;
      int t = r - f * 29;
      xs[(cc * 43 + f) * 32 + t] = xp[cc * 3741 + (fc * 43 + f) * 29 + t];
    }
    for (int i = tid; i < 129; i += 256) {
      xs[i * 32 + 29] = 0.f; xs[i * 32 + 30] = 0.f; xs[i * 32 + 31] = 0.f;
    }
    __syncthreads();
    if (tid < 192) {
      const float* xb = xs + (c * 43) * 32 + t0;
      const float* wb = ws + (fc * 43) * 32 + m0;
      for (int f = 0; f < 43; ++f) {
        float4 xv = *(const float4*)(xb + f * 32);
        float4 wv = *(const float4*)(wb + f * 32);
        float xa[4] = {xv.x, xv.y, xv.z, xv.w};
        float wa[4] = {wv.x, wv.y, wv.z, wv.w};
#pragma unroll
        for (int i = 0; i < 4; ++i)
#pragma unroll
          for (int j = 0; j < 4; ++j) acc[i][j] += wa[i] * xa[j];
      }
    }
  }
  if (tid < 192) {
    const int nt = (t0 == 28) ? 1 : 4;
    for (int i = 0; i < 4; ++i)
      for (int j = 0; j < nt; ++j)
        h1[(size_t)n * 2784 + (size_t)(c * 32 + m0 + i) * 29 + (t0 + j)] = acc[i][j];
  }
}

// ------------------------------ K2: conv1 (f16 weights, float4 reads) -------
__global__ __launch_bounds__(256) void k2_conv1(const float* __restrict__ h1,
                                                const f16* __restrict__ wh,
                                                const float* __restrict__ bias,
                                                float* __restrict__ h2,
                                                float* __restrict__ part1) {
  __shared__ __align__(16) float ins[2 * 96 * 32];
  __shared__ __align__(16) f16 wls[96 * 81 + 8];
  const int tid = threadIdx.x;
  const int wg = blockIdx.x;

  for (int i = tid; i < 2 * 2784; i += 256) {
    int img = i / 2784;
    int e = i - img * 2784;
    int ci = e / 29;
    int t = e - ci * 29;
    ins[img * 3072 + ci * 32 + t] = h1[(size_t)(wg * 2 + img) * 2784 + e];
  }

  const int img = tid / 96;
  const int co = tid - img * 96;
  float acc[25];
#pragma unroll
  for (int t = 0; t < 25; ++t) acc[t] = 0.f;

  for (int cc = 0; cc < 6; ++cc) {
    __syncthreads();
    for (int i = tid; i < 7680; i += 256) {
      int cw = i / 80;
      int r = i - cw * 80;
      wls[cw * 81 + r] = wh[cw * 480 + cc * 80 + r];
    }
    __syncthreads();
    if (tid < 192) {
      for (int ci = 0; ci < 16; ++ci) {
        float xv[32];
        const float4* xr = (const float4*)&ins[img * 3072 + (cc * 16 + ci) * 32];
#pragma unroll
        for (int q = 0; q < 8; ++q) *(float4*)&xv[4 * q] = xr[q];
        float wv[5];
#pragma unroll
        for (int d = 0; d < 5; ++d) wv[d] = (float)wls[co * 81 + ci * 5 + d];
#pragma unroll
        for (int t = 0; t < 25; ++t) {
          float s = acc[t];
#pragma unroll
          for (int d = 0; d < 5; ++d) s += xv[t + d] * wv[d];
          acc[t] = s;
        }
      }
    }
  }
  if (tid < 192) {
    const int n = wg * 2 + img;
    const float bval = bias[co];
    float s1 = 0.f, s2 = 0.f;
    for (int t = 0; t < 25; ++t) {
      float v = acc[t] + bval;
      h2[(size_t)n * 2400 + co * 25 + t] = v;
      s1 += v;
      s2 += v * v;
    }
    part1[((size_t)n * 96 + co) * 2 + 0] = s1;
    part1[((size_t)n * 96 + co) * 2 + 1] = s2;
  }
}

// ------------------------------ K3/K5: BN reduce -----------------------------
__global__ __launch_bounds__(256) void k3_bn1(const float* __restrict__ part,
                                              const float* __restrict__ gg,
                                              const float* __restrict__ be,
                                              float* __restrict__ ab) {
  __shared__ double sd[256], sq[256];
  const int c = blockIdx.x;
  const int t = threadIdx.x;
  double s = 0.0, q = 0.0;
  for (int n = t; n < NIMG; n += 256) {
    s += (double)part[((size_t)n * 96 + c) * 2 + 0];
    q += (double)part[((size_t)n * 96 + c) * 2 + 1];
  }
  sd[t] = s; sq[t] = q;
  __syncthreads();
  for (int off = 128; off > 0; off >>= 1) {
    if (t < off) { sd[t] += sd[t + off]; sq[t] += sq[t + off]; }
    __syncthreads();
  }
  if (t == 0) {
    double mu = sd[0] / 80000.0;
    double var = sq[0] / 80000.0 - mu * mu;
    float A = (float)((double)gg[c] / sqrt(var + 1e-5));
    ab[c * 2 + 0] = A;
    ab[c * 2 + 1] = (float)((double)be[c] - mu * (double)A);
  }
}

__global__ __launch_bounds__(256) void k5_bn2(const float* __restrict__ part,
                                              const float* __restrict__ gg,
                                              const float* __restrict__ be,
                                              float* __restrict__ ab) {
  __shared__ double sd[256], sq[256];
  const int c = blockIdx.x;
  const int t = threadIdx.x;
  double s = 0.0, q = 0.0;
  for (int n = t; n < 800; n += 256) {
    s += (double)part[((size_t)n * 16 + c) * 2 + 0];
    q += (double)part[((size_t)n * 16 + c) * 2 + 1];
  }
  sd[t] = s; sq[t] = q;
  __syncthreads();
  for (int off = 128; off > 0; off >>= 1) {
    if (t < off) { sd[t] += sd[t + off]; sq[t] += sq[t + off]; }
    __syncthreads();
  }
  if (t == 0) {
    double mu = sd[0] / 67200.0;
    double var = sq[0] / 67200.0 - mu * mu;
    float A = (float)((double)gg[c] / sqrt(var + 1e-5));
    ab[c * 2 + 0] = A;
    ab[c * 2 + 1] = (float)((double)be[c] - mu * (double)A);
  }
}

// ------------------------------ K4: conv2 ------------------------------
__global__ __launch_bounds__(256) void k4_conv2(const float* __restrict__ h2,
                                                const float* __restrict__ w,
                                                const float* __restrict__ bias,
                                                const float* __restrict__ bn1,
                                                float* __restrict__ h3,
                                                float* __restrict__ part2) {
  __shared__ __align__(16) float ins[4 * 96 * 26];
  __shared__ __align__(16) float wls[16 * 241];
  __shared__ float A1s[96], B1s[96];
  __shared__ float red[16 * 16 * 2];
  const int tid = threadIdx.x;
  const int wg = blockIdx.x;

  if (tid < 96) {
    A1s[tid] = bn1[tid * 2 + 0];
    B1s[tid] = bn1[tid * 2 + 1];
  }
  __syncthreads();
  for (int i = tid; i < 9600; i += 256) {
    int img = i / 2400;
    int e = i - img * 2400;
    int ci = e / 25;
    int t = e - ci * 25;
    float v = h2[(size_t)(wg * 4 + img) * 2400 + e];
    v = A1s[ci] * v + B1s[ci];
    v = (v >= 0.f) ? v : 0.01f * v;
    ins[img * 2496 + ci * 26 + t] = v;
  }
  for (int i = tid; i < 4 * 96; i += 256) ins[(i / 96) * 2496 + (i % 96) * 26 + 25] = 0.f;

  const int img = tid >> 6;
  const int co = (tid >> 2) & 15;
  const int tg = tid & 3;
  const int t0s[4] = {0, 6, 11, 16};
  const int t0 = t0s[tg];
  const int tl = (tg == 0) ? 6 : 5;
  float acc[6] = {0.f, 0.f, 0.f, 0.f, 0.f, 0.f};

  for (int cc = 0; cc < 2; ++cc) {
    __syncthreads();
    for (int i = tid; i < 3840; i += 256) {
      int cw = i / 240;
      int r = i - cw * 240;
      wls[cw * 241 + r] = w[cw * 480 + cc * 240 + r];
    }
    __syncthreads();
    for (int ci = 0; ci < 48; ++ci) {
      float xv[10];
#pragma unroll
      for (int j = 0; j < 10; ++j) xv[j] = ins[img * 2496 + (cc * 48 + ci) * 26 + t0 + j];
      float wv[5];
#pragma unroll
      for (int d = 0; d < 5; ++d) wv[d] = wls[co * 241 + ci * 5 + d];
#pragma unroll
      for (int t = 0; t < 6; ++t) {
        float s = acc[t];
#pragma unroll
        for (int d = 0; d < 5; ++d) s += xv[t + d] * wv[d];
        acc[t] = s;
      }
    }
  }
  const float bval = bias[co];
  float s1 = 0.f, s2 = 0.f;
  const int n = wg * 4 + img;
  for (int t = 0; t < 6; ++t) {
    if (t < tl) {
      float v = acc[t] + bval;
      h3[(size_t)n * 336 + co * 21 + t0 + t] = v;
      s1 += v;
      s2 += v * v;
    }
  }
  red[(co * 16 + img * 4 + tg) * 2 + 0] = s1;
  red[(co * 16 + img * 4 + tg) * 2 + 1] = s2;
  __syncthreads();
  if (tid < 16) {
    float s = 0.f, q = 0.f;
    for (int k = 0; k < 16; ++k) {
      s += red[(tid * 16 + k) * 2 + 0];
      q += red[(tid * 16 + k) * 2 + 1];
    }
    part2[((size_t)wg * 16 + tid) * 2 + 0] = s;
    part2[((size_t)wg * 16 + tid) * 2 + 1] = q;
  }
}

// ------------------------------ K6: OAS + Cholesky ---------------------------
__global__ __launch_bounds__(256) void k6_oas(const float* __restrict__ h3,
                                              const float* __restrict__ bn2,
                                              float* __restrict__ xd,
                                              float* __restrict__ xo) {
  __shared__ float X[4][21 * 17 + 3];
  __shared__ float A[4][16 * 17];
  __shared__ float mcol[4][16];
  const int tid = threadIdx.x;
  const int wid = tid >> 6;
  const int lane = tid & 63;
  const int n = blockIdx.x * 4 + wid;
  const float* hp = h3 + (size_t)n * 336;

  for (int e = lane; e < 336; e += 64) {
    int c = e / 21;
    int t = e - c * 21;
    float v = hp[e];
    v = bn2[c * 2 + 0] * v + bn2[c * 2 + 1];
    v = (v >= 0.f) ? v : 0.01f * v;
    X[wid][t * 17 + c] = v;
  }
  __syncthreads();
  if (lane < 16) {
    float s = 0.f;
    for (int t = 0; t < 21; ++t) s += X[wid][t * 17 + lane];
    mcol[wid][lane] = s * (1.f / 21.f);
  }
  __syncthreads();
  for (int e = lane; e < 336; e += 64) {
    int t = e / 16;
    int c = e - t * 16;
    X[wid][t * 17 + c] -= mcol[wid][c];
  }
  __syncthreads();

  float tr_p = 0.f, al_p = 0.f;
  float ent[3];
  int ei[3], ej[3], ne = 0;
  for (int e = lane; e < 136; e += 64) {
    int i = 0, e2 = e;
    while (e2 >= 16 - i) { e2 -= 16 - i; i++; }
    int j = i + e2;
    float s = 0.f;
    for (int t = 0; t < 21; ++t) s += X[wid][t * 17 + i] * X[wid][t * 17 + j];
    s *= (1.f / 20.f);
    ent[ne] = s; ei[ne] = i; ej[ne] = j; ne++;
    if (i == j) tr_p += s;
    al_p += s * s * ((i == j) ? 1.f : 2.f);
  }
  for (int m = 1; m < 64; m <<= 1) {
    tr_p += __shfl_xor(tr_p, m);
    al_p += __shfl_xor(al_p, m);
  }
  const float mu = tr_p * (1.f / 16.f);
  const float alpha = al_p * (1.f / 256.f);
  const float num = alpha + mu * mu;
  const float den = 22.f * (alpha - mu * mu * (1.f / 16.f));
  const float shr = (den == 0.f) ? 1.f : fminf(num / den, 1.f);
  for (int q = 0; q < ne; ++q) {
    float c = (1.f - shr) * ent[q] + ((ei[q] == ej[q]) ? shr * mu : 0.f);
    A[wid][ei[q] * 17 + ej[q]] = c;
    A[wid][ej[q] * 17 + ei[q]] = c;
  }
  __syncthreads();

  for (int k = 0; k < 16; ++k) {
    float akk = A[wid][k * 17 + k];
    __syncthreads();
    float d = sqrtf(akk);
    float rd = 1.f / d;
    if (lane == k) A[wid][k * 17 + k] = d;
    if (lane > k && lane < 16) A[wid][lane * 17 + k] *= rd;
    __syncthreads();
    if (lane > k && lane < 16) {
      float Lik = A[wid][lane * 17 + k];
      for (int j = k + 1; j <= lane; ++j) A[wid][lane * 17 + j] -= Lik * A[wid][j * 17 + k];
    }
    __syncthreads();
  }
  if (lane < 16) xd[(size_t)n * 16 + lane] = A[wid][lane * 17 + lane];
  for (int p = lane; p < 120; p += 64) {
    int i = 1, p2 = p;
    while (p2 >= i) { p2 -= i; i++; }
    xo[(size_t)n * 120 + p] = A[wid][i * 17 + p2];
  }
}

// ------------------------------ K0: pack W fragments ------------------------
// u32 slot within region: tile=(t*NT+nt), rem: lane=rem/4, word=rem%4.
// col = nt*16 + (lane&15), k = t*32 + 8*(lane>>4) + 2*word (+1).
__global__ __launch_bounds__(256) void k0_pack(const float* __restrict__ w0,
                                               const float* __restrict__ w1,
                                               const float* __restrict__ w2,
                                               const float* __restrict__ w3,
                                               const float* __restrict__ wxo,
                                               const float* __restrict__ who,
                                               uint32_t* __restrict__ dst) {
  int i = blockIdx.x * 256 + threadIdx.x;
  if (i >= PK2_TOT) return;
  int j = i, kind, NT;
  if (j < OFF_W1)       { kind = 0; NT = 16; }
  else if (j < OFF_W2)  { kind = 1; NT = 16; j -= OFF_W1; }
  else if (j < OFF_W3)  { kind = 2; NT = 16; j -= OFF_W2; }
  else if (j < OFF_GRZ) { kind = 3; NT = 9;  j -= OFF_W3; }
  else if (j < OFF_GNX) { kind = 4; NT = 15; j -= OFF_GRZ; }
  else if (j < OFF_GNH) { kind = 5; NT = 8;  j -= OFF_GNX; }
  else                  { kind = 6; NT = 8;  j -= OFF_GNH; }
  const int tile = j >> 8;
  const int rem = j & 255;
  const int l = rem >> 2;
  const int wd = rem & 3;
  const int t = tile / NT;
  const int nt = tile - t * NT;
  const int col = nt * 16 + (l & 15);
  const int kk = t * 32 + 8 * (l >> 4) + 2 * wd;

  float v[2];
#pragma unroll
  for (int q = 0; q < 2; ++q) {
    const int k = kk + q;
    float s = 0.f;
    if (kind == 0)      { if (k < 136) s = w0[k * 256 + col]; }
    else if (kind == 1) { s = w1[k * 256 + col]; }
    else if (kind == 2) { s = w2[k * 256 + col]; }
    else if (kind == 3) { if (col < 136) s = w3[k * 136 + col]; }
    else if (kind == 4) {
      if (k < 120) s = wxo[k * 360 + col];
      else if (k >= 128 && k < 248) s = who[(k - 128) * 360 + col];
    } else if (kind == 5) { if (k < 120 && col < 120) s = wxo[k * 360 + 240 + col]; }
    else                  { if (k < 120 && col < 120) s = who[k * 360 + 240 + col]; }
    v[q] = s;
  }
  union { f16 h[2]; uint32_t u; } cv;
  cv.h[0] = (f16)v[0];
  cv.h[1] = (f16)v[1];
  dst[i] = cv.u;
}

// ------------------------------ K7 helpers ----------------------------------
// X buffers: fragment-linear. uint4 slot index = tile*64 + lane.
// Element (row,k): lane = row + 16*((k>>3)&3), tile = k>>5, f16 pos = k&7.
__device__ __forceinline__ uint4 aread_lin(const f16* X, int t, int l) {
  return ((const uint4*)X)[t * 64 + l];
}
__device__ __forceinline__ void xwrite_frag(f16* X, int row, int col, float v) {
  const int slot = row + 16 * ((col >> 3) & 3);
  const int byte = (((col >> 5) * 64 + slot) << 4) + 2 * (col & 7);
  *(f16*)((char*)X + byte) = (f16)v;
}

union UF { uint4 u; f16x8 h; };

// MLP phase with cross-barrier rolling prefetch: consumes persistent bf and
// refills bf[t<nkt2] with B2's fragments for tile nt2. nt2<0 => keep.
// MODE 0 only (tanh -> Xout).
template <int KT, int NT>
__device__ __forceinline__ void mlp_pf(const f16* __restrict__ Xin,
                                       const float* __restrict__ bias,
                                       f16* __restrict__ Xout,
                                       int nt, int l,
                                       uint4 (&bf)[8],
                                       const uint4* __restrict__ B2,
                                       int NT2, int nt2, int nkt2) {
  const int m = l & 15;
  const int g = l >> 4;
  const bool act = (nt >= 0 && nt < NT);
  f32x4 acc = {0.f, 0.f, 0.f, 0.f};
#pragma unroll
  for (int t = 0; t < 8; ++t) {
    if (t < KT && act) {
      UF a; a.u = aread_lin(Xin, t, l);
      UF b; b.u = bf[t];
      acc = __builtin_amdgcn_mfma_f32_16x16x32_f16(a.h, b.h, acc, 0, 0, 0);
    }
    if (nt2 >= 0 && t < nkt2) bf[t] = B2[(t * NT2 + nt2) * 64 + l];
  }
  if (!act) return;
  const int col = nt * 16 + m;
  const float bb = bias[col];
#pragma unroll
  for (int i2 = 0; i2 < 4; ++i2)
    xwrite_frag(Xout, 4 * g + i2, col, ftanh(acc[i2] + bb));
}

// L3 phase: consumes W3 from LDS (zero global loads). bf untouched.
// MODE 1: hcf += 0.25*(.+b), mirror to Xnext(=XA). MODE 2: hcf += ...;
// col>=16 -> Xnext(=XG) at col+112; col<16 -> ehl = exp.
template <int MODE>
__device__ __forceinline__ void mlp_lds(const f16* __restrict__ Xin,
                                        const uint4* __restrict__ W3s,
                                        const float* __restrict__ bias,
                                        float* __restrict__ hcf,
                                        f16* __restrict__ Xnext,
                                        float* __restrict__ ehl,
                                        int nt, int l) {
  if (nt < 0) return;
  const int m = l & 15;
  const int g = l >> 4;
  f32x4 acc = {0.f, 0.f, 0.f, 0.f};
#pragma unroll
  for (int t = 0; t < 8; ++t) {
    UF a; a.u = aread_lin(Xin, t, l);
    UF b; b.u = W3s[(t * 9 + nt) * 64 + l];
    acc = __builtin_amdgcn_mfma_f32_16x16x32_f16(a.h, b.h, acc, 0, 0, 0);
  }
  const int col = nt * 16 + m;
  if (col < 136) {
    const float bb = bias[col];
#pragma unroll
    for (int i2 = 0; i2 < 4; ++i2) {
      const int row = 4 * g + i2;
      float v = hcf[row * HS + col] + 0.25f * (acc[i2] + bb);
      hcf[row * HS + col] = v;
      if (MODE == 1) {
        xwrite_frag(Xnext, row, col, v);
      } else {
        if (col >= 16) xwrite_frag(Xnext, row, col + 112, v);
        else ehl[row * 16 + col] = __expf(v);
      }
    }
  }
}

// Gate RZ: consumes persistent bf (prefetched at e==3 L2), no refill.
template <int KT, int NT>
__device__ __forceinline__ void gate_rz(const f16* __restrict__ Xin,
                                        float* __restrict__ GO,
                                        int nt, int gooff, int l,
                                        uint4 (&bf)[8]) {
  if (nt < 0) return;
  const int m = l & 15;
  const int g = l >> 4;
  f32x4 acc = {0.f, 0.f, 0.f, 0.f};
#pragma unroll
  for (int t = 0; t < KT; ++t) {
    UF a; a.u = aread_lin(Xin, t, l);
    UF b; b.u = bf[t];
    acc = __builtin_amdgcn_mfma_f32_16x16x32_f16(a.h, b.h, acc, 0, 0, 0);
  }
  const int col = nt * 16 + m;
#pragma unroll
  for (int i2 = 0; i2 < 4; ++i2)
    GO[(4 * g + i2) * GS + gooff + col] = acc[i2];
}

// Self-loading gate tile (NX/NH, small KT).
template <int KT, int NT>
__device__ __forceinline__ void gate_tile(const f16* __restrict__ Xin,
                                          const uint4* __restrict__ B,
                                          float* __restrict__ GO,
                                          int nt, int ktoff, int gooff, int l) {
  if (nt < 0) return;
  const int m = l & 15;
  const int g = l >> 4;
  uint4 bfx[KT];
#pragma unroll
  for (int t = 0; t < KT; ++t) bfx[t] = B[(t * NT + nt) * 64 + l];
  f32x4 acc = {0.f, 0.f, 0.f, 0.f};
#pragma unroll
  for (int t = 0; t < KT; ++t) {
    UF a; a.u = aread_lin(Xin, t + ktoff, l);
    UF b; b.u = bfx[t];
    acc = __builtin_amdgcn_mfma_f32_16x16x32_f16(a.h, b.h, acc, 0, 0, 0);
  }
  const int col = nt * 16 + m;
#pragma unroll
  for (int i2 = 0; i2 < 4; ++i2)
    GO[(4 * g + i2) * GS + gooff + col] = acc[i2];
}

// ------------------------------ K7: scan (W3 LDS-resident) ------------------
__global__ __launch_bounds__(1024, 1) void k7_scan(
    const float* __restrict__ xdv, const float* __restrict__ xov,
    const float* __restrict__ wxd, const float* __restrict__ whd,
    const float* __restrict__ bdv, const float* __restrict__ bov,
    const uint32_t* __restrict__ pk,
    const float* __restrict__ b0, const float* __restrict__ b1,
    const float* __restrict__ b2, const float* __restrict__ b3,
    const float* __restrict__ cw, const float* __restrict__ cbv,
    float* __restrict__ out) {
  __shared__ __align__(16) f16 XA[16 * 256];
  __shared__ __align__(16) f16 XB[16 * 256];
  __shared__ __align__(16) f16 XG[16 * 256];
  __shared__ __align__(16) uint4 W3s[4608];       // 73728 B: W3 resident
  __shared__ __align__(16) float GO[16 * GS];
  __shared__ __align__(16) float hcf[16 * HS];
  __shared__ __align__(16) float xdlv[16 * 16];
  __shared__ __align__(16) float ehl[16 * 16];
  __shared__ __align__(16) float G2[16 * 96];
  __shared__ __align__(16) float wdaT[48 * 16], whaT[48 * 16];
  __shared__ float b0l[256], b1l[256], b2l[256], b3l[144], bovl[360], bdvl[48];

  const int tid = threadIdx.x;
  const int w = tid >> 6;
  const int l = tid & 63;
  const int blk = blockIdx.x;

  const uint4* BW0 = (const uint4*)(pk + OFF_W0);
  const uint4* BW1 = (const uint4*)(pk + OFF_W1);
  const uint4* BW2 = (const uint4*)(pk + OFF_W2);
  const uint4* BW3 = (const uint4*)(pk + OFF_W3);
  const uint4* BRZ = (const uint4*)(pk + OFF_GRZ);
  const uint4* BNX = (const uint4*)(pk + OFF_GNX);
  const uint4* BNH = (const uint4*)(pk + OFF_GNH);

  // init LDS constants + resident W3
  for (int i = tid; i < 4608; i += 1024) W3s[i] = BW3[i];
  for (int i = tid; i < 768; i += 1024) {
    int k = i / 48, c = i - k * 48;
    wdaT[c * 16 + k] = fabsf(wxd[i]);
    whaT[c * 16 + k] = fabsf(whd[i]);
  }
  for (int i = tid; i < 256; i += 1024) { b0l[i] = b0[i]; b1l[i] = b1[i]; b2l[i] = b2[i]; }
  if (tid < 144) b3l[tid] = (tid < 136) ? b3[tid] : 0.f;
  if (tid < 360) bovl[tid] = bov[tid];
  if (tid < 48) bdvl[tid] = fabsf(bdv[tid]);
  for (int i = tid; i < 16 * HS; i += 1024) hcf[i] = 0.f;
  for (int i = tid; i < 4096; i += 1024) { XA[i] = (f16)0.f; XG[i] = (f16)0.f; }

  // persistent weight fragments; preload e0-L0 (BW0, tile w)
  uint4 bf[8];
#pragma unroll
  for (int t = 0; t < 5; ++t) bf[t] = BW0[(t * 16 + w) * 64 + l];
  __syncthreads();

#pragma unroll 1
  for (int s = 0; s < 50; ++s) {
    // ---- ODE: 4 Euler steps; 4 phases each ----
#pragma unroll 1
    for (int e = 0; e < 4; ++e) {
      // L0: read XA -> write XB. consume BW0, prefetch BW1.
      mlp_pf<5, 16>(XA, b0l, XB, w, l, bf, BW1, 16, w, 8);
      if (e == 0) {
        for (int i = tid; i < 1920; i += 1024) {
          int row = i / 120, c = i - row * 120;
          xwrite_frag(XG, row, c, xov[((size_t)(blk * 16 + row) * 50 + s) * 120 + c]);
        }
        if (tid < 256) {
          int row = tid >> 4, k = tid & 15;
          xdlv[tid] = xdv[((size_t)(blk * 16 + row) * 50 + s) * 16 + k];
        }
      }
      __syncthreads();
      // L1: read XB -> write XA. consume BW1, prefetch BW2.
      mlp_pf<8, 16>(XB, b1l, XA, w, l, bf, BW2, 16, w, 8);
      __syncthreads();
      // L2: read XA -> write XB. consume BW2, prefetch (BW0 | BRZ).
      {
        const uint4* nb = (e == 3) ? BRZ : BW0;
        const int nNT = (e == 3) ? 15 : 16;
        const int nnt = (e == 3) ? ((w < 15) ? w : -1) : w;
        const int nk = (e == 3) ? 8 : 5;
        mlp_pf<8, 16>(XA, b2l, XB, w, l, bf, nb, nNT, nnt, nk);
      }
      __syncthreads();
      // L3: read XB, W3 from LDS (zero global loads); bf untouched.
      if (e < 3)
        mlp_lds<1>(XB, W3s, b3l, hcf, XA, nullptr, (w < 9) ? w : -1, l);
      else
        mlp_lds<2>(XB, W3s, b3l, hcf, XG, ehl, (w < 9) ? w : -1, l);
      __syncthreads();
    }

    // ---- gate matmuls (RZ consumes persistent bf) + d-gate dots ----
    gate_rz<8, 15>(XG, GO, (w < 15) ? w : -1, 0, l, bf);
    gate_tile<4, 8>(XG, BNX, GO, (w < 8) ? w : -1, 0, 256, l);
    gate_tile<4, 8>(XG, BNH, GO, (w >= 8) ? (w - 8) : -1, 4, 384, l);
    for (int i = tid; i < 1536; i += 1024) {
      int row = i / 96, c = i - row * 96;
      const float4* sv = (const float4*)((c < 48) ? &xdlv[row * 16] : &ehl[row * 16]);
      const float4* wv = (const float4*)((c < 48) ? &wdaT[c * 16] : &whaT[(c - 48) * 16]);
      float a = 0.f;
#pragma unroll
      for (int q = 0; q < 4; ++q) {
        float4 xq = sv[q], wq = wv[q];
        a += xq.x * wq.x + xq.y * wq.y + xq.z * wq.z + xq.w * wq.w;
      }
      G2[row * 96 + c] = a;
    }
    __syncthreads();

    // ---- state update (prefetch next step's BW0 first; writes hcf + XA) ----
#pragma unroll
    for (int t = 0; t < 5; ++t) bf[t] = BW0[(t * 16 + w) * 64 + l];
    for (int i = tid; i < 1920; i += 1024) {
      int row = i / 120, e2 = i - row * 120;
      float rr = fsigm(GO[row * GS + e2] + bovl[e2]);
      float zz = fsigm(GO[row * GS + 120 + e2] + bovl[120 + e2]);
      float ng = ftanh(GO[row * GS + 256 + e2] + rr * GO[row * GS + 384 + e2] + bovl[240 + e2]);
      float ho = hcf[row * HS + 16 + e2];
      float v = ng + zz * (ho - ng);
      hcf[row * HS + 16 + e2] = v;
      xwrite_frag(XA, row, 16 + e2, v);
    }
    if (tid < 256) {
      int row = tid >> 4, t = tid & 15;
      float ixr = G2[row * 96 + t], ixi = G2[row * 96 + 16 + t], ixn = G2[row * 96 + 32 + t];
      float hhr = G2[row * 96 + 48 + t], hhi = G2[row * 96 + 64 + t], hhn = G2[row * 96 + 80 + t];
      float br = bdvl[t], bi = bdvl[16 + t], bn = bdvl[32 + t];
      float rr = fsigm(br * ixr * hhr);
      float zz = fsigm(bi * ixi * hhi);
      float sp = bn * ixn * rr * hhn;
      float ng = (sp > 20.f) ? sp : __logf(1.f + __expf(sp));
      float ldp = hcf[row * HS + t];
      float v = zz * ldp + (1.f - zz) * __logf(ng);
      hcf[row * HS + t] = v;
      xwrite_frag(XA, row, t, v);
    }
    __syncthreads();
  }

  // ---- classifier ----
  if (tid < 80) {
    int row = tid / 5, c = tid - row * 5;
    float a = cbv[c];
    for (int k = 0; k < 136; ++k) a += hcf[row * HS + k] * cw[k * 5 + c];
    out[(size_t)(blk * 16 + row) * 5 + c] = a;
  }
}

// ------------------------------ launch ------------------------------
extern "C" void kernel_launch(void* const* d_in, const int* in_sizes, int n_in,
                              void* d_out, int out_size, void* d_ws, size_t ws_size,
                              hipStream_t stream) {
  const float* x       = (const float*)d_in[0];
  const float* fw      = (const float*)d_in[1];
  const float* s_tri   = (const float*)d_in[2];
  const float* conv1_w = (const float*)d_in[3];
  const float* conv1_b = (const float*)d_in[4];
  const float* bn1_g   = (const float*)d_in[5];
  const float* bn1_b   = (const float*)d_in[6];
  const float* conv2_w = (const float*)d_in[7];
  const float* conv2_b = (const float*)d_in[8];
  const float* bn2_g   = (const float*)d_in[9];
  const float* bn2_b   = (const float*)d_in[10];
  const float* wx_d    = (const float*)d_in[11];
  const float* wh_d    = (const float*)d_in[12];
  const float* bias_d  = (const float*)d_in[13];
  const float* wx_o    = (const float*)d_in[14];
  const float* wh_o    = (const float*)d_in[15];
  const float* bias_o  = (const float*)d_in[16];
  const float* ode_w0  = (const float*)d_in[17];
  const float* ode_b0  = (const float*)d_in[18];
  const float* ode_w1  = (const float*)d_in[19];
  const float* ode_b1  = (const float*)d_in[20];
  const float* ode_w2  = (const float*)d_in[21];
  const float* ode_b2  = (const float*)d_in[22];
  const float* ode_w3  = (const float*)d_in[23];
  const float* ode_b3  = (const float*)d_in[24];
  const float* cls_w   = (const float*)d_in[25];
  const float* cls_b   = (const float*)d_in[26];

  float* ws = (float*)d_ws;
  float* h1  = ws;                    // 8,908,800 floats (K1->K2), then dead
  float* h3  = ws;                    // 1,075,200 floats (K4->K6)
  float* xd  = ws + 1075200;          // 51,200
  float* xo  = ws + 1126400;          // 384,000
  float* h2  = ws + 8908800;          // 7,680,000 (K2->K4), then reused by K0
  float* p1  = ws + 16588800;         // 614,400
  float* bn1 = ws + 17203200;         // 192
  float* p2  = ws + 17203392;         // 25,600
  float* bn2 = ws + 17228992;         // 32
  f16*   cw1h = (f16*)(ws + 17229024);      // 46,080 f16 (23,040 floats)
  uint32_t* pk = (uint32_t*)(ws + 8908800); // packed W-fragments (dead h2)

  hipLaunchKernelGGL(k0b_w1h, dim3(180),    dim3(256), 0, stream, conv1_w, cw1h);
  hipLaunchKernelGGL(k1_fb,   dim3(NIMG),   dim3(256), 0, stream, x, fw, s_tri, h1);
  hipLaunchKernelGGL(k2_conv1,dim3(NIMG/2), dim3(256), 0, stream, h1, cw1h, conv1_b, h2, p1);
  hipLaunchKernelGGL(k3_bn1,  dim3(96),     dim3(256), 0, stream, p1, bn1_g, bn1_b, bn1);
  hipLaunchKernelGGL(k4_conv2,dim3(NIMG/4), dim3(256), 0, stream, h2, conv2_w, conv2_b, bn1, h3, p2);
  hipLaunchKernelGGL(k5_bn2,  dim3(16),     dim3(256), 0, stream, p2, bn2_g, bn2_b, bn2);
  hipLaunchKernelGGL(k6_oas,  dim3(NIMG/4), dim3(256), 0, stream, h3, bn2, xd, xo);
  hipLaunchKernelGGL(k0_pack, dim3((PK2_TOT + 255) / 256), dim3(256), 0, stream,
                     ode_w0, ode_w1, ode_w2, ode_w3, wx_o, wh_o, pk);
  hipLaunchKernelGGL(k7_scan, dim3(4),      dim3(1024), 0, stream,
                     xd, xo, wx_d, wh_d, bias_d, bias_o, pk,
                     ode_b0, ode_b1, ode_b2, ode_b3, cls_w, cls_b, (float*)d_out);
}